// Round 1
// baseline (6715.335 us; speedup 1.0000x reference)
//
#include <hip/hip_runtime.h>
#include <math.h>

#define B_  2
#define L_  2048
#define D_  1024
#define H_  16
#define DH_ 64
#define BL_ (B_*L_)   // 4096

// workspace offsets (floats)
#define WS_Q   0
#define WS_K   4194304
#define WS_V   8388608
#define WS_AO  12582912
#define WS_COS 16777216
#define WS_SIN 16842752
#define WS_PB  16908288
#define WS_L   16910336
// total ~16.98M floats = ~68 MB

// ---------------------------------------------------------------- tables
__global__ void fill_tables(float* __restrict__ costab, float* __restrict__ sintab,
                            float* __restrict__ pbtab) {
  int idx = blockIdx.x * 256 + threadIdx.x;
  if (idx < L_ * 32) {
    int l = idx >> 5, tp = idx & 31;
    double inv = pow(10000.0, -2.0 * (double)tp / 64.0);
    double th  = (double)l * inv;
    costab[idx] = (float)cos(th);
    sintab[idx] = (float)sin(th);
  }
  if (idx < L_) {
    double d = (double)idx;
    double v = 0.5  * cos(6.283185307179586 * d / 24.0)
             + 0.25 * cos(6.283185307179586 * d / 168.0);
    pbtab[idx] = (float)v;
  }
}

// ---------------------------------------------------------------- GEMM 128x128, BK=16, 256 thr, 8x8 micro
// C[M=4096][1024] = A[4096][1024] @ W[1024][1024] + bias ; optional fused RoPE epilogue
__global__ __launch_bounds__(256) void gemm128(
    const float* __restrict__ A, const float* __restrict__ W,
    const float* __restrict__ bias, float* __restrict__ C,
    int doRope, const float* __restrict__ costab, const float* __restrict__ sintab)
{
  __shared__ float AsT[16][128];   // [k][row]
  __shared__ float Bs [16][128];   // [k][col]
  const int t  = threadIdx.x;
  const int tx = t & 15, ty = t >> 4;
  const int row0 = blockIdx.x << 7, col0 = blockIdx.y << 7;
  const int ar  = t >> 1;          // 0..127
  const int akk = (t & 1) << 3;    // 0 or 8
  const int br  = t >> 4;          // 0..15
  const int bc  = (t & 15) << 3;   // 0..120

  float acc[8][8];
  #pragma unroll
  for (int i = 0; i < 8; ++i)
    #pragma unroll
    for (int j = 0; j < 8; ++j) acc[i][j] = 0.f;

  for (int k0 = 0; k0 < D_; k0 += 16) {
    float4 a0 = *(const float4*)(A + (size_t)(row0 + ar)*D_ + k0 + akk);
    float4 a1 = *(const float4*)(A + (size_t)(row0 + ar)*D_ + k0 + akk + 4);
    float4 b0 = *(const float4*)(W + (size_t)(k0 + br)*D_ + col0 + bc);
    float4 b1 = *(const float4*)(W + (size_t)(k0 + br)*D_ + col0 + bc + 4);
    __syncthreads();
    AsT[akk+0][ar] = a0.x; AsT[akk+1][ar] = a0.y; AsT[akk+2][ar] = a0.z; AsT[akk+3][ar] = a0.w;
    AsT[akk+4][ar] = a1.x; AsT[akk+5][ar] = a1.y; AsT[akk+6][ar] = a1.z; AsT[akk+7][ar] = a1.w;
    *(float4*)(&Bs[br][bc])   = b0;
    *(float4*)(&Bs[br][bc+4]) = b1;
    __syncthreads();
    #pragma unroll
    for (int kk = 0; kk < 16; ++kk) {
      float av[8], bv[8];
      *(float4*)(av)   = *(const float4*)(&AsT[kk][(ty<<3)]);
      *(float4*)(av+4) = *(const float4*)(&AsT[kk][(ty<<3)+4]);
      *(float4*)(bv)   = *(const float4*)(&Bs[kk][(tx<<3)]);
      *(float4*)(bv+4) = *(const float4*)(&Bs[kk][(tx<<3)+4]);
      #pragma unroll
      for (int i = 0; i < 8; ++i)
        #pragma unroll
        for (int j = 0; j < 8; ++j)
          acc[i][j] += av[i]*bv[j];
    }
  }

  // epilogue
  const int n0 = col0 + (tx << 3);
  float bb[8];
  *(float4*)(bb)   = *(const float4*)(bias + n0);
  *(float4*)(bb+4) = *(const float4*)(bias + n0 + 4);

  #pragma unroll
  for (int i = 0; i < 8; ++i) {
    const int m = row0 + (ty << 3) + i;
    float o[8];
    if (doRope) {
      const int l   = m & (L_ - 1);
      const int tp0 = (n0 & 63) >> 1;
      #pragma unroll
      for (int p = 0; p < 4; ++p) {
        const float c = costab[l*32 + tp0 + p];
        const float s = sintab[l*32 + tp0 + p];
        const float x1 = acc[i][2*p]   + bb[2*p];
        const float x2 = acc[i][2*p+1] + bb[2*p+1];
        o[2*p]   = x1*c - x2*s;
        o[2*p+1] = x1*s + x2*c;
      }
    } else {
      #pragma unroll
      for (int j = 0; j < 8; ++j) o[j] = acc[i][j] + bb[j];
    }
    *(float4*)(&C[(size_t)m*D_ + n0])     = make_float4(o[0],o[1],o[2],o[3]);
    *(float4*)(&C[(size_t)m*D_ + n0 + 4]) = make_float4(o[4],o[5],o[6],o[7]);
  }
}

// ---------------------------------------------------------------- attention (single pass, unnormalized exp, fixed m=0)
// Q/K/V: [B*L][D] with head h at cols h*64..h*64+63 (post-RoPE for Q,K)
// writes: Pout (unnormalized, lower-triangle tiles only), AO (normalized), lrow (row sums)
__global__ __launch_bounds__(256) void attn_fwd(
    const float* __restrict__ Q, const float* __restrict__ K, const float* __restrict__ V,
    const float* __restrict__ pbtab, float* __restrict__ Pout, float* __restrict__ AO,
    float* __restrict__ lrow)
{
  __shared__ float QsT[64][64];  // [k][row^swz]
  __shared__ float KsT[64][64];  // [k][jcol^swz]
  __shared__ float Vs [64][64];  // [j][d^swz]
  __shared__ float PsT[64][64];  // [j][row^swz]
  const int t  = threadIdx.x;
  const int tx = t & 15, ty = t >> 4;
  const int bh = blockIdx.y;
  const int b  = bh >> 4, h = bh & 15;
  const int it = blockIdx.x;
  const int i0 = it << 6;
  const size_t base = ((size_t)b * L_) * D_ + h * DH_;

  // load Q tile transposed+swizzled: QsT[kk][r ^ (kk&60)]
  {
    const int r = t >> 2, c0 = (t & 3) << 4;
    const float* qg = Q + base + (size_t)(i0 + r) * D_;
    #pragma unroll
    for (int u = 0; u < 4; ++u) {
      const int kkb = c0 + 4*u;
      float4 v = *(const float4*)(qg + kkb);
      const int cw = r ^ kkb;
      QsT[kkb+0][cw] = v.x; QsT[kkb+1][cw] = v.y;
      QsT[kkb+2][cw] = v.z; QsT[kkb+3][cw] = v.w;
    }
  }

  float oacc[4][4];
  #pragma unroll
  for (int i = 0; i < 4; ++i)
    #pragma unroll
    for (int j = 0; j < 4; ++j) oacc[i][j] = 0.f;
  float lsum[4] = {0.f, 0.f, 0.f, 0.f};
  const int rbase = i0 + (ty << 2);

  for (int jt = 0; jt <= it; ++jt) {
    const int j0 = jt << 6;
    __syncthreads();   // prev iter done with KsT/Vs/PsT
    {
      const int r = t >> 2, c0 = (t & 3) << 4;
      const float* kg = K + base + (size_t)(j0 + r) * D_;
      const float* vg = V + base + (size_t)(j0 + r) * D_;
      #pragma unroll
      for (int u = 0; u < 4; ++u) {
        const int kkb = c0 + 4*u;
        float4 kv = *(const float4*)(kg + kkb);
        float4 vv = *(const float4*)(vg + kkb);
        const int cw = r ^ kkb;
        KsT[kkb+0][cw] = kv.x; KsT[kkb+1][cw] = kv.y;
        KsT[kkb+2][cw] = kv.z; KsT[kkb+3][cw] = kv.w;
        *(float4*)(&Vs[r][kkb ^ (r & 60)]) = vv;
      }
    }
    __syncthreads();

    // S = Q K^T  (4x4 micro, outer product over kk)
    float s[4][4];
    #pragma unroll
    for (int i = 0; i < 4; ++i)
      #pragma unroll
      for (int j = 0; j < 4; ++j) s[i][j] = 0.f;
    #pragma unroll
    for (int kk = 0; kk < 64; ++kk) {
      const float4 qa = *(const float4*)(&QsT[kk][(ty<<2) ^ (kk & 60)]);
      const float4 kb = *(const float4*)(&KsT[kk][(tx<<2) ^ (kk & 60)]);
      s[0][0] += qa.x*kb.x; s[0][1] += qa.x*kb.y; s[0][2] += qa.x*kb.z; s[0][3] += qa.x*kb.w;
      s[1][0] += qa.y*kb.x; s[1][1] += qa.y*kb.y; s[1][2] += qa.y*kb.z; s[1][3] += qa.y*kb.w;
      s[2][0] += qa.z*kb.x; s[2][1] += qa.z*kb.y; s[2][2] += qa.z*kb.z; s[2][3] += qa.z*kb.w;
      s[3][0] += qa.w*kb.x; s[3][1] += qa.w*kb.y; s[3][2] += qa.w*kb.z; s[3][3] += qa.w*kb.w;
    }

    // bias + exp + write unnormalized P (global + LDS transposed)
    const int jb = j0 + (tx << 2);
    const int jr = tx << 2;
    #pragma unroll
    for (int ii = 0; ii < 4; ++ii) {
      const int i = rbase + ii;
      float pr[4];
      #pragma unroll
      for (int jj = 0; jj < 4; ++jj) {
        const int d = i - (jb + jj);
        const float pbv = pbtab[d < 0 ? 0 : d];
        const float pe  = (d >= 0) ? __expf(s[ii][jj]*0.125f + pbv) : 0.f;
        pr[jj] = pe;
        lsum[ii] += pe;
      }
      *(float4*)(Pout + ((size_t)bh*L_ + i)*L_ + jb) = make_float4(pr[0],pr[1],pr[2],pr[3]);
      const int rw = ((ty<<2) + ii) ^ jr;
      PsT[jr+0][rw] = pr[0]; PsT[jr+1][rw] = pr[1];
      PsT[jr+2][rw] = pr[2]; PsT[jr+3][rw] = pr[3];
    }
    __syncthreads();

    // PV accumulate (outer product over jj)
    #pragma unroll
    for (int jj = 0; jj < 64; ++jj) {
      const float4 pa = *(const float4*)(&PsT[jj][(ty<<2) ^ (jj & 60)]);
      const float4 vb = *(const float4*)(&Vs[jj][(tx<<2) ^ (jj & 60)]);
      oacc[0][0] += pa.x*vb.x; oacc[0][1] += pa.x*vb.y; oacc[0][2] += pa.x*vb.z; oacc[0][3] += pa.x*vb.w;
      oacc[1][0] += pa.y*vb.x; oacc[1][1] += pa.y*vb.y; oacc[1][2] += pa.y*vb.z; oacc[1][3] += pa.y*vb.w;
      oacc[2][0] += pa.z*vb.x; oacc[2][1] += pa.z*vb.y; oacc[2][2] += pa.z*vb.z; oacc[2][3] += pa.z*vb.w;
      oacc[3][0] += pa.w*vb.x; oacc[3][1] += pa.w*vb.y; oacc[3][2] += pa.w*vb.z; oacc[3][3] += pa.w*vb.w;
    }
  }

  // reduce lsum across the 16 lanes sharing the same rows
  #pragma unroll
  for (int ii = 0; ii < 4; ++ii) {
    float v = lsum[ii];
    for (int off = 1; off < 16; off <<= 1) v += __shfl_xor(v, off, 16);
    lsum[ii] = v;
  }
  if (tx == 0) {
    #pragma unroll
    for (int ii = 0; ii < 4; ++ii)
      lrow[(size_t)bh*L_ + rbase + ii] = lsum[ii];
  }

  // write normalized attention output (layout [B*L][D], head cols)
  #pragma unroll
  for (int ii = 0; ii < 4; ++ii) {
    const float rinv = 1.f / lsum[ii];
    const int i = rbase + ii;
    *(float4*)(AO + base + (size_t)i*D_ + (tx<<2)) =
        make_float4(oacc[ii][0]*rinv, oacc[ii][1]*rinv, oacc[ii][2]*rinv, oacc[ii][3]*rinv);
  }
}

// ---------------------------------------------------------------- normalize P rows + zero upper triangle
__global__ __launch_bounds__(256) void rescale_p(float* __restrict__ P, const float* __restrict__ lrow) {
  const int row = blockIdx.x;            // bh*2048 + i, 0..65535
  const int i   = row & (L_ - 1);
  const float rinv = 1.f / lrow[row];
  float4* pr = (float4*)(P + (size_t)row * L_);
  const int lim = i >> 2;
  for (int c4 = threadIdx.x; c4 < L_/4; c4 += 256) {
    if (c4 < lim) {
      float4 v = pr[c4];
      v.x *= rinv; v.y *= rinv; v.z *= rinv; v.w *= rinv;
      pr[c4] = v;
    } else if (c4 == lim) {
      float4 v = pr[c4];
      const int j = c4 << 2;
      v.x = (j     <= i) ? v.x*rinv : 0.f;
      v.y = (j + 1 <= i) ? v.y*rinv : 0.f;
      v.z = (j + 2 <= i) ? v.z*rinv : 0.f;
      v.w = (j + 3 <= i) ? v.w*rinv : 0.f;
      pr[c4] = v;
    } else {
      pr[c4] = make_float4(0.f, 0.f, 0.f, 0.f);
    }
  }
}

// ---------------------------------------------------------------- launch
extern "C" void kernel_launch(void* const* d_in, const int* in_sizes, int n_in,
                              void* d_out, int out_size, void* d_ws, size_t ws_size,
                              hipStream_t stream) {
  const float* x  = (const float*)d_in[0];
  const float* Wq = (const float*)d_in[1];
  const float* bq = (const float*)d_in[2];
  const float* Wk = (const float*)d_in[3];
  const float* bk = (const float*)d_in[4];
  const float* Wv = (const float*)d_in[5];
  const float* bv = (const float*)d_in[6];
  const float* Wo = (const float*)d_in[7];
  const float* bo = (const float*)d_in[8];

  float* out  = (float*)d_out;
  float* Pout = out + (size_t)BL_ * D_;   // p region: 134,217,728 floats

  float* ws   = (float*)d_ws;
  float* Qw   = ws + WS_Q;
  float* Kw   = ws + WS_K;
  float* Vw   = ws + WS_V;
  float* AOw  = ws + WS_AO;
  float* cosT = ws + WS_COS;
  float* sinT = ws + WS_SIN;
  float* pbT  = ws + WS_PB;
  float* lw   = ws + WS_L;

  fill_tables<<<256, 256, 0, stream>>>(cosT, sinT, pbT);

  dim3 gg(BL_/128, D_/128);  // (32, 8)
  gemm128<<<gg, 256, 0, stream>>>(x, Wq, bq, Qw, 1, cosT, sinT);
  gemm128<<<gg, 256, 0, stream>>>(x, Wk, bk, Kw, 1, cosT, sinT);
  gemm128<<<gg, 256, 0, stream>>>(x, Wv, bv, Vw, 0, cosT, sinT);

  attn_fwd<<<dim3(L_/64, B_*H_), 256, 0, stream>>>(Qw, Kw, Vw, pbT, Pout, AOw, lw);

  rescale_p<<<B_*H_*L_, 256, 0, stream>>>(Pout, lw);

  gemm128<<<gg, 256, 0, stream>>>(AOw, Wo, bo, out, 0, cosT, sinT);
}

// Round 2
// 1049.793 us; speedup vs baseline: 6.3968x; 6.3968x over previous
//
#include <hip/hip_runtime.h>
#include <math.h>

#define B_  2
#define L_  2048
#define D_  1024
#define H_  16
#define DH_ 64
#define BL_ (B_*L_)   // 4096

typedef __attribute__((ext_vector_type(8))) short short8;
typedef __attribute__((ext_vector_type(4))) float f32x4;

// workspace offsets (in floats); bf16 buffers occupy elems/2 floats
#define WS_QB  0          // [32][2048][64] bf16 = 2097152 floats
#define WS_KB  2097152
#define WS_VB  4194304
#define WS_VT  6291456
#define WS_AO  8388608    // fp32 [4096][1024]
#define WS_COS 12582912
#define WS_SIN 12648448
#define WS_PB  12713984
#define WS_L   12716032
// total ~12.78M floats = ~51 MB

__device__ __forceinline__ unsigned short f2b(float f) {
  union { float f; unsigned u; } v; v.f = f;
  unsigned r = (v.u + 0x7fffu + ((v.u >> 16) & 1u)) >> 16;
  return (unsigned short)r;
}

// ---------------------------------------------------------------- tables
__global__ void fill_tables(float* __restrict__ costab, float* __restrict__ sintab,
                            float* __restrict__ pbtab) {
  int idx = blockIdx.x * 256 + threadIdx.x;
  if (idx < L_ * 32) {
    int l = idx >> 5, tp = idx & 31;
    double inv = pow(10000.0, -2.0 * (double)tp / 64.0);
    double th  = (double)l * inv;
    costab[idx] = (float)cos(th);
    sintab[idx] = (float)sin(th);
  }
  if (idx < L_) {
    double d = (double)idx;
    double v = 0.5  * cos(6.283185307179586 * d / 24.0)
             + 0.25 * cos(6.283185307179586 * d / 168.0);
    pbtab[idx] = (float)v;
  }
}

// ---------------------------------------------------------------- GEMM 128x128, BK=16, 256 thr, 8x8 micro
// mode 0: C fp32 [M][1024] + bias
// mode 1: bf16 out to Cb[bh][L][64] with RoPE
// mode 2: bf16 out to Cb[bh][L][64] no RoPE
__global__ __launch_bounds__(256) void gemm128(
    const float* __restrict__ A, const float* __restrict__ W,
    const float* __restrict__ bias, float* __restrict__ C, unsigned short* __restrict__ Cb,
    int mode, const float* __restrict__ costab, const float* __restrict__ sintab)
{
  __shared__ float AsT[16][128];   // [k][row]
  __shared__ float Bs [16][128];   // [k][col]
  const int t  = threadIdx.x;
  const int tx = t & 15, ty = t >> 4;
  const int row0 = blockIdx.x << 7, col0 = blockIdx.y << 7;
  const int ar  = t >> 1;          // 0..127
  const int akk = (t & 1) << 3;    // 0 or 8
  const int br  = t >> 4;          // 0..15
  const int bc  = (t & 15) << 3;   // 0..120

  float acc[8][8];
  #pragma unroll
  for (int i = 0; i < 8; ++i)
    #pragma unroll
    for (int j = 0; j < 8; ++j) acc[i][j] = 0.f;

  for (int k0 = 0; k0 < D_; k0 += 16) {
    float4 a0 = *(const float4*)(A + (size_t)(row0 + ar)*D_ + k0 + akk);
    float4 a1 = *(const float4*)(A + (size_t)(row0 + ar)*D_ + k0 + akk + 4);
    float4 b0 = *(const float4*)(W + (size_t)(k0 + br)*D_ + col0 + bc);
    float4 b1 = *(const float4*)(W + (size_t)(k0 + br)*D_ + col0 + bc + 4);
    __syncthreads();
    AsT[akk+0][ar] = a0.x; AsT[akk+1][ar] = a0.y; AsT[akk+2][ar] = a0.z; AsT[akk+3][ar] = a0.w;
    AsT[akk+4][ar] = a1.x; AsT[akk+5][ar] = a1.y; AsT[akk+6][ar] = a1.z; AsT[akk+7][ar] = a1.w;
    *(float4*)(&Bs[br][bc])   = b0;
    *(float4*)(&Bs[br][bc+4]) = b1;
    __syncthreads();
    #pragma unroll
    for (int kk = 0; kk < 16; ++kk) {
      float av[8], bv[8];
      *(float4*)(av)   = *(const float4*)(&AsT[kk][(ty<<3)]);
      *(float4*)(av+4) = *(const float4*)(&AsT[kk][(ty<<3)+4]);
      *(float4*)(bv)   = *(const float4*)(&Bs[kk][(tx<<3)]);
      *(float4*)(bv+4) = *(const float4*)(&Bs[kk][(tx<<3)+4]);
      #pragma unroll
      for (int i = 0; i < 8; ++i)
        #pragma unroll
        for (int j = 0; j < 8; ++j)
          acc[i][j] += av[i]*bv[j];
    }
  }

  const int n0 = col0 + (tx << 3);
  float bb[8];
  *(float4*)(bb)   = *(const float4*)(bias + n0);
  *(float4*)(bb+4) = *(const float4*)(bias + n0 + 4);

  #pragma unroll
  for (int i = 0; i < 8; ++i) {
    const int m = row0 + (ty << 3) + i;
    float o[8];
    if (mode == 1) {
      const int l   = m & (L_ - 1);
      const int tp0 = (n0 & 63) >> 1;
      #pragma unroll
      for (int p = 0; p < 4; ++p) {
        const float c = costab[l*32 + tp0 + p];
        const float s = sintab[l*32 + tp0 + p];
        const float x1 = acc[i][2*p]   + bb[2*p];
        const float x2 = acc[i][2*p+1] + bb[2*p+1];
        o[2*p]   = x1*c - x2*s;
        o[2*p+1] = x1*s + x2*c;
      }
    } else {
      #pragma unroll
      for (int j = 0; j < 8; ++j) o[j] = acc[i][j] + bb[j];
    }
    if (mode == 0) {
      *(float4*)(&C[(size_t)m*D_ + n0])     = make_float4(o[0],o[1],o[2],o[3]);
      *(float4*)(&C[(size_t)m*D_ + n0 + 4]) = make_float4(o[4],o[5],o[6],o[7]);
    } else {
      // bf16 head layout: [b*16+h][l][d]
      const int b = m >> 11, l = m & (L_ - 1);
      const int h = n0 >> 6, d0 = n0 & 63;
      unsigned short us[8];
      #pragma unroll
      for (int j = 0; j < 8; ++j) us[j] = f2b(o[j]);
      *(short8*)(Cb + ((size_t)(b*16 + h)*L_ + l)*64 + d0) = *(short8*)us;
    }
  }
}

// ---------------------------------------------------------------- V transpose: Vb[bh][L][64] -> Vt[bh][64][L]
__global__ __launch_bounds__(256) void vtrans(const unsigned short* __restrict__ Vb,
                                              unsigned short* __restrict__ Vt) {
  __shared__ unsigned short s[64][72];   // [d][l], padded
  const int bh = blockIdx.y;
  const int l0 = blockIdx.x << 6;
  const int t  = threadIdx.x;
  const int r  = t >> 3;
  const int c  = (t & 7) << 3;
  const unsigned short* src = Vb + ((size_t)bh*L_ + l0)*64;
  #pragma unroll
  for (int rr = r; rr < 64; rr += 32) {
    short8 v = *(const short8*)(src + rr*64 + c);
    #pragma unroll
    for (int u = 0; u < 8; ++u) s[c + u][rr] = ((unsigned short*)&v)[u];
  }
  __syncthreads();
  const int d = t >> 2, lc = (t & 3) << 4;
  unsigned short* dst = Vt + ((size_t)bh*64 + d)*L_ + l0 + lc;
  *(short8*)(dst)     = *(const short8*)(&s[d][lc]);
  *(short8*)(dst + 8) = *(const short8*)(&s[d][lc + 8]);
}

// ---------------------------------------------------------------- MFMA attention
// Qb,Kb: [bh][L][64] bf16 (post-RoPE); Vt: [bh][64][L] bf16
// writes unnormalized exp P (lower-tri tiles), AO fp32 [B*L][1024], lrow
__global__ __launch_bounds__(256, 3) void attn_mfma(
    const unsigned short* __restrict__ Qb, const unsigned short* __restrict__ Kb,
    const unsigned short* __restrict__ Vt, const float* __restrict__ pbtab,
    float* __restrict__ Pout, float* __restrict__ AO, float* __restrict__ lrow)
{
  __shared__ unsigned short Pb[4][1024];   // per wave: 16 rows x 64 cols bf16, XOR-swizzled
  const int t  = threadIdx.x;
  const int w  = t >> 6;
  const int l  = t & 63;
  const int lt = l & 15;        // col-ish lane id
  const int lg = l >> 4;        // k-group
  const int bh = blockIdx.y;
  const int b  = bh >> 4, h = bh & 15;
  const int itx = blockIdx.x;
  const int it = (itx & 1) ? (31 - (itx >> 1)) : (itx >> 1);   // big/small interleave
  const int i0 = it << 6;

  // Q fragments (A-layout): lane: row = i0+w*16+lt, k = lg*8 + [0..7]
  const unsigned short* qp = Qb + ((size_t)bh*L_ + i0 + w*16 + lt)*64 + lg*8;
  const short8 qf0 = *(const short8*)(qp);
  const short8 qf1 = *(const short8*)(qp + 32);

  f32x4 oacc[4];
  #pragma unroll
  for (int dt = 0; dt < 4; ++dt) oacc[dt] = (f32x4){0.f,0.f,0.f,0.f};
  float lsum[4] = {0.f,0.f,0.f,0.f};

  char* pbase = (char*)(&Pb[w][0]);

  for (int kvt = 0; kvt <= it; ++kvt) {
    const int j0 = kvt << 6;

    // ---- S = Q K^T : 4 j-tiles x (K=64 -> 2 mfma)
    const unsigned short* kp = Kb + ((size_t)bh*L_ + j0 + lt)*64 + lg*8;
    f32x4 s[4];
    #pragma unroll
    for (int jt = 0; jt < 4; ++jt) {
      short8 kf0 = *(const short8*)(kp + jt*16*64);
      short8 kf1 = *(const short8*)(kp + jt*16*64 + 32);
      f32x4 z = (f32x4){0.f,0.f,0.f,0.f};
      z = __builtin_amdgcn_mfma_f32_16x16x32_bf16(qf0, kf0, z, 0, 0, 0);
      z = __builtin_amdgcn_mfma_f32_16x16x32_bf16(qf1, kf1, z, 0, 0, 0);
      s[jt] = z;
    }

    // ---- bias + mask + exp; write P global (unnorm) + Pb LDS (bf16, swizzled)
    const int rloc0 = 4*lg;                    // local row base for D-frag
    const int diag  = (kvt == it);
    #pragma unroll
    for (int jt = 0; jt < 4; ++jt) {
      const int j = j0 + jt*16 + lt;
      #pragma unroll
      for (int r = 0; r < 4; ++r) {
        const int i = i0 + w*16 + rloc0 + r;
        const int d = i - j;
        const int dc = d < 0 ? 0 : d;
        float pe = __expf(s[jt][r]*0.125f + pbtab[dc]);
        if (diag && d < 0) pe = 0.f;
        lsum[r] += pe;
        Pout[((size_t)bh*L_ + i)*L_ + j] = pe;
        const int rl = rloc0 + r;
        const int byteoff = rl*128 + ((2*(jt*16 + lt)) ^ ((rl & 7) << 4));
        *(unsigned short*)(pbase + byteoff) = f2b(pe);
      }
    }

    // ---- PV: A-frags from Pb (same wave -> no barrier), B-frags from Vt (L2)
    short8 pa[2];
    #pragma unroll
    for (int jh = 0; jh < 2; ++jh) {
      const int byteoff = lt*128 + ((jh*64 + lg*16) ^ ((lt & 7) << 4));
      pa[jh] = *(const short8*)(pbase + byteoff);
    }
    const unsigned short* vp = Vt + ((size_t)bh*64 + lt)*L_ + j0 + lg*8;
    #pragma unroll
    for (int dt = 0; dt < 4; ++dt) {
      short8 vf0 = *(const short8*)(vp + dt*16*L_);
      short8 vf1 = *(const short8*)(vp + dt*16*L_ + 32);
      oacc[dt] = __builtin_amdgcn_mfma_f32_16x16x32_bf16(pa[0], vf0, oacc[dt], 0, 0, 0);
      oacc[dt] = __builtin_amdgcn_mfma_f32_16x16x32_bf16(pa[1], vf1, oacc[dt], 0, 0, 0);
    }
  }

  // ---- row sums across the 16 lanes of this k-group (same 4 rows)
  #pragma unroll
  for (int r = 0; r < 4; ++r) {
    float v = lsum[r];
    #pragma unroll
    for (int off = 1; off < 16; off <<= 1) v += __shfl_xor(v, off, 16);
    lsum[r] = v;
  }

  const int ig0 = i0 + w*16 + 4*lg;
  if (lt == 0) {
    #pragma unroll
    for (int r = 0; r < 4; ++r) lrow[(size_t)bh*L_ + ig0 + r] = lsum[r];
  }

  // ---- normalized AO write: rows ig0+r, cols h*64 + dt*16 + lt
  #pragma unroll
  for (int r = 0; r < 4; ++r) {
    const float rinv = 1.f / lsum[r];
    float* ao = AO + ((size_t)(b*L_ + ig0 + r))*D_ + h*64 + lt;
    #pragma unroll
    for (int dt = 0; dt < 4; ++dt) ao[dt*16] = oacc[dt][r] * rinv;
  }
}

// ---------------------------------------------------------------- normalize P rows + zero upper triangle
__global__ __launch_bounds__(256) void rescale_p(float* __restrict__ P, const float* __restrict__ lrow) {
  const int row = blockIdx.x;            // bh*2048 + i
  const int i   = row & (L_ - 1);
  const float rinv = 1.f / lrow[row];
  float4* pr = (float4*)(P + (size_t)row * L_);
  const int lim = i >> 2;
  for (int c4 = threadIdx.x; c4 < L_/4; c4 += 256) {
    if (c4 < lim) {
      float4 v = pr[c4];
      v.x *= rinv; v.y *= rinv; v.z *= rinv; v.w *= rinv;
      pr[c4] = v;
    } else if (c4 == lim) {
      float4 v = pr[c4];
      const int j = c4 << 2;
      v.x = (j     <= i) ? v.x*rinv : 0.f;
      v.y = (j + 1 <= i) ? v.y*rinv : 0.f;
      v.z = (j + 2 <= i) ? v.z*rinv : 0.f;
      v.w = (j + 3 <= i) ? v.w*rinv : 0.f;
      pr[c4] = v;
    } else {
      pr[c4] = make_float4(0.f, 0.f, 0.f, 0.f);
    }
  }
}

// ---------------------------------------------------------------- launch
extern "C" void kernel_launch(void* const* d_in, const int* in_sizes, int n_in,
                              void* d_out, int out_size, void* d_ws, size_t ws_size,
                              hipStream_t stream) {
  const float* x  = (const float*)d_in[0];
  const float* Wq = (const float*)d_in[1];
  const float* bq = (const float*)d_in[2];
  const float* Wk = (const float*)d_in[3];
  const float* bk = (const float*)d_in[4];
  const float* Wv = (const float*)d_in[5];
  const float* bv = (const float*)d_in[6];
  const float* Wo = (const float*)d_in[7];
  const float* bo = (const float*)d_in[8];

  float* out  = (float*)d_out;
  float* Pout = out + (size_t)BL_ * D_;   // p region

  float* ws = (float*)d_ws;
  unsigned short* Qb = (unsigned short*)(ws + WS_QB);
  unsigned short* Kb = (unsigned short*)(ws + WS_KB);
  unsigned short* Vb = (unsigned short*)(ws + WS_VB);
  unsigned short* Vt = (unsigned short*)(ws + WS_VT);
  float* AOw  = ws + WS_AO;
  float* cosT = ws + WS_COS;
  float* sinT = ws + WS_SIN;
  float* pbT  = ws + WS_PB;
  float* lw   = ws + WS_L;

  fill_tables<<<256, 256, 0, stream>>>(cosT, sinT, pbT);

  dim3 gg(BL_/128, D_/128);  // (32, 8)
  gemm128<<<gg, 256, 0, stream>>>(x, Wq, bq, nullptr, Qb, 1, cosT, sinT);
  gemm128<<<gg, 256, 0, stream>>>(x, Wk, bk, nullptr, Kb, 1, cosT, sinT);
  gemm128<<<gg, 256, 0, stream>>>(x, Wv, bv, nullptr, Vb, 2, cosT, sinT);

  vtrans<<<dim3(L_/64, B_*H_), 256, 0, stream>>>(Vb, Vt);

  attn_mfma<<<dim3(L_/64, B_*H_), 256, 0, stream>>>(Qb, Kb, Vt, pbT, Pout, AOw, lw);

  rescale_p<<<B_*H_*L_, 256, 0, stream>>>(Pout, lw);

  gemm128<<<gg, 256, 0, stream>>>(AOw, Wo, bo, out, nullptr, 0, cosT, sinT);
}

// Round 4
// 522.027 us; speedup vs baseline: 12.8639x; 2.0110x over previous
//
#include <hip/hip_runtime.h>
#include <math.h>

#define B_  2
#define L_  2048
#define D_  1024
#define H_  16
#define DH_ 64
#define BL_ (B_*L_)   // 4096

typedef unsigned short u16;
typedef __attribute__((ext_vector_type(8))) short short8;
typedef __attribute__((ext_vector_type(4))) float f32x4;
typedef __attribute__((ext_vector_type(4))) unsigned short u16x4;

template<bool V> struct BC { static constexpr bool value = V; };

// ---- workspace offsets (floats) -- each bf16 [4096][1024]-sized buffer = 2,097,152 floats
#define WS_XB   0            // x bf16 [4096][1024]
#define WS_WT4  2097152      // Wt bf16 [4][1024][1024] (2 u16 per float slot)
#define WS_QB   4194304      // [32][2048][64] bf16  = 4,194,304 u16 = 2,097,152 floats
#define WS_KB   6291456
#define WS_VT   8388608      // [32][64][2048] bf16
#define WS_AOB  10485760     // AO bf16 [4096][1024]
#define WS_COS  12582912     // [2048][32] f32
#define WS_SIN  12648448
#define WS_PBL  12713984     // [2048] f32 (pre-scaled by log2e)
#define WS_LROW 12716032     // [65536] f32
// end 12781568 floats ~ 51.1 MB

__device__ __forceinline__ u16 f2b(float f) {
  union { float f; unsigned u; } v; v.f = f;
  unsigned r = (v.u + 0x7fffu + ((v.u >> 16) & 1u)) >> 16;
  return (u16)r;
}
__device__ __forceinline__ u16x4 f2b4(float a, float b, float c, float d) {
  u16x4 u; u.x = f2b(a); u.y = f2b(b); u.z = f2b(c); u.w = f2b(d); return u;
}
__device__ __forceinline__ void gl_lds16(const void* g, void* l) {
  __builtin_amdgcn_global_load_lds(
      (const __attribute__((address_space(1))) unsigned int*)g,
      (__attribute__((address_space(3))) unsigned int*)l, 16, 0, 0);
}

// ---------------------------------------------------------------- tables
__global__ void fill_tables(float* __restrict__ costab, float* __restrict__ sintab,
                            float* __restrict__ pbl) {
  int idx = blockIdx.x * 256 + threadIdx.x;
  if (idx < L_ * 32) {
    int l = idx >> 5, tp = idx & 31;
    double inv = pow(10000.0, -2.0 * (double)tp / 64.0);
    double th  = (double)l * inv;
    costab[idx] = (float)cos(th);
    sintab[idx] = (float)sin(th);
  }
  if (idx < L_) {
    double d = (double)idx;
    double v = 0.5  * cos(6.283185307179586 * d / 24.0)
             + 0.25 * cos(6.283185307179586 * d / 168.0);
    pbl[idx] = (float)(v * 1.4426950408889634);
  }
}

// ---------------------------------------------------------------- x -> bf16
__global__ __launch_bounds__(256) void xcast(const float* __restrict__ x, u16* __restrict__ xb) {
  const size_t i = ((size_t)blockIdx.x * 256 + threadIdx.x) * 8;
  float4 a = *(const float4*)(x + i);
  float4 b = *(const float4*)(x + i + 4);
  u16 us[8] = { f2b(a.x),f2b(a.y),f2b(a.z),f2b(a.w), f2b(b.x),f2b(b.y),f2b(b.z),f2b(b.w) };
  *(short8*)(xb + i) = *(short8*)us;
}

// ---------------------------------------------------------------- W[k][n] f32 -> Wt[n][k] bf16
__global__ __launch_bounds__(256) void wtrans(const float* __restrict__ W, u16* __restrict__ Wt) {
  __shared__ u16 tt[64][80];
  const int k0 = blockIdx.x << 6, n0 = blockIdx.y << 6;
  const int t = threadIdx.x;
  {
    const int r = t >> 4, c4 = (t & 15) << 2;
    for (int rr = r; rr < 64; rr += 16) {
      float4 v = *(const float4*)(W + (size_t)(k0 + rr) * D_ + n0 + c4);
      tt[c4+0][rr] = f2b(v.x); tt[c4+1][rr] = f2b(v.y);
      tt[c4+2][rr] = f2b(v.z); tt[c4+3][rr] = f2b(v.w);
    }
  }
  __syncthreads();
  const int n = t >> 2, kc = (t & 3) << 4;
  u16* dst = Wt + (size_t)(n0 + n) * D_ + k0 + kc;
  #pragma unroll
  for (int u = 0; u < 16; ++u) dst[u] = tt[n][kc + u];
}

// ---------------------------------------------------------------- bf16 MFMA GEMM, 128x128 tile, BK=64
// KIND 0: out-proj -> Cout fp32 [4096][1024]
// KIND 1: QKV (grid.y 0-7 Q rope, 8-15 K rope, 16-23 V -> V^T)
template<int KIND>
__global__ __launch_bounds__(256) void gemm_k(
    const u16* __restrict__ Ag, const u16* __restrict__ Bg,
    const float* __restrict__ b0, const float* __restrict__ b1, const float* __restrict__ b2,
    const float* __restrict__ costab, const float* __restrict__ sintab,
    u16* __restrict__ O0, u16* __restrict__ O1, u16* __restrict__ O2,
    float* __restrict__ Cout)
{
  __shared__ u16 As[8192];
  __shared__ u16 Bs[8192];
  const int t = threadIdx.x, w = t >> 6, lane = t & 63;
  const int lt = lane & 15, lg = lane >> 4;
  const int row0 = blockIdx.x << 7;
  const int gy   = blockIdx.y;
  const int col0 = gy << 7;                    // row offset into Bg (Wt rows)
  const int wm = (w & 1) << 6, wn = (w >> 1) << 6;
  const int proj = (KIND == 1) ? (gy >> 3) : 0;
  const bool swp = (KIND == 0) || (proj < 2);

  // staging constants: LDS (row, chunk c) holds global chunk c ^ (row&7)
  const int srow = lane >> 3;
  const int gch  = (lane & 7) ^ (srow & 7);
  const u16* aptr[4]; const u16* bptr[4];
  char* adst[4]; char* bdst[4];
  #pragma unroll
  for (int u = 0; u < 4; ++u) {
    const int rl = w * 32 + u * 8 + srow;
    aptr[u] = Ag + (size_t)(row0 + rl) * 1024 + gch * 8;
    bptr[u] = Bg + (size_t)(col0 + rl) * 1024 + gch * 8;
    adst[u] = (char*)As + (w * 32 + u * 8) * 128;
    bdst[u] = (char*)Bs + (w * 32 + u * 8) * 128;
  }
  int aoff[2][4], boff[2][4];
  #pragma unroll
  for (int ks = 0; ks < 2; ++ks)
    #pragma unroll
    for (int q = 0; q < 4; ++q) {
      const int ra = wm + q * 16 + lt;
      aoff[ks][q] = ra * 128 + (((ks * 4 + lg) ^ (ra & 7)) << 4);
      const int rb = wn + q * 16 + lt;
      boff[ks][q] = rb * 128 + (((ks * 4 + lg) ^ (rb & 7)) << 4);
    }

  f32x4 acc[4][4];
  #pragma unroll
  for (int i = 0; i < 4; ++i)
    #pragma unroll
    for (int j = 0; j < 4; ++j) acc[i][j] = (f32x4){0.f,0.f,0.f,0.f};

  auto loop = [&](auto SW) {
    for (int kt = 0; kt < 16; ++kt) {
      #pragma unroll
      for (int u = 0; u < 4; ++u) {
        gl_lds16(aptr[u] + kt * 64, adst[u]);
        gl_lds16(bptr[u] + kt * 64, bdst[u]);
      }
      __syncthreads();
      #pragma unroll
      for (int ks = 0; ks < 2; ++ks) {
        short8 af[4], bf[4];
        #pragma unroll
        for (int q = 0; q < 4; ++q) {
          af[q] = *(const short8*)((const char*)As + aoff[ks][q]);
          bf[q] = *(const short8*)((const char*)Bs + boff[ks][q]);
        }
        #pragma unroll
        for (int mi = 0; mi < 4; ++mi)
          #pragma unroll
          for (int nj = 0; nj < 4; ++nj) {
            if constexpr (decltype(SW)::value)
              acc[mi][nj] = __builtin_amdgcn_mfma_f32_16x16x32_bf16(bf[nj], af[mi], acc[mi][nj], 0, 0, 0);
            else
              acc[mi][nj] = __builtin_amdgcn_mfma_f32_16x16x32_bf16(af[mi], bf[nj], acc[mi][nj], 0, 0, 0);
          }
      }
      __syncthreads();
    }
  };
  if (swp) loop(BC<true>{}); else loop(BC<false>{});

  if constexpr (KIND == 0) {
    // swapped: lane holds fixed m (=lt), regs = 4 consecutive n
    #pragma unroll
    for (int mi = 0; mi < 4; ++mi) {
      const int m = row0 + wm + mi * 16 + lt;
      #pragma unroll
      for (int nj = 0; nj < 4; ++nj) {
        const int nb = col0 + wn + nj * 16 + (lg << 2);
        float4 bb = *(const float4*)(b0 + nb);
        float4 o = make_float4(acc[mi][nj][0] + bb.x, acc[mi][nj][1] + bb.y,
                               acc[mi][nj][2] + bb.z, acc[mi][nj][3] + bb.w);
        *(float4*)(Cout + (size_t)m * 1024 + nb) = o;
      }
    }
  } else if (proj < 2) {
    const float* bias = proj ? b1 : b0;
    u16* Ob = proj ? O1 : O0;
    const int col0p = (gy & 7) << 7;
    #pragma unroll
    for (int mi = 0; mi < 4; ++mi) {
      const int m = row0 + wm + mi * 16 + lt;
      const int bb_ = m >> 11, lpos = m & (L_ - 1);
      #pragma unroll
      for (int nj = 0; nj < 4; ++nj) {
        const int nb = col0p + wn + nj * 16 + (lg << 2);
        const int d0 = nb & 63, h = nb >> 6;
        float4 ba = *(const float4*)(bias + nb);
        const float o0 = acc[mi][nj][0] + ba.x, o1 = acc[mi][nj][1] + ba.y;
        const float o2 = acc[mi][nj][2] + ba.z, o3 = acc[mi][nj][3] + ba.w;
        const float* ct = costab + lpos * 32 + (d0 >> 1);
        const float* st = sintab + lpos * 32 + (d0 >> 1);
        const float c0 = ct[0], c1 = ct[1], s0 = st[0], s1 = st[1];
        const float r0 = o0 * c0 - o1 * s0, r1 = o0 * s0 + o1 * c0;
        const float r2 = o2 * c1 - o3 * s1, r3 = o2 * s1 + o3 * c1;
        *(u16x4*)(Ob + ((size_t)(bb_ * 16 + h) * L_ + lpos) * 64 + d0) = f2b4(r0, r1, r2, r3);
      }
    }
  } else {
    // V: normal order, lane holds fixed n (=lt), regs = 4 consecutive tokens -> V^T [bh][64][L]
    const int col0p = (gy & 7) << 7;
    #pragma unroll
    for (int mi = 0; mi < 4; ++mi) {
      const int lb = row0 + wm + mi * 16 + (lg << 2);
      const int bb_ = lb >> 11;
      #pragma unroll
      for (int nj = 0; nj < 4; ++nj) {
        const int n = col0p + wn + nj * 16 + lt;
        const int h = n >> 6, dh = n & 63;
        const float bv1 = b2[n];
        *(u16x4*)(O2 + ((size_t)(bb_ * 16 + h) * 64 + dh) * L_ + (lb & (L_ - 1))) =
            f2b4(acc[mi][nj][0] + bv1, acc[mi][nj][1] + bv1,
                 acc[mi][nj][2] + bv1, acc[mi][nj][3] + bv1);
      }
    }
  }
}

// ---------------------------------------------------------------- MFMA attention (swapped QK^T)
__global__ __launch_bounds__(256) void attn_mfma(
    const u16* __restrict__ Qb, const u16* __restrict__ Kb, const u16* __restrict__ Vt,
    const float* __restrict__ pblg, float* __restrict__ Pout,
    u16* __restrict__ AOb, float* __restrict__ lrow)
{
  __shared__ u16 Pb[4][1024];
  __shared__ float pbl[2048];
  const int t = threadIdx.x, w = t >> 6, lane = t & 63;
  const int lt = lane & 15, lg = lane >> 4;
  {
    const int i8 = t * 8;
    *(float4*)(pbl + i8)     = *(const float4*)(pblg + i8);
    *(float4*)(pbl + i8 + 4) = *(const float4*)(pblg + i8 + 4);
  }
  const int bh = blockIdx.y, b = bh >> 4, h = bh & 15;
  const int itx = blockIdx.x;
  const int it = (itx & 1) ? (31 - (itx >> 1)) : (itx >> 1);
  const int i0 = it << 6;
  __syncthreads();

  const u16* qp = Qb + ((size_t)bh * L_ + i0 + w * 16 + lt) * 64 + lg * 8;
  const short8 qf0 = *(const short8*)(qp);
  const short8 qf1 = *(const short8*)(qp + 32);
  const int i = i0 + w * 16 + lt;   // this lane's q-row

  f32x4 oacc[4];
  #pragma unroll
  for (int dt = 0; dt < 4; ++dt) oacc[dt] = (f32x4){0.f,0.f,0.f,0.f};
  f32x4 lsacc = (f32x4){0.f,0.f,0.f,0.f};

  short8 ones;
  #pragma unroll
  for (int e = 0; e < 8; ++e) ones[e] = (short)0x3F80;

  char* pbase = (char*)(&Pb[w][0]);
  const int swz = (lt & 7) << 4;
  const float C1 = 0.18033688011112042f;   // 0.125 * log2(e)

  for (int kvt = 0; kvt <= it; ++kvt) {
    const int j0 = kvt << 6;
    const u16* kp = Kb + ((size_t)bh * L_ + j0 + lt) * 64 + lg * 8;

    #pragma unroll
    for (int jt = 0; jt < 4; ++jt) {
      short8 kf0 = *(const short8*)(kp + jt * 1024);
      short8 kf1 = *(const short8*)(kp + jt * 1024 + 32);
      f32x4 z = (f32x4){0.f,0.f,0.f,0.f};
      z = __builtin_amdgcn_mfma_f32_16x16x32_bf16(kf0, qf0, z, 0, 0, 0);
      z = __builtin_amdgcn_mfma_f32_16x16x32_bf16(kf1, qf1, z, 0, 0, 0);
      // z rows: j = j0 + jt*16 + lg*4 + r ; col: i
      const int jb = j0 + jt * 16 + (lg << 2);
      const int dd = i - jb;
      float pr[4];
      #pragma unroll
      for (int r = 0; r < 4; ++r) {
        const int d  = dd - r;
        const int dc = d < 0 ? 0 : d;
        float pe = exp2f(fmaf(z[r], C1, pbl[dc]));
        pr[r] = d < 0 ? 0.f : pe;
      }
      *(float4*)(Pout + ((size_t)bh * L_ + i) * L_ + jb) = make_float4(pr[0], pr[1], pr[2], pr[3]);
      *(u16x4*)(pbase + lt * 128 + ((jt * 32 + lg * 8) ^ swz)) = f2b4(pr[0], pr[1], pr[2], pr[3]);
    }

    // PV (per-wave LDS region, no barrier)
    short8 pa0 = *(const short8*)(pbase + lt * 128 + ((lg * 16) ^ swz));
    short8 pa1 = *(const short8*)(pbase + lt * 128 + ((64 + lg * 16) ^ swz));
    lsacc = __builtin_amdgcn_mfma_f32_16x16x32_bf16(pa0, ones, lsacc, 0, 0, 0);
    lsacc = __builtin_amdgcn_mfma_f32_16x16x32_bf16(pa1, ones, lsacc, 0, 0, 0);
    const u16* vp = Vt + ((size_t)bh * 64 + lt) * L_ + j0 + lg * 8;
    #pragma unroll
    for (int dt = 0; dt < 4; ++dt) {
      short8 vf0 = *(const short8*)(vp + dt * 16 * L_);
      short8 vf1 = *(const short8*)(vp + dt * 16 * L_ + 32);
      oacc[dt] = __builtin_amdgcn_mfma_f32_16x16x32_bf16(pa0, vf0, oacc[dt], 0, 0, 0);
      oacc[dt] = __builtin_amdgcn_mfma_f32_16x16x32_bf16(pa1, vf1, oacc[dt], 0, 0, 0);
    }
  }

  // epilogue: rows ig = i0 + w*16 + lg*4 + r
  #pragma unroll
  for (int r = 0; r < 4; ++r) {
    const int irow = i0 + w * 16 + (lg << 2) + r;
    const float ls = lsacc[r];
    if (lt == 0) lrow[(size_t)bh * L_ + irow] = ls;
    const float rinv = 1.f / ls;
    u16* ao = AOb + ((size_t)(b * L_ + irow)) * 1024 + h * 64 + lt;
    #pragma unroll
    for (int dt = 0; dt < 4; ++dt) ao[dt * 16] = f2b(oacc[dt][r] * rinv);
  }
}

// ---------------------------------------------------------------- normalize P rows + zero upper triangle
__global__ __launch_bounds__(256) void rescale_p(float* __restrict__ P, const float* __restrict__ lrow) {
  const int row = blockIdx.x;
  const int i   = row & (L_ - 1);
  const float rinv = 1.f / lrow[row];
  float4* pr = (float4*)(P + (size_t)row * L_);
  const int lim = i >> 2;
  for (int c4 = threadIdx.x; c4 < L_/4; c4 += 256) {
    if (c4 < lim) {
      float4 v = pr[c4];
      v.x *= rinv; v.y *= rinv; v.z *= rinv; v.w *= rinv;
      pr[c4] = v;
    } else if (c4 == lim) {
      float4 v = pr[c4];
      const int j = c4 << 2;
      v.x = (j     <= i) ? v.x*rinv : 0.f;
      v.y = (j + 1 <= i) ? v.y*rinv : 0.f;
      v.z = (j + 2 <= i) ? v.z*rinv : 0.f;
      v.w = (j + 3 <= i) ? v.w*rinv : 0.f;
      pr[c4] = v;
    } else {
      pr[c4] = make_float4(0.f, 0.f, 0.f, 0.f);
    }
  }
}

// ---------------------------------------------------------------- launch
extern "C" void kernel_launch(void* const* d_in, const int* in_sizes, int n_in,
                              void* d_out, int out_size, void* d_ws, size_t ws_size,
                              hipStream_t stream) {
  const float* x  = (const float*)d_in[0];
  const float* Wq = (const float*)d_in[1];
  const float* bq = (const float*)d_in[2];
  const float* Wk = (const float*)d_in[3];
  const float* bk = (const float*)d_in[4];
  const float* Wv = (const float*)d_in[5];
  const float* bv = (const float*)d_in[6];
  const float* Wo = (const float*)d_in[7];
  const float* bo = (const float*)d_in[8];

  float* out  = (float*)d_out;
  float* Pout = out + (size_t)BL_ * D_;

  float* ws = (float*)d_ws;
  u16* XB  = (u16*)(ws + WS_XB);
  u16* WT4 = (u16*)(ws + WS_WT4);
  u16* QB  = (u16*)(ws + WS_QB);
  u16* KB  = (u16*)(ws + WS_KB);
  u16* VT  = (u16*)(ws + WS_VT);
  u16* AOB = (u16*)(ws + WS_AOB);
  float* cosT = ws + WS_COS;
  float* sinT = ws + WS_SIN;
  float* pblG = ws + WS_PBL;
  float* lw   = ws + WS_LROW;

  fill_tables<<<256, 256, 0, stream>>>(cosT, sinT, pblG);
  xcast<<<2048, 256, 0, stream>>>(x, XB);
  wtrans<<<dim3(16,16), 256, 0, stream>>>(Wq, WT4);
  wtrans<<<dim3(16,16), 256, 0, stream>>>(Wk, WT4 + (size_t)1024*1024);
  wtrans<<<dim3(16,16), 256, 0, stream>>>(Wv, WT4 + (size_t)2*1024*1024);
  wtrans<<<dim3(16,16), 256, 0, stream>>>(Wo, WT4 + (size_t)3*1024*1024);

  gemm_k<1><<<dim3(32,24), 256, 0, stream>>>(XB, WT4, bq, bk, bv, cosT, sinT,
                                             QB, KB, VT, nullptr);

  attn_mfma<<<dim3(32,32), 256, 0, stream>>>(QB, KB, VT, pblG, Pout, AOB, lw);

  rescale_p<<<B_*H_*L_, 256, 0, stream>>>(Pout, lw);

  gemm_k<0><<<dim3(32,8), 256, 0, stream>>>(AOB, WT4 + (size_t)3*1024*1024, bo,
                                            nullptr, nullptr, nullptr, nullptr,
                                            nullptr, nullptr, nullptr, out);
}

// Round 5
// 465.549 us; speedup vs baseline: 14.4246x; 1.1213x over previous
//
#include <hip/hip_runtime.h>
#include <math.h>

#define B_  2
#define L_  2048
#define D_  1024
#define H_  16
#define DH_ 64
#define BL_ (B_*L_)   // 4096

typedef unsigned short u16;
typedef __attribute__((ext_vector_type(8))) short short8;
typedef __attribute__((ext_vector_type(4))) float f32x4;
typedef __attribute__((ext_vector_type(4))) unsigned short u16x4;

template<bool V> struct BC { static constexpr bool value = V; };

// ---- workspace offsets (floats) -- each bf16 [4096][1024]-sized buffer = 2,097,152 floats
#define WS_XB   0            // x bf16 [4096][1024]
#define WS_WT4  2097152      // Wt bf16 [4][1024][1024]
#define WS_QB   4194304      // [32][2048][64] bf16
#define WS_KB   6291456
#define WS_VT   8388608      // [32][64][2048] bf16
#define WS_AOB  10485760     // AO bf16 [4096][1024]
#define WS_COS  12582912     // [2048][32] f32
#define WS_SIN  12648448
#define WS_PBL  12713984     // [2048] f32 (pre-scaled by log2e)
// end ~12.72M floats ~ 50.9 MB

__device__ __forceinline__ u16 f2b(float f) {
  union { float f; unsigned u; } v; v.f = f;
  unsigned r = (v.u + 0x7fffu + ((v.u >> 16) & 1u)) >> 16;
  return (u16)r;
}
__device__ __forceinline__ u16x4 f2b4(float a, float b, float c, float d) {
  u16x4 u; u.x = f2b(a); u.y = f2b(b); u.z = f2b(c); u.w = f2b(d); return u;
}
__device__ __forceinline__ void gl_lds16(const void* g, void* l) {
  __builtin_amdgcn_global_load_lds(
      (const __attribute__((address_space(1))) unsigned int*)g,
      (__attribute__((address_space(3))) unsigned int*)l, 16, 0, 0);
}

// ---------------------------------------------------------------- tables
__global__ void fill_tables(float* __restrict__ costab, float* __restrict__ sintab,
                            float* __restrict__ pbl) {
  int idx = blockIdx.x * 256 + threadIdx.x;
  if (idx < L_ * 32) {
    int l = idx >> 5, tp = idx & 31;
    double inv = pow(10000.0, -2.0 * (double)tp / 64.0);
    double th  = (double)l * inv;
    costab[idx] = (float)cos(th);
    sintab[idx] = (float)sin(th);
  }
  if (idx < L_) {
    double d = (double)idx;
    double v = 0.5  * cos(6.283185307179586 * d / 24.0)
             + 0.25 * cos(6.283185307179586 * d / 168.0);
    pbl[idx] = (float)(v * 1.4426950408889634);
  }
}

// ---------------------------------------------------------------- x -> bf16
__global__ __launch_bounds__(256) void xcast(const float* __restrict__ x, u16* __restrict__ xb) {
  const size_t i = ((size_t)blockIdx.x * 256 + threadIdx.x) * 8;
  float4 a = *(const float4*)(x + i);
  float4 b = *(const float4*)(x + i + 4);
  u16 us[8] = { f2b(a.x),f2b(a.y),f2b(a.z),f2b(a.w), f2b(b.x),f2b(b.y),f2b(b.z),f2b(b.w) };
  *(short8*)(xb + i) = *(short8*)us;
}

// ---------------------------------------------------------------- W[k][n] f32 -> Wt[n][k] bf16 (4 weights, z-indexed)
__global__ __launch_bounds__(256) void wtrans4(const float* __restrict__ W0, const float* __restrict__ W1,
                                               const float* __restrict__ W2, const float* __restrict__ W3,
                                               u16* __restrict__ Wt) {
  __shared__ u16 tt[64][80];
  const int z = blockIdx.z;
  const float* W = (z == 0) ? W0 : (z == 1) ? W1 : (z == 2) ? W2 : W3;
  u16* Wtz = Wt + (size_t)z * 1024 * 1024;
  const int k0 = blockIdx.x << 6, n0 = blockIdx.y << 6;
  const int t = threadIdx.x;
  {
    const int r = t >> 4, c4 = (t & 15) << 2;
    for (int rr = r; rr < 64; rr += 16) {
      float4 v = *(const float4*)(W + (size_t)(k0 + rr) * D_ + n0 + c4);
      tt[c4+0][rr] = f2b(v.x); tt[c4+1][rr] = f2b(v.y);
      tt[c4+2][rr] = f2b(v.z); tt[c4+3][rr] = f2b(v.w);
    }
  }
  __syncthreads();
  const int n = t >> 2, kc = (t & 3) << 4;
  u16* dst = Wtz + (size_t)(n0 + n) * D_ + k0 + kc;
  #pragma unroll
  for (int u = 0; u < 16; ++u) dst[u] = tt[n][kc + u];
}

// ---------------------------------------------------------------- bf16 MFMA GEMM, 128x128 tile, BK=64
// KIND 0: out-proj -> Cout fp32 [4096][1024]
// KIND 1: QKV (grid.y 0-7 Q rope, 8-15 K rope, 16-23 V -> V^T)
template<int KIND>
__global__ __launch_bounds__(256) void gemm_k(
    const u16* __restrict__ Ag, const u16* __restrict__ Bg,
    const float* __restrict__ b0, const float* __restrict__ b1, const float* __restrict__ b2,
    const float* __restrict__ costab, const float* __restrict__ sintab,
    u16* __restrict__ O0, u16* __restrict__ O1, u16* __restrict__ O2,
    float* __restrict__ Cout)
{
  __shared__ u16 As[8192];
  __shared__ u16 Bs[8192];
  const int t = threadIdx.x, w = t >> 6, lane = t & 63;
  const int lt = lane & 15, lg = lane >> 4;
  const int row0 = blockIdx.x << 7;
  const int gy   = blockIdx.y;
  const int col0 = gy << 7;
  const int wm = (w & 1) << 6, wn = (w >> 1) << 6;
  const int proj = (KIND == 1) ? (gy >> 3) : 0;
  const bool swp = (KIND == 0) || (proj < 2);

  const int srow = lane >> 3;
  const int gch  = (lane & 7) ^ (srow & 7);
  const u16* aptr[4]; const u16* bptr[4];
  char* adst[4]; char* bdst[4];
  #pragma unroll
  for (int u = 0; u < 4; ++u) {
    const int rl = w * 32 + u * 8 + srow;
    aptr[u] = Ag + (size_t)(row0 + rl) * 1024 + gch * 8;
    bptr[u] = Bg + (size_t)(col0 + rl) * 1024 + gch * 8;
    adst[u] = (char*)As + (w * 32 + u * 8) * 128;
    bdst[u] = (char*)Bs + (w * 32 + u * 8) * 128;
  }
  int aoff[2][4], boff[2][4];
  #pragma unroll
  for (int ks = 0; ks < 2; ++ks)
    #pragma unroll
    for (int q = 0; q < 4; ++q) {
      const int ra = wm + q * 16 + lt;
      aoff[ks][q] = ra * 128 + (((ks * 4 + lg) ^ (ra & 7)) << 4);
      const int rb = wn + q * 16 + lt;
      boff[ks][q] = rb * 128 + (((ks * 4 + lg) ^ (rb & 7)) << 4);
    }

  f32x4 acc[4][4];
  #pragma unroll
  for (int i = 0; i < 4; ++i)
    #pragma unroll
    for (int j = 0; j < 4; ++j) acc[i][j] = (f32x4){0.f,0.f,0.f,0.f};

  auto loop = [&](auto SW) {
    for (int kt = 0; kt < 16; ++kt) {
      #pragma unroll
      for (int u = 0; u < 4; ++u) {
        gl_lds16(aptr[u] + kt * 64, adst[u]);
        gl_lds16(bptr[u] + kt * 64, bdst[u]);
      }
      __syncthreads();
      #pragma unroll
      for (int ks = 0; ks < 2; ++ks) {
        short8 af[4], bf[4];
        #pragma unroll
        for (int q = 0; q < 4; ++q) {
          af[q] = *(const short8*)((const char*)As + aoff[ks][q]);
          bf[q] = *(const short8*)((const char*)Bs + boff[ks][q]);
        }
        #pragma unroll
        for (int mi = 0; mi < 4; ++mi)
          #pragma unroll
          for (int nj = 0; nj < 4; ++nj) {
            if constexpr (decltype(SW)::value)
              acc[mi][nj] = __builtin_amdgcn_mfma_f32_16x16x32_bf16(bf[nj], af[mi], acc[mi][nj], 0, 0, 0);
            else
              acc[mi][nj] = __builtin_amdgcn_mfma_f32_16x16x32_bf16(af[mi], bf[nj], acc[mi][nj], 0, 0, 0);
          }
      }
      __syncthreads();
    }
  };
  if (swp) loop(BC<true>{}); else loop(BC<false>{});

  if constexpr (KIND == 0) {
    #pragma unroll
    for (int mi = 0; mi < 4; ++mi) {
      const int m = row0 + wm + mi * 16 + lt;
      #pragma unroll
      for (int nj = 0; nj < 4; ++nj) {
        const int nb = col0 + wn + nj * 16 + (lg << 2);
        float4 bb = *(const float4*)(b0 + nb);
        float4 o = make_float4(acc[mi][nj][0] + bb.x, acc[mi][nj][1] + bb.y,
                               acc[mi][nj][2] + bb.z, acc[mi][nj][3] + bb.w);
        *(float4*)(Cout + (size_t)m * 1024 + nb) = o;
      }
    }
  } else if (proj < 2) {
    const float* bias = proj ? b1 : b0;
    u16* Ob = proj ? O1 : O0;
    const int col0p = (gy & 7) << 7;
    #pragma unroll
    for (int mi = 0; mi < 4; ++mi) {
      const int m = row0 + wm + mi * 16 + lt;
      const int bb_ = m >> 11, lpos = m & (L_ - 1);
      #pragma unroll
      for (int nj = 0; nj < 4; ++nj) {
        const int nb = col0p + wn + nj * 16 + (lg << 2);
        const int d0 = nb & 63, h = nb >> 6;
        float4 ba = *(const float4*)(bias + nb);
        const float o0 = acc[mi][nj][0] + ba.x, o1 = acc[mi][nj][1] + ba.y;
        const float o2 = acc[mi][nj][2] + ba.z, o3 = acc[mi][nj][3] + ba.w;
        const float* ct = costab + lpos * 32 + (d0 >> 1);
        const float* st = sintab + lpos * 32 + (d0 >> 1);
        const float c0 = ct[0], c1 = ct[1], s0 = st[0], s1 = st[1];
        const float r0 = o0 * c0 - o1 * s0, r1 = o0 * s0 + o1 * c0;
        const float r2 = o2 * c1 - o3 * s1, r3 = o2 * s1 + o3 * c1;
        *(u16x4*)(Ob + ((size_t)(bb_ * 16 + h) * L_ + lpos) * 64 + d0) = f2b4(r0, r1, r2, r3);
      }
    }
  } else {
    const int col0p = (gy & 7) << 7;
    #pragma unroll
    for (int mi = 0; mi < 4; ++mi) {
      const int lb = row0 + wm + mi * 16 + (lg << 2);
      const int bb_ = lb >> 11;
      #pragma unroll
      for (int nj = 0; nj < 4; ++nj) {
        const int n = col0p + wn + nj * 16 + lt;
        const int h = n >> 6, dh = n & 63;
        const float bv1 = b2[n];
        *(u16x4*)(O2 + ((size_t)(bb_ * 16 + h) * 64 + dh) * L_ + (lb & (L_ - 1))) =
            f2b4(acc[mi][nj][0] + bv1, acc[mi][nj][1] + bv1,
                 acc[mi][nj][2] + bv1, acc[mi][nj][3] + bv1);
      }
    }
  }
}

// ---------------------------------------------------------------- MFMA attention, fused normalization
// Two passes over kvt: pass1 row-sums (fp32), pass2 normalized P write + PV.
// Also zeroes this block's upper-triangle stripe of P.
__global__ __launch_bounds__(256) void attn_mfma(
    const u16* __restrict__ Qb, const u16* __restrict__ Kb, const u16* __restrict__ Vt,
    const float* __restrict__ pblg, float* __restrict__ Pout, u16* __restrict__ AOb)
{
  __shared__ u16 Pb[4][1024];
  __shared__ float pbl[2048];
  const int t = threadIdx.x, w = t >> 6, lane = t & 63;
  const int lt = lane & 15, lg = lane >> 4;
  {
    const int i8 = t * 8;
    *(float4*)(pbl + i8)     = *(const float4*)(pblg + i8);
    *(float4*)(pbl + i8 + 4) = *(const float4*)(pblg + i8 + 4);
  }
  const int bh = blockIdx.y, b = bh >> 4, h = bh & 15;
  const int itx = blockIdx.x;
  const int it = (itx & 1) ? (31 - (itx >> 1)) : (itx >> 1);
  const int i0 = it << 6;
  __syncthreads();

  const u16* qp = Qb + ((size_t)bh * L_ + i0 + w * 16 + lt) * 64 + lg * 8;
  const short8 qf0 = *(const short8*)(qp);
  const short8 qf1 = *(const short8*)(qp + 32);
  const int i = i0 + w * 16 + lt;   // this lane's q-row

  char* pbase = (char*)(&Pb[w][0]);
  const int swz = (lt & 7) << 4;
  const float C1 = 0.18033688011112042f;   // 0.125 * log2(e)

  // ---- pass 1: fp32 row-sum
  float lsum = 0.f;
  for (int kvt = 0; kvt <= it; ++kvt) {
    const int j0 = kvt << 6;
    const u16* kp = Kb + ((size_t)bh * L_ + j0 + lt) * 64 + lg * 8;
    #pragma unroll
    for (int jt = 0; jt < 4; ++jt) {
      short8 kf0 = *(const short8*)(kp + jt * 1024);
      short8 kf1 = *(const short8*)(kp + jt * 1024 + 32);
      f32x4 z = (f32x4){0.f,0.f,0.f,0.f};
      z = __builtin_amdgcn_mfma_f32_16x16x32_bf16(kf0, qf0, z, 0, 0, 0);
      z = __builtin_amdgcn_mfma_f32_16x16x32_bf16(kf1, qf1, z, 0, 0, 0);
      const int jb = j0 + jt * 16 + (lg << 2);
      const int dd = i - jb;
      #pragma unroll
      for (int r = 0; r < 4; ++r) {
        const int d  = dd - r;
        const int dc = d < 0 ? 0 : d;
        const float pe = exp2f(fmaf(z[r], C1, pbl[dc]));
        if (d >= 0) lsum += pe;
      }
    }
  }
  lsum += __shfl_xor(lsum, 16);
  lsum += __shfl_xor(lsum, 32);
  const float rinv = 1.f / lsum;

  // ---- pass 2: normalized P write + PV
  f32x4 oacc[4];
  #pragma unroll
  for (int dt = 0; dt < 4; ++dt) oacc[dt] = (f32x4){0.f,0.f,0.f,0.f};

  for (int kvt = 0; kvt <= it; ++kvt) {
    const int j0 = kvt << 6;
    const u16* kp = Kb + ((size_t)bh * L_ + j0 + lt) * 64 + lg * 8;
    #pragma unroll
    for (int jt = 0; jt < 4; ++jt) {
      short8 kf0 = *(const short8*)(kp + jt * 1024);
      short8 kf1 = *(const short8*)(kp + jt * 1024 + 32);
      f32x4 z = (f32x4){0.f,0.f,0.f,0.f};
      z = __builtin_amdgcn_mfma_f32_16x16x32_bf16(kf0, qf0, z, 0, 0, 0);
      z = __builtin_amdgcn_mfma_f32_16x16x32_bf16(kf1, qf1, z, 0, 0, 0);
      const int jb = j0 + jt * 16 + (lg << 2);
      const int dd = i - jb;
      float pr[4];
      #pragma unroll
      for (int r = 0; r < 4; ++r) {
        const int d  = dd - r;
        const int dc = d < 0 ? 0 : d;
        float pe = exp2f(fmaf(z[r], C1, pbl[dc])) * rinv;
        pr[r] = d < 0 ? 0.f : pe;
      }
      *(float4*)(Pout + ((size_t)bh * L_ + i) * L_ + jb) = make_float4(pr[0], pr[1], pr[2], pr[3]);
      *(u16x4*)(pbase + lt * 128 + ((jt * 32 + lg * 8) ^ swz)) = f2b4(pr[0], pr[1], pr[2], pr[3]);
    }

    short8 pa0 = *(const short8*)(pbase + lt * 128 + ((lg * 16) ^ swz));
    short8 pa1 = *(const short8*)(pbase + lt * 128 + ((64 + lg * 16) ^ swz));
    const u16* vp = Vt + ((size_t)bh * 64 + lt) * L_ + j0 + lg * 8;
    #pragma unroll
    for (int dt = 0; dt < 4; ++dt) {
      short8 vf0 = *(const short8*)(vp + dt * 16 * L_);
      short8 vf1 = *(const short8*)(vp + dt * 16 * L_ + 32);
      oacc[dt] = __builtin_amdgcn_mfma_f32_16x16x32_bf16(pa0, vf0, oacc[dt], 0, 0, 0);
      oacc[dt] = __builtin_amdgcn_mfma_f32_16x16x32_bf16(pa1, vf1, oacc[dt], 0, 0, 0);
    }
  }

  // ---- zero upper-triangle stripe: rows i0..i0+63, cols (it+1)*64 .. 2047
  {
    const int zc0 = (it + 1) << 4;               // first float4 index
    float4* prow = (float4*)(Pout + ((size_t)bh * L_ + i0 + (t >> 2)) * L_);
    const float4 zz = make_float4(0.f, 0.f, 0.f, 0.f);
    for (int c4 = zc0 + (t & 3); c4 < 512; c4 += 4) prow[c4] = zz;
  }

  // ---- epilogue: AO (already normalized)
  #pragma unroll
  for (int r = 0; r < 4; ++r) {
    const int irow = i0 + w * 16 + (lg << 2) + r;
    u16* ao = AOb + ((size_t)(b * L_ + irow)) * 1024 + h * 64 + lt;
    #pragma unroll
    for (int dt = 0; dt < 4; ++dt) ao[dt * 16] = f2b(oacc[dt][r]);
  }
}

// ---------------------------------------------------------------- launch
extern "C" void kernel_launch(void* const* d_in, const int* in_sizes, int n_in,
                              void* d_out, int out_size, void* d_ws, size_t ws_size,
                              hipStream_t stream) {
  const float* x  = (const float*)d_in[0];
  const float* Wq = (const float*)d_in[1];
  const float* bq = (const float*)d_in[2];
  const float* Wk = (const float*)d_in[3];
  const float* bk = (const float*)d_in[4];
  const float* Wv = (const float*)d_in[5];
  const float* bv = (const float*)d_in[6];
  const float* Wo = (const float*)d_in[7];
  const float* bo = (const float*)d_in[8];

  float* out  = (float*)d_out;
  float* Pout = out + (size_t)BL_ * D_;

  float* ws = (float*)d_ws;
  u16* XB  = (u16*)(ws + WS_XB);
  u16* WT4 = (u16*)(ws + WS_WT4);
  u16* QB  = (u16*)(ws + WS_QB);
  u16* KB  = (u16*)(ws + WS_KB);
  u16* VT  = (u16*)(ws + WS_VT);
  u16* AOB = (u16*)(ws + WS_AOB);
  float* cosT = ws + WS_COS;
  float* sinT = ws + WS_SIN;
  float* pblG = ws + WS_PBL;

  fill_tables<<<256, 256, 0, stream>>>(cosT, sinT, pblG);
  xcast<<<2048, 256, 0, stream>>>(x, XB);
  wtrans4<<<dim3(16,16,4), 256, 0, stream>>>(Wq, Wk, Wv, Wo, WT4);

  gemm_k<1><<<dim3(32,24), 256, 0, stream>>>(XB, WT4, bq, bk, bv, cosT, sinT,
                                             QB, KB, VT, nullptr);

  attn_mfma<<<dim3(32,32), 256, 0, stream>>>(QB, KB, VT, pblG, Pout, AOB);

  gemm_k<0><<<dim3(32,8), 256, 0, stream>>>(AOB, WT4 + (size_t)3*1024*1024, bo,
                                            nullptr, nullptr, nullptr, nullptr,
                                            nullptr, nullptr, nullptr, out);
}

// Round 6
// 433.218 us; speedup vs baseline: 15.5010x; 1.0746x over previous
//
#include <hip/hip_runtime.h>
#include <math.h>

#define B_  2
#define L_  2048
#define D_  1024
#define H_  16
#define DH_ 64
#define BL_ (B_*L_)   // 4096

typedef unsigned short u16;
typedef __attribute__((ext_vector_type(8))) short short8;
typedef __attribute__((ext_vector_type(4))) float f32x4;
typedef __attribute__((ext_vector_type(4))) unsigned short u16x4;

template<bool V> struct BC { static constexpr bool value = V; };

// ---- workspace offsets (floats) -- each bf16 [4096][1024]-sized buffer = 2,097,152 floats
#define WS_XB   0            // x bf16 [4096][1024]
#define WS_WT4  2097152      // Wt bf16 [4][1024][1024]
#define WS_QB   4194304      // [32][2048][64] bf16
#define WS_KB   6291456
#define WS_VT   8388608      // [32][64][2048] bf16
#define WS_AOB  10485760     // AO bf16 [4096][1024]
#define WS_COS  12582912     // [2048][32] f32
#define WS_SIN  12648448
#define WS_PBL  12713984     // [2048] f32 (pre-scaled by log2e)
// end ~12.72M floats ~ 50.9 MB

__device__ __forceinline__ u16 f2b(float f) {
  union { float f; unsigned u; } v; v.f = f;
  unsigned r = (v.u + 0x7fffu + ((v.u >> 16) & 1u)) >> 16;
  return (u16)r;
}
__device__ __forceinline__ u16x4 f2b4(float a, float b, float c, float d) {
  u16x4 u; u.x = f2b(a); u.y = f2b(b); u.z = f2b(c); u.w = f2b(d); return u;
}
__device__ __forceinline__ void gl_lds16(const void* g, void* l) {
  __builtin_amdgcn_global_load_lds(
      (const __attribute__((address_space(1))) unsigned int*)g,
      (__attribute__((address_space(3))) unsigned int*)l, 16, 0, 0);
}

// ---------------------------------------------------------------- tables
__global__ void fill_tables(float* __restrict__ costab, float* __restrict__ sintab,
                            float* __restrict__ pbl) {
  int idx = blockIdx.x * 256 + threadIdx.x;
  if (idx < L_ * 32) {
    int l = idx >> 5, tp = idx & 31;
    double inv = pow(10000.0, -2.0 * (double)tp / 64.0);
    double th  = (double)l * inv;
    costab[idx] = (float)cos(th);
    sintab[idx] = (float)sin(th);
  }
  if (idx < L_) {
    double d = (double)idx;
    double v = 0.5  * cos(6.283185307179586 * d / 24.0)
             + 0.25 * cos(6.283185307179586 * d / 168.0);
    pbl[idx] = (float)(v * 1.4426950408889634);
  }
}

// ---------------------------------------------------------------- x -> bf16
__global__ __launch_bounds__(256) void xcast(const float* __restrict__ x, u16* __restrict__ xb) {
  const size_t i = ((size_t)blockIdx.x * 256 + threadIdx.x) * 8;
  float4 a = *(const float4*)(x + i);
  float4 b = *(const float4*)(x + i + 4);
  u16 us[8] = { f2b(a.x),f2b(a.y),f2b(a.z),f2b(a.w), f2b(b.x),f2b(b.y),f2b(b.z),f2b(b.w) };
  *(short8*)(xb + i) = *(short8*)us;
}

// ---------------------------------------------------------------- W[k][n] f32 -> Wt[n][k] bf16 (4 weights, z-indexed)
__global__ __launch_bounds__(256) void wtrans4(const float* __restrict__ W0, const float* __restrict__ W1,
                                               const float* __restrict__ W2, const float* __restrict__ W3,
                                               u16* __restrict__ Wt) {
  __shared__ u16 tt[64][80];
  const int z = blockIdx.z;
  const float* W = (z == 0) ? W0 : (z == 1) ? W1 : (z == 2) ? W2 : W3;
  u16* Wtz = Wt + (size_t)z * 1024 * 1024;
  const int k0 = blockIdx.x << 6, n0 = blockIdx.y << 6;
  const int t = threadIdx.x;
  {
    const int r = t >> 4, c4 = (t & 15) << 2;
    for (int rr = r; rr < 64; rr += 16) {
      float4 v = *(const float4*)(W + (size_t)(k0 + rr) * D_ + n0 + c4);
      tt[c4+0][rr] = f2b(v.x); tt[c4+1][rr] = f2b(v.y);
      tt[c4+2][rr] = f2b(v.z); tt[c4+3][rr] = f2b(v.w);
    }
  }
  __syncthreads();
  const int n = t >> 2, kc = (t & 3) << 4;
  u16* dst = Wtz + (size_t)(n0 + n) * D_ + k0 + kc;
  #pragma unroll
  for (int u = 0; u < 16; ++u) dst[u] = tt[n][kc + u];
}

// ---------------------------------------------------------------- bf16 MFMA GEMM, 128x128 tile, BK=64
// KIND 0: out-proj -> Cout fp32 [4096][1024]
// KIND 1: QKV (grid.y 0-7 Q rope, 8-15 K rope, 16-23 V -> V^T)
template<int KIND>
__global__ __launch_bounds__(256) void gemm_k(
    const u16* __restrict__ Ag, const u16* __restrict__ Bg,
    const float* __restrict__ b0, const float* __restrict__ b1, const float* __restrict__ b2,
    const float* __restrict__ costab, const float* __restrict__ sintab,
    u16* __restrict__ O0, u16* __restrict__ O1, u16* __restrict__ O2,
    float* __restrict__ Cout)
{
  __shared__ u16 As[8192];
  __shared__ u16 Bs[8192];
  const int t = threadIdx.x, w = t >> 6, lane = t & 63;
  const int lt = lane & 15, lg = lane >> 4;
  const int row0 = blockIdx.x << 7;
  const int gy   = blockIdx.y;
  const int col0 = gy << 7;
  const int wm = (w & 1) << 6, wn = (w >> 1) << 6;
  const int proj = (KIND == 1) ? (gy >> 3) : 0;
  const bool swp = (KIND == 0) || (proj < 2);

  const int srow = lane >> 3;
  const int gch  = (lane & 7) ^ (srow & 7);
  const u16* aptr[4]; const u16* bptr[4];
  char* adst[4]; char* bdst[4];
  #pragma unroll
  for (int u = 0; u < 4; ++u) {
    const int rl = w * 32 + u * 8 + srow;
    aptr[u] = Ag + (size_t)(row0 + rl) * 1024 + gch * 8;
    bptr[u] = Bg + (size_t)(col0 + rl) * 1024 + gch * 8;
    adst[u] = (char*)As + (w * 32 + u * 8) * 128;
    bdst[u] = (char*)Bs + (w * 32 + u * 8) * 128;
  }
  int aoff[2][4], boff[2][4];
  #pragma unroll
  for (int ks = 0; ks < 2; ++ks)
    #pragma unroll
    for (int q = 0; q < 4; ++q) {
      const int ra = wm + q * 16 + lt;
      aoff[ks][q] = ra * 128 + (((ks * 4 + lg) ^ (ra & 7)) << 4);
      const int rb = wn + q * 16 + lt;
      boff[ks][q] = rb * 128 + (((ks * 4 + lg) ^ (rb & 7)) << 4);
    }

  f32x4 acc[4][4];
  #pragma unroll
  for (int i = 0; i < 4; ++i)
    #pragma unroll
    for (int j = 0; j < 4; ++j) acc[i][j] = (f32x4){0.f,0.f,0.f,0.f};

  auto loop = [&](auto SW) {
    for (int kt = 0; kt < 16; ++kt) {
      #pragma unroll
      for (int u = 0; u < 4; ++u) {
        gl_lds16(aptr[u] + kt * 64, adst[u]);
        gl_lds16(bptr[u] + kt * 64, bdst[u]);
      }
      __syncthreads();
      #pragma unroll
      for (int ks = 0; ks < 2; ++ks) {
        short8 af[4], bf[4];
        #pragma unroll
        for (int q = 0; q < 4; ++q) {
          af[q] = *(const short8*)((const char*)As + aoff[ks][q]);
          bf[q] = *(const short8*)((const char*)Bs + boff[ks][q]);
        }
        #pragma unroll
        for (int mi = 0; mi < 4; ++mi)
          #pragma unroll
          for (int nj = 0; nj < 4; ++nj) {
            if constexpr (decltype(SW)::value)
              acc[mi][nj] = __builtin_amdgcn_mfma_f32_16x16x32_bf16(bf[nj], af[mi], acc[mi][nj], 0, 0, 0);
            else
              acc[mi][nj] = __builtin_amdgcn_mfma_f32_16x16x32_bf16(af[mi], bf[nj], acc[mi][nj], 0, 0, 0);
          }
      }
      __syncthreads();
    }
  };
  if (swp) loop(BC<true>{}); else loop(BC<false>{});

  if constexpr (KIND == 0) {
    #pragma unroll
    for (int mi = 0; mi < 4; ++mi) {
      const int m = row0 + wm + mi * 16 + lt;
      #pragma unroll
      for (int nj = 0; nj < 4; ++nj) {
        const int nb = col0 + wn + nj * 16 + (lg << 2);
        float4 bb = *(const float4*)(b0 + nb);
        float4 o = make_float4(acc[mi][nj][0] + bb.x, acc[mi][nj][1] + bb.y,
                               acc[mi][nj][2] + bb.z, acc[mi][nj][3] + bb.w);
        *(float4*)(Cout + (size_t)m * 1024 + nb) = o;
      }
    }
  } else if (proj < 2) {
    const float* bias = proj ? b1 : b0;
    u16* Ob = proj ? O1 : O0;
    const int col0p = (gy & 7) << 7;
    #pragma unroll
    for (int mi = 0; mi < 4; ++mi) {
      const int m = row0 + wm + mi * 16 + lt;
      const int bb_ = m >> 11, lpos = m & (L_ - 1);
      #pragma unroll
      for (int nj = 0; nj < 4; ++nj) {
        const int nb = col0p + wn + nj * 16 + (lg << 2);
        const int d0 = nb & 63, h = nb >> 6;
        float4 ba = *(const float4*)(bias + nb);
        const float o0 = acc[mi][nj][0] + ba.x, o1 = acc[mi][nj][1] + ba.y;
        const float o2 = acc[mi][nj][2] + ba.z, o3 = acc[mi][nj][3] + ba.w;
        const float* ct = costab + lpos * 32 + (d0 >> 1);
        const float* st = sintab + lpos * 32 + (d0 >> 1);
        const float c0 = ct[0], c1 = ct[1], s0 = st[0], s1 = st[1];
        const float r0 = o0 * c0 - o1 * s0, r1 = o0 * s0 + o1 * c0;
        const float r2 = o2 * c1 - o3 * s1, r3 = o2 * s1 + o3 * c1;
        *(u16x4*)(Ob + ((size_t)(bb_ * 16 + h) * L_ + lpos) * 64 + d0) = f2b4(r0, r1, r2, r3);
      }
    }
  } else {
    const int col0p = (gy & 7) << 7;
    #pragma unroll
    for (int mi = 0; mi < 4; ++mi) {
      const int lb = row0 + wm + mi * 16 + (lg << 2);
      const int bb_ = lb >> 11;
      #pragma unroll
      for (int nj = 0; nj < 4; ++nj) {
        const int n = col0p + wn + nj * 16 + lt;
        const int h = n >> 6, dh = n & 63;
        const float bv1 = b2[n];
        *(u16x4*)(O2 + ((size_t)(bb_ * 16 + h) * 64 + dh) * L_ + (lb & (L_ - 1))) =
            f2b4(acc[mi][nj][0] + bv1, acc[mi][nj][1] + bv1,
                 acc[mi][nj][2] + bv1, acc[mi][nj][3] + bv1);
      }
    }
  }
}

// ---------------------------------------------------------------- MFMA attention, fused normalization
// Work-balanced: block p handles stripe pair {p, 63-p} (32 rows each).
// Waves 0,1 -> stripe p (16 rows each); waves 2,3 -> stripe 63-p.
// Per-block cost = 33 kv-tile-units for every p (uniform).
__global__ __launch_bounds__(256) void attn_mfma(
    const u16* __restrict__ Qb, const u16* __restrict__ Kb, const u16* __restrict__ Vt,
    const float* __restrict__ pblg, float* __restrict__ Pout, u16* __restrict__ AOb)
{
  __shared__ u16 Pb[4][1024];
  __shared__ float pbl[2048];
  const int t = threadIdx.x, w = t >> 6, lane = t & 63;
  const int lt = lane & 15, lg = lane >> 4;
  {
    const int i8 = t * 8;
    *(float4*)(pbl + i8)     = *(const float4*)(pblg + i8);
    *(float4*)(pbl + i8 + 4) = *(const float4*)(pblg + i8 + 4);
  }
  const int bh = blockIdx.y, b = bh >> 4, h = bh & 15;
  const int p  = blockIdx.x;
  const int S  = (w < 2) ? p : (63 - p);      // 32-row stripe id (0..63)
  const int i0 = S * 32 + (w & 1) * 16;       // this wave's 16-row base
  const int kvN = (S >> 1) + 1;               // kv tiles needed (causal)
  __syncthreads();

  const u16* qp = Qb + ((size_t)bh * L_ + i0 + lt) * 64 + lg * 8;
  const short8 qf0 = *(const short8*)(qp);
  const short8 qf1 = *(const short8*)(qp + 32);
  const int i = i0 + lt;   // this lane's q-row

  char* pbase = (char*)(&Pb[w][0]);
  const int swz = (lt & 7) << 4;
  const float C1 = 0.18033688011112042f;   // 0.125 * log2(e)

  // ---- pass 1: fp32 row-sum
  float lsum = 0.f;
  for (int kvt = 0; kvt < kvN; ++kvt) {
    const int j0 = kvt << 6;
    const u16* kp = Kb + ((size_t)bh * L_ + j0 + lt) * 64 + lg * 8;
    #pragma unroll
    for (int jt = 0; jt < 4; ++jt) {
      short8 kf0 = *(const short8*)(kp + jt * 1024);
      short8 kf1 = *(const short8*)(kp + jt * 1024 + 32);
      f32x4 z = (f32x4){0.f,0.f,0.f,0.f};
      z = __builtin_amdgcn_mfma_f32_16x16x32_bf16(kf0, qf0, z, 0, 0, 0);
      z = __builtin_amdgcn_mfma_f32_16x16x32_bf16(kf1, qf1, z, 0, 0, 0);
      const int jb = j0 + jt * 16 + (lg << 2);
      const int dd = i - jb;
      #pragma unroll
      for (int r = 0; r < 4; ++r) {
        const int d  = dd - r;
        const int dc = d < 0 ? 0 : d;
        const float pe = exp2f(fmaf(z[r], C1, pbl[dc]));
        if (d >= 0) lsum += pe;
      }
    }
  }
  lsum += __shfl_xor(lsum, 16);
  lsum += __shfl_xor(lsum, 32);
  const float rinv = 1.f / lsum;

  // ---- pass 2: normalized P write + PV
  f32x4 oacc[4];
  #pragma unroll
  for (int dt = 0; dt < 4; ++dt) oacc[dt] = (f32x4){0.f,0.f,0.f,0.f};

  for (int kvt = 0; kvt < kvN; ++kvt) {
    const int j0 = kvt << 6;
    const u16* kp = Kb + ((size_t)bh * L_ + j0 + lt) * 64 + lg * 8;
    #pragma unroll
    for (int jt = 0; jt < 4; ++jt) {
      short8 kf0 = *(const short8*)(kp + jt * 1024);
      short8 kf1 = *(const short8*)(kp + jt * 1024 + 32);
      f32x4 z = (f32x4){0.f,0.f,0.f,0.f};
      z = __builtin_amdgcn_mfma_f32_16x16x32_bf16(kf0, qf0, z, 0, 0, 0);
      z = __builtin_amdgcn_mfma_f32_16x16x32_bf16(kf1, qf1, z, 0, 0, 0);
      const int jb = j0 + jt * 16 + (lg << 2);
      const int dd = i - jb;
      float pr[4];
      #pragma unroll
      for (int r = 0; r < 4; ++r) {
        const int d  = dd - r;
        const int dc = d < 0 ? 0 : d;
        float pe = exp2f(fmaf(z[r], C1, pbl[dc])) * rinv;
        pr[r] = d < 0 ? 0.f : pe;
      }
      *(float4*)(Pout + ((size_t)bh * L_ + i) * L_ + jb) = make_float4(pr[0], pr[1], pr[2], pr[3]);
      *(u16x4*)(pbase + lt * 128 + ((jt * 32 + lg * 8) ^ swz)) = f2b4(pr[0], pr[1], pr[2], pr[3]);
    }

    short8 pa0 = *(const short8*)(pbase + lt * 128 + ((lg * 16) ^ swz));
    short8 pa1 = *(const short8*)(pbase + lt * 128 + ((64 + lg * 16) ^ swz));
    const u16* vp = Vt + ((size_t)bh * 64 + lt) * L_ + j0 + lg * 8;
    #pragma unroll
    for (int dt = 0; dt < 4; ++dt) {
      short8 vf0 = *(const short8*)(vp + dt * 16 * L_);
      short8 vf1 = *(const short8*)(vp + dt * 16 * L_ + 32);
      oacc[dt] = __builtin_amdgcn_mfma_f32_16x16x32_bf16(pa0, vf0, oacc[dt], 0, 0, 0);
      oacc[dt] = __builtin_amdgcn_mfma_f32_16x16x32_bf16(pa1, vf1, oacc[dt], 0, 0, 0);
    }
  }

  // ---- zero upper-triangle: stripe rows, cols kvN*64 .. 2047
  // threads 0..127 -> stripe p ; threads 128..255 -> stripe 63-p
  {
    const int Sz   = (t < 128) ? p : (63 - p);
    const int kvNz = (Sz >> 1) + 1;
    const int tt   = t & 127;
    const int row  = Sz * 32 + (tt >> 2);
    float4* prow = (float4*)(Pout + ((size_t)bh * L_ + row) * L_);
    const float4 zz = make_float4(0.f, 0.f, 0.f, 0.f);
    for (int c4 = (kvNz << 4) + (tt & 3); c4 < 512; c4 += 4) prow[c4] = zz;
  }

  // ---- epilogue: AO (already normalized)
  #pragma unroll
  for (int r = 0; r < 4; ++r) {
    const int irow = i0 + (lg << 2) + r;
    u16* ao = AOb + ((size_t)(b * L_ + irow)) * 1024 + h * 64 + lt;
    #pragma unroll
    for (int dt = 0; dt < 4; ++dt) ao[dt * 16] = f2b(oacc[dt][r]);
  }
}

// ---------------------------------------------------------------- launch
extern "C" void kernel_launch(void* const* d_in, const int* in_sizes, int n_in,
                              void* d_out, int out_size, void* d_ws, size_t ws_size,
                              hipStream_t stream) {
  const float* x  = (const float*)d_in[0];
  const float* Wq = (const float*)d_in[1];
  const float* bq = (const float*)d_in[2];
  const float* Wk = (const float*)d_in[3];
  const float* bk = (const float*)d_in[4];
  const float* Wv = (const float*)d_in[5];
  const float* bv = (const float*)d_in[6];
  const float* Wo = (const float*)d_in[7];
  const float* bo = (const float*)d_in[8];

  float* out  = (float*)d_out;
  float* Pout = out + (size_t)BL_ * D_;

  float* ws = (float*)d_ws;
  u16* XB  = (u16*)(ws + WS_XB);
  u16* WT4 = (u16*)(ws + WS_WT4);
  u16* QB  = (u16*)(ws + WS_QB);
  u16* KB  = (u16*)(ws + WS_KB);
  u16* VT  = (u16*)(ws + WS_VT);
  u16* AOB = (u16*)(ws + WS_AOB);
  float* cosT = ws + WS_COS;
  float* sinT = ws + WS_SIN;
  float* pblG = ws + WS_PBL;

  fill_tables<<<256, 256, 0, stream>>>(cosT, sinT, pblG);
  xcast<<<2048, 256, 0, stream>>>(x, XB);
  wtrans4<<<dim3(16,16,4), 256, 0, stream>>>(Wq, Wk, Wv, Wo, WT4);

  gemm_k<1><<<dim3(32,24), 256, 0, stream>>>(XB, WT4, bq, bk, bv, cosT, sinT,
                                             QB, KB, VT, nullptr);

  attn_mfma<<<dim3(32,32), 256, 0, stream>>>(QB, KB, VT, pblG, Pout, AOB);

  gemm_k<0><<<dim3(32,8), 256, 0, stream>>>(AOB, WT4 + (size_t)3*1024*1024, bo,
                                            nullptr, nullptr, nullptr, nullptr,
                                            nullptr, nullptr, nullptr, out);
}

// Round 7
// 407.199 us; speedup vs baseline: 16.4915x; 1.0639x over previous
//
#include <hip/hip_runtime.h>
#include <math.h>

#define B_  2
#define L_  2048
#define D_  1024
#define H_  16
#define DH_ 64
#define BL_ (B_*L_)   // 4096

typedef unsigned short u16;
typedef __attribute__((ext_vector_type(8))) short short8;
typedef __attribute__((ext_vector_type(4))) float f32x4;
typedef __attribute__((ext_vector_type(4))) unsigned short u16x4;

template<bool V> struct BC { static constexpr bool value = V; };

// ---- workspace offsets (floats) -- each bf16 [4096][1024]-sized buffer = 2,097,152 floats
#define WS_XB   0            // x bf16 [4096][1024]
#define WS_WT4  2097152      // Wt bf16 [4][1024][1024]
#define WS_QB   4194304      // [32][2048][64] bf16
#define WS_KB   6291456
#define WS_VT   8388608      // [32][64][2048] bf16
#define WS_AOB  10485760     // AO bf16 [4096][1024]
#define WS_COS  12582912     // [2048][32] f32
#define WS_SIN  12648448
#define WS_PBL  12713984     // [2048] f32 (pre-scaled by log2e)
// end ~12.72M floats ~ 50.9 MB

__device__ __forceinline__ u16 f2b(float f) {
  union { float f; unsigned u; } v; v.f = f;
  unsigned r = (v.u + 0x7fffu + ((v.u >> 16) & 1u)) >> 16;
  return (u16)r;
}
__device__ __forceinline__ u16x4 f2b4(float a, float b, float c, float d) {
  u16x4 u; u.x = f2b(a); u.y = f2b(b); u.z = f2b(c); u.w = f2b(d); return u;
}
__device__ __forceinline__ void gl_lds16(const void* g, void* l) {
  __builtin_amdgcn_global_load_lds(
      (const __attribute__((address_space(1))) unsigned int*)g,
      (__attribute__((address_space(3))) unsigned int*)l, 16, 0, 0);
}

// ---------------------------------------------------------------- tables
__global__ void fill_tables(float* __restrict__ costab, float* __restrict__ sintab,
                            float* __restrict__ pbl) {
  int idx = blockIdx.x * 256 + threadIdx.x;
  if (idx < L_ * 32) {
    int l = idx >> 5, tp = idx & 31;
    double inv = pow(10000.0, -2.0 * (double)tp / 64.0);
    double th  = (double)l * inv;
    costab[idx] = (float)cos(th);
    sintab[idx] = (float)sin(th);
  }
  if (idx < L_) {
    double d = (double)idx;
    double v = 0.5  * cos(6.283185307179586 * d / 24.0)
             + 0.25 * cos(6.283185307179586 * d / 168.0);
    pbl[idx] = (float)(v * 1.4426950408889634);
  }
}

// ---------------------------------------------------------------- x -> bf16
__global__ __launch_bounds__(256) void xcast(const float* __restrict__ x, u16* __restrict__ xb) {
  const size_t i = ((size_t)blockIdx.x * 256 + threadIdx.x) * 8;
  float4 a = *(const float4*)(x + i);
  float4 b = *(const float4*)(x + i + 4);
  u16 us[8] = { f2b(a.x),f2b(a.y),f2b(a.z),f2b(a.w), f2b(b.x),f2b(b.y),f2b(b.z),f2b(b.w) };
  *(short8*)(xb + i) = *(short8*)us;
}

// ---------------------------------------------------------------- W[k][n] f32 -> Wt[n][k] bf16 (4 weights, z-indexed)
__global__ __launch_bounds__(256) void wtrans4(const float* __restrict__ W0, const float* __restrict__ W1,
                                               const float* __restrict__ W2, const float* __restrict__ W3,
                                               u16* __restrict__ Wt) {
  __shared__ u16 tt[64][80];
  const int z = blockIdx.z;
  const float* W = (z == 0) ? W0 : (z == 1) ? W1 : (z == 2) ? W2 : W3;
  u16* Wtz = Wt + (size_t)z * 1024 * 1024;
  const int k0 = blockIdx.x << 6, n0 = blockIdx.y << 6;
  const int t = threadIdx.x;
  {
    const int r = t >> 4, c4 = (t & 15) << 2;
    for (int rr = r; rr < 64; rr += 16) {
      float4 v = *(const float4*)(W + (size_t)(k0 + rr) * D_ + n0 + c4);
      tt[c4+0][rr] = f2b(v.x); tt[c4+1][rr] = f2b(v.y);
      tt[c4+2][rr] = f2b(v.z); tt[c4+3][rr] = f2b(v.w);
    }
  }
  __syncthreads();
  const int n = t >> 2, kc = (t & 3) << 4;
  u16* dst = Wtz + (size_t)(n0 + n) * D_ + k0 + kc;
  #pragma unroll
  for (int u = 0; u < 16; ++u) dst[u] = tt[n][kc + u];
}

// ---------------------------------------------------------------- bf16 MFMA GEMM, 128x128 tile, BK=64
// KIND 0: out-proj -> Cout fp32 [4096][1024]
// KIND 1: QKV (grid.y 0-7 Q rope, 8-15 K rope, 16-23 V -> V^T)
template<int KIND>
__global__ __launch_bounds__(256) void gemm_k(
    const u16* __restrict__ Ag, const u16* __restrict__ Bg,
    const float* __restrict__ b0, const float* __restrict__ b1, const float* __restrict__ b2,
    const float* __restrict__ costab, const float* __restrict__ sintab,
    u16* __restrict__ O0, u16* __restrict__ O1, u16* __restrict__ O2,
    float* __restrict__ Cout)
{
  __shared__ u16 As[8192];
  __shared__ u16 Bs[8192];
  const int t = threadIdx.x, w = t >> 6, lane = t & 63;
  const int lt = lane & 15, lg = lane >> 4;
  const int row0 = blockIdx.x << 7;
  const int gy   = blockIdx.y;
  const int col0 = gy << 7;
  const int wm = (w & 1) << 6, wn = (w >> 1) << 6;
  const int proj = (KIND == 1) ? (gy >> 3) : 0;
  const bool swp = (KIND == 0) || (proj < 2);

  const int srow = lane >> 3;
  const int gch  = (lane & 7) ^ (srow & 7);
  const u16* aptr[4]; const u16* bptr[4];
  char* adst[4]; char* bdst[4];
  #pragma unroll
  for (int u = 0; u < 4; ++u) {
    const int rl = w * 32 + u * 8 + srow;
    aptr[u] = Ag + (size_t)(row0 + rl) * 1024 + gch * 8;
    bptr[u] = Bg + (size_t)(col0 + rl) * 1024 + gch * 8;
    adst[u] = (char*)As + (w * 32 + u * 8) * 128;
    bdst[u] = (char*)Bs + (w * 32 + u * 8) * 128;
  }
  int aoff[2][4], boff[2][4];
  #pragma unroll
  for (int ks = 0; ks < 2; ++ks)
    #pragma unroll
    for (int q = 0; q < 4; ++q) {
      const int ra = wm + q * 16 + lt;
      aoff[ks][q] = ra * 128 + (((ks * 4 + lg) ^ (ra & 7)) << 4);
      const int rb = wn + q * 16 + lt;
      boff[ks][q] = rb * 128 + (((ks * 4 + lg) ^ (rb & 7)) << 4);
    }

  f32x4 acc[4][4];
  #pragma unroll
  for (int i = 0; i < 4; ++i)
    #pragma unroll
    for (int j = 0; j < 4; ++j) acc[i][j] = (f32x4){0.f,0.f,0.f,0.f};

  auto loop = [&](auto SW) {
    for (int kt = 0; kt < 16; ++kt) {
      #pragma unroll
      for (int u = 0; u < 4; ++u) {
        gl_lds16(aptr[u] + kt * 64, adst[u]);
        gl_lds16(bptr[u] + kt * 64, bdst[u]);
      }
      __syncthreads();
      #pragma unroll
      for (int ks = 0; ks < 2; ++ks) {
        short8 af[4], bf[4];
        #pragma unroll
        for (int q = 0; q < 4; ++q) {
          af[q] = *(const short8*)((const char*)As + aoff[ks][q]);
          bf[q] = *(const short8*)((const char*)Bs + boff[ks][q]);
        }
        #pragma unroll
        for (int mi = 0; mi < 4; ++mi)
          #pragma unroll
          for (int nj = 0; nj < 4; ++nj) {
            if constexpr (decltype(SW)::value)
              acc[mi][nj] = __builtin_amdgcn_mfma_f32_16x16x32_bf16(bf[nj], af[mi], acc[mi][nj], 0, 0, 0);
            else
              acc[mi][nj] = __builtin_amdgcn_mfma_f32_16x16x32_bf16(af[mi], bf[nj], acc[mi][nj], 0, 0, 0);
          }
      }
      __syncthreads();
    }
  };
  if (swp) loop(BC<true>{}); else loop(BC<false>{});

  if constexpr (KIND == 0) {
    #pragma unroll
    for (int mi = 0; mi < 4; ++mi) {
      const int m = row0 + wm + mi * 16 + lt;
      #pragma unroll
      for (int nj = 0; nj < 4; ++nj) {
        const int nb = col0 + wn + nj * 16 + (lg << 2);
        float4 bb = *(const float4*)(b0 + nb);
        float4 o = make_float4(acc[mi][nj][0] + bb.x, acc[mi][nj][1] + bb.y,
                               acc[mi][nj][2] + bb.z, acc[mi][nj][3] + bb.w);
        *(float4*)(Cout + (size_t)m * 1024 + nb) = o;
      }
    }
  } else if (proj < 2) {
    const float* bias = proj ? b1 : b0;
    u16* Ob = proj ? O1 : O0;
    const int col0p = (gy & 7) << 7;
    #pragma unroll
    for (int mi = 0; mi < 4; ++mi) {
      const int m = row0 + wm + mi * 16 + lt;
      const int bb_ = m >> 11, lpos = m & (L_ - 1);
      #pragma unroll
      for (int nj = 0; nj < 4; ++nj) {
        const int nb = col0p + wn + nj * 16 + (lg << 2);
        const int d0 = nb & 63, h = nb >> 6;
        float4 ba = *(const float4*)(bias + nb);
        const float o0 = acc[mi][nj][0] + ba.x, o1 = acc[mi][nj][1] + ba.y;
        const float o2 = acc[mi][nj][2] + ba.z, o3 = acc[mi][nj][3] + ba.w;
        const float* ct = costab + lpos * 32 + (d0 >> 1);
        const float* st = sintab + lpos * 32 + (d0 >> 1);
        const float c0 = ct[0], c1 = ct[1], s0 = st[0], s1 = st[1];
        const float r0 = o0 * c0 - o1 * s0, r1 = o0 * s0 + o1 * c0;
        const float r2 = o2 * c1 - o3 * s1, r3 = o2 * s1 + o3 * c1;
        *(u16x4*)(Ob + ((size_t)(bb_ * 16 + h) * L_ + lpos) * 64 + d0) = f2b4(r0, r1, r2, r3);
      }
    }
  } else {
    const int col0p = (gy & 7) << 7;
    #pragma unroll
    for (int mi = 0; mi < 4; ++mi) {
      const int lb = row0 + wm + mi * 16 + (lg << 2);
      const int bb_ = lb >> 11;
      #pragma unroll
      for (int nj = 0; nj < 4; ++nj) {
        const int n = col0p + wn + nj * 16 + lt;
        const int h = n >> 6, dh = n & 63;
        const float bv1 = b2[n];
        *(u16x4*)(O2 + ((size_t)(bb_ * 16 + h) * 64 + dh) * L_ + (lb & (L_ - 1))) =
            f2b4(acc[mi][nj][0] + bv1, acc[mi][nj][1] + bv1,
                 acc[mi][nj][2] + bv1, acc[mi][nj][3] + bv1);
      }
    }
  }
}

// ---------------------------------------------------------------- MFMA attention, fused normalization
// 512 threads / 8 waves. Stripe pair {p, 63-p}; within a stripe, 2 row-halves x 2 kv-parities.
// wave w: stripe = (w<4)?p:63-p ; row-half = w&1 ; kv-parity = (w>>1)&1.
// Parity partners (w ^ 2) combine lsum (LDS) and oacc (LDS, reusing Pb).
__global__ __launch_bounds__(512, 8) void attn_mfma(
    const u16* __restrict__ Qb, const u16* __restrict__ Kb, const u16* __restrict__ Vt,
    const float* __restrict__ pblg, float* __restrict__ Pout, u16* __restrict__ AOb)
{
  __shared__ u16 Pb[8][1024];      // per-wave P staging (2KB each); reused as oacc exchange buf
  __shared__ float pbl[2048];
  __shared__ float lsbuf[8][16];
  const int t = threadIdx.x, w = t >> 6, lane = t & 63;
  const int lt = lane & 15, lg = lane >> 4;
  *(float4*)(pbl + t * 4) = *(const float4*)(pblg + t * 4);
  const int bh = blockIdx.y, b = bh >> 4, h = bh & 15;
  const int p  = blockIdx.x;
  const int S   = (w < 4) ? p : (63 - p);     // 32-row stripe id (0..63)
  const int sub = w & 1;
  const int par = (w >> 1) & 1;               // kv parity
  const int i0  = S * 32 + sub * 16;          // this wave's 16-row base
  const int kvN = (S >> 1) + 1;               // kv tiles needed (causal)
  __syncthreads();

  const u16* qp = Qb + ((size_t)bh * L_ + i0 + lt) * 64 + lg * 8;
  const short8 qf0 = *(const short8*)(qp);
  const short8 qf1 = *(const short8*)(qp + 32);
  const int i = i0 + lt;   // this lane's q-row

  char* pbase = (char*)(&Pb[w][0]);
  const int swz = (lt & 7) << 4;
  const float C1 = 0.18033688011112042f;   // 0.125 * log2(e)

  // ---- pass 1: partial fp32 row-sum over this wave's kv parity
  float lsum = 0.f;
  for (int kvt = par; kvt < kvN; kvt += 2) {
    const int j0 = kvt << 6;
    const u16* kp = Kb + ((size_t)bh * L_ + j0 + lt) * 64 + lg * 8;
    #pragma unroll
    for (int jt = 0; jt < 4; ++jt) {
      short8 kf0 = *(const short8*)(kp + jt * 1024);
      short8 kf1 = *(const short8*)(kp + jt * 1024 + 32);
      f32x4 z = (f32x4){0.f,0.f,0.f,0.f};
      z = __builtin_amdgcn_mfma_f32_16x16x32_bf16(kf0, qf0, z, 0, 0, 0);
      z = __builtin_amdgcn_mfma_f32_16x16x32_bf16(kf1, qf1, z, 0, 0, 0);
      const int jb = j0 + jt * 16 + (lg << 2);
      const int dd = i - jb;
      #pragma unroll
      for (int r = 0; r < 4; ++r) {
        const int d  = dd - r;
        const int dc = d < 0 ? 0 : d;
        const float pe = exp2f(fmaf(z[r], C1, pbl[dc]));
        if (d >= 0) lsum += pe;
      }
    }
  }
  lsum += __shfl_xor(lsum, 16);
  lsum += __shfl_xor(lsum, 32);
  if (lane < 16) lsbuf[w][lt] = lsum;
  __syncthreads();
  const float rinv = 1.f / (lsbuf[w][lt] + lsbuf[w ^ 2][lt]);

  // ---- pass 2: normalized P write + PV (this wave's kv parity only)
  f32x4 oacc[4];
  #pragma unroll
  for (int dt = 0; dt < 4; ++dt) oacc[dt] = (f32x4){0.f,0.f,0.f,0.f};

  for (int kvt = par; kvt < kvN; kvt += 2) {
    const int j0 = kvt << 6;
    const u16* kp = Kb + ((size_t)bh * L_ + j0 + lt) * 64 + lg * 8;
    #pragma unroll
    for (int jt = 0; jt < 4; ++jt) {
      short8 kf0 = *(const short8*)(kp + jt * 1024);
      short8 kf1 = *(const short8*)(kp + jt * 1024 + 32);
      f32x4 z = (f32x4){0.f,0.f,0.f,0.f};
      z = __builtin_amdgcn_mfma_f32_16x16x32_bf16(kf0, qf0, z, 0, 0, 0);
      z = __builtin_amdgcn_mfma_f32_16x16x32_bf16(kf1, qf1, z, 0, 0, 0);
      const int jb = j0 + jt * 16 + (lg << 2);
      const int dd = i - jb;
      float pr[4];
      #pragma unroll
      for (int r = 0; r < 4; ++r) {
        const int d  = dd - r;
        const int dc = d < 0 ? 0 : d;
        float pe = exp2f(fmaf(z[r], C1, pbl[dc])) * rinv;
        pr[r] = d < 0 ? 0.f : pe;
      }
      *(float4*)(Pout + ((size_t)bh * L_ + i) * L_ + jb) = make_float4(pr[0], pr[1], pr[2], pr[3]);
      *(u16x4*)(pbase + lt * 128 + ((jt * 32 + lg * 8) ^ swz)) = f2b4(pr[0], pr[1], pr[2], pr[3]);
    }

    short8 pa0 = *(const short8*)(pbase + lt * 128 + ((lg * 16) ^ swz));
    short8 pa1 = *(const short8*)(pbase + lt * 128 + ((64 + lg * 16) ^ swz));
    const u16* vp = Vt + ((size_t)bh * 64 + lt) * L_ + j0 + lg * 8;
    #pragma unroll
    for (int dt = 0; dt < 4; ++dt) {
      short8 vf0 = *(const short8*)(vp + dt * 16 * L_);
      short8 vf1 = *(const short8*)(vp + dt * 16 * L_ + 32);
      oacc[dt] = __builtin_amdgcn_mfma_f32_16x16x32_bf16(pa0, vf0, oacc[dt], 0, 0, 0);
      oacc[dt] = __builtin_amdgcn_mfma_f32_16x16x32_bf16(pa1, vf1, oacc[dt], 0, 0, 0);
    }
  }

  // ---- oacc exchange: odd-parity waves dump into retired Pb space
  __syncthreads();
  float* obuf = (float*)&Pb[0][0];            // 4096 floats
  const int slot = ((w >> 2) << 1) | (w & 1); // 0..3 per (stripe, row-half)
  if (par == 1) {
    float* dst = obuf + slot * 1024 + lane * 16;
    #pragma unroll
    for (int dt = 0; dt < 4; ++dt) *(f32x4*)(dst + dt * 4) = oacc[dt];
  }
  __syncthreads();

  // ---- zero upper-triangle: all 512 threads
  {
    const int Sz   = (t < 256) ? p : (63 - p);
    const int kvNz = (Sz >> 1) + 1;
    const int tt   = t & 255;
    const int row  = Sz * 32 + (tt >> 3);
    float4* prow = (float4*)(Pout + ((size_t)bh * L_ + row) * L_);
    const float4 zz = make_float4(0.f, 0.f, 0.f, 0.f);
    for (int c4 = (kvNz << 4) + (tt & 7); c4 < 512; c4 += 8) prow[c4] = zz;
  }

  // ---- even-parity waves combine + write AO (already normalized)
  if (par == 0) {
    const float* src = obuf + slot * 1024 + lane * 16;
    #pragma unroll
    for (int dt = 0; dt < 4; ++dt) {
      f32x4 o = *(const f32x4*)(src + dt * 4);
      oacc[dt][0] += o[0]; oacc[dt][1] += o[1];
      oacc[dt][2] += o[2]; oacc[dt][3] += o[3];
    }
    #pragma unroll
    for (int r = 0; r < 4; ++r) {
      const int irow = i0 + (lg << 2) + r;
      u16* ao = AOb + ((size_t)(b * L_ + irow)) * 1024 + h * 64 + lt;
      #pragma unroll
      for (int dt = 0; dt < 4; ++dt) ao[dt * 16] = f2b(oacc[dt][r]);
    }
  }
}

// ---------------------------------------------------------------- launch
extern "C" void kernel_launch(void* const* d_in, const int* in_sizes, int n_in,
                              void* d_out, int out_size, void* d_ws, size_t ws_size,
                              hipStream_t stream) {
  const float* x  = (const float*)d_in[0];
  const float* Wq = (const float*)d_in[1];
  const float* bq = (const float*)d_in[2];
  const float* Wk = (const float*)d_in[3];
  const float* bk = (const float*)d_in[4];
  const float* Wv = (const float*)d_in[5];
  const float* bv = (const float*)d_in[6];
  const float* Wo = (const float*)d_in[7];
  const float* bo = (const float*)d_in[8];

  float* out  = (float*)d_out;
  float* Pout = out + (size_t)BL_ * D_;

  float* ws = (float*)d_ws;
  u16* XB  = (u16*)(ws + WS_XB);
  u16* WT4 = (u16*)(ws + WS_WT4);
  u16* QB  = (u16*)(ws + WS_QB);
  u16* KB  = (u16*)(ws + WS_KB);
  u16* VT  = (u16*)(ws + WS_VT);
  u16* AOB = (u16*)(ws + WS_AOB);
  float* cosT = ws + WS_COS;
  float* sinT = ws + WS_SIN;
  float* pblG = ws + WS_PBL;

  fill_tables<<<256, 256, 0, stream>>>(cosT, sinT, pblG);
  xcast<<<2048, 256, 0, stream>>>(x, XB);
  wtrans4<<<dim3(16,16,4), 256, 0, stream>>>(Wq, Wk, Wv, Wo, WT4);

  gemm_k<1><<<dim3(32,24), 256, 0, stream>>>(XB, WT4, bq, bk, bv, cosT, sinT,
                                             QB, KB, VT, nullptr);

  attn_mfma<<<dim3(32,32), 512, 0, stream>>>(QB, KB, VT, pblG, Pout, AOB);

  gemm_k<0><<<dim3(32,8), 256, 0, stream>>>(AOB, WT4 + (size_t)3*1024*1024, bo,
                                            nullptr, nullptr, nullptr, nullptr,
                                            nullptr, nullptr, nullptr, out);
}

// Round 8
// 336.754 us; speedup vs baseline: 19.9414x; 1.2092x over previous
//
#include <hip/hip_runtime.h>
#include <math.h>

#define B_  2
#define L_  2048
#define D_  1024
#define H_  16
#define DH_ 64
#define BL_ (B_*L_)   // 4096

typedef unsigned short u16;
typedef __attribute__((ext_vector_type(8))) short short8;
typedef __attribute__((ext_vector_type(4))) float f32x4;
typedef __attribute__((ext_vector_type(4))) unsigned short u16x4;

template<bool V> struct BC { static constexpr bool value = V; };

// ---- workspace offsets (floats)
#define WS_XB   0            // x bf16 [4096][1024]
#define WS_WT4  2097152      // Wt bf16 [4][1024][1024]
#define WS_QB   4194304      // [32][2048][64] bf16
#define WS_KB   6291456
#define WS_VT   8388608      // [32][64][2048] bf16
#define WS_AOB  10485760     // AO bf16 [4096][1024]
#define WS_COS  12582912     // [2048][32] f32
#define WS_SIN  12648448
#define WS_PBL  12713984     // [2048] f32 (pre-scaled by log2e)
// end ~12.72M floats ~ 50.9 MB

__device__ __forceinline__ u16 f2b(float f) {
  union { float f; unsigned u; } v; v.f = f;
  unsigned r = (v.u + 0x7fffu + ((v.u >> 16) & 1u)) >> 16;
  return (u16)r;
}
__device__ __forceinline__ u16x4 f2b4(float a, float b, float c, float d) {
  u16x4 u; u.x = f2b(a); u.y = f2b(b); u.z = f2b(c); u.w = f2b(d); return u;
}
__device__ __forceinline__ float bf2f(u16 u) {
  union { unsigned u; float f; } v; v.u = ((unsigned)u) << 16; return v.f;
}
__device__ __forceinline__ void gl_lds16(const void* g, void* l) {
  __builtin_amdgcn_global_load_lds(
      (const __attribute__((address_space(1))) unsigned int*)g,
      (__attribute__((address_space(3))) unsigned int*)l, 16, 0, 0);
}

// ---------------------------------------------------------------- tables
__global__ void fill_tables(float* __restrict__ costab, float* __restrict__ sintab,
                            float* __restrict__ pbl) {
  int idx = blockIdx.x * 256 + threadIdx.x;
  if (idx < L_ * 32) {
    int l = idx >> 5, tp = idx & 31;
    double inv = pow(10000.0, -2.0 * (double)tp / 64.0);
    double th  = (double)l * inv;
    costab[idx] = (float)cos(th);
    sintab[idx] = (float)sin(th);
  }
  if (idx < L_) {
    double d = (double)idx;
    double v = 0.5  * cos(6.283185307179586 * d / 24.0)
             + 0.25 * cos(6.283185307179586 * d / 168.0);
    pbl[idx] = (float)(v * 1.4426950408889634);
  }
}

// ---------------------------------------------------------------- x -> bf16
__global__ __launch_bounds__(256) void xcast(const float* __restrict__ x, u16* __restrict__ xb) {
  const size_t i = ((size_t)blockIdx.x * 256 + threadIdx.x) * 8;
  float4 a = *(const float4*)(x + i);
  float4 b = *(const float4*)(x + i + 4);
  u16 us[8] = { f2b(a.x),f2b(a.y),f2b(a.z),f2b(a.w), f2b(b.x),f2b(b.y),f2b(b.z),f2b(b.w) };
  *(short8*)(xb + i) = *(short8*)us;
}

// ---------------------------------------------------------------- W[k][n] f32 -> Wt[n][k] bf16 (4 weights, z-indexed)
__global__ __launch_bounds__(256) void wtrans4(const float* __restrict__ W0, const float* __restrict__ W1,
                                               const float* __restrict__ W2, const float* __restrict__ W3,
                                               u16* __restrict__ Wt) {
  __shared__ u16 tt[64][80];
  const int z = blockIdx.z;
  const float* W = (z == 0) ? W0 : (z == 1) ? W1 : (z == 2) ? W2 : W3;
  u16* Wtz = Wt + (size_t)z * 1024 * 1024;
  const int k0 = blockIdx.x << 6, n0 = blockIdx.y << 6;
  const int t = threadIdx.x;
  {
    const int r = t >> 4, c4 = (t & 15) << 2;
    for (int rr = r; rr < 64; rr += 16) {
      float4 v = *(const float4*)(W + (size_t)(k0 + rr) * D_ + n0 + c4);
      tt[c4+0][rr] = f2b(v.x); tt[c4+1][rr] = f2b(v.y);
      tt[c4+2][rr] = f2b(v.z); tt[c4+3][rr] = f2b(v.w);
    }
  }
  __syncthreads();
  const int n = t >> 2, kc = (t & 3) << 4;
  u16* dst = Wtz + (size_t)(n0 + n) * D_ + k0 + kc;
  #pragma unroll
  for (int u = 0; u < 16; ++u) dst[u] = tt[n][kc + u];
}

// ---------------------------------------------------------------- bf16 MFMA GEMM, 128x128 tile, BK=64
template<int KIND>
__global__ __launch_bounds__(256) void gemm_k(
    const u16* __restrict__ Ag, const u16* __restrict__ Bg,
    const float* __restrict__ b0, const float* __restrict__ b1, const float* __restrict__ b2,
    const float* __restrict__ costab, const float* __restrict__ sintab,
    u16* __restrict__ O0, u16* __restrict__ O1, u16* __restrict__ O2,
    float* __restrict__ Cout)
{
  __shared__ u16 As[8192];
  __shared__ u16 Bs[8192];
  const int t = threadIdx.x, w = t >> 6, lane = t & 63;
  const int lt = lane & 15, lg = lane >> 4;
  const int row0 = blockIdx.x << 7;
  const int gy   = blockIdx.y;
  const int col0 = gy << 7;
  const int wm = (w & 1) << 6, wn = (w >> 1) << 6;
  const int proj = (KIND == 1) ? (gy >> 3) : 0;
  const bool swp = (KIND == 0) || (proj < 2);

  const int srow = lane >> 3;
  const int gch  = (lane & 7) ^ (srow & 7);
  const u16* aptr[4]; const u16* bptr[4];
  char* adst[4]; char* bdst[4];
  #pragma unroll
  for (int u = 0; u < 4; ++u) {
    const int rl = w * 32 + u * 8 + srow;
    aptr[u] = Ag + (size_t)(row0 + rl) * 1024 + gch * 8;
    bptr[u] = Bg + (size_t)(col0 + rl) * 1024 + gch * 8;
    adst[u] = (char*)As + (w * 32 + u * 8) * 128;
    bdst[u] = (char*)Bs + (w * 32 + u * 8) * 128;
  }
  int aoff[2][4], boff[2][4];
  #pragma unroll
  for (int ks = 0; ks < 2; ++ks)
    #pragma unroll
    for (int q = 0; q < 4; ++q) {
      const int ra = wm + q * 16 + lt;
      aoff[ks][q] = ra * 128 + (((ks * 4 + lg) ^ (ra & 7)) << 4);
      const int rb = wn + q * 16 + lt;
      boff[ks][q] = rb * 128 + (((ks * 4 + lg) ^ (rb & 7)) << 4);
    }

  f32x4 acc[4][4];
  #pragma unroll
  for (int i = 0; i < 4; ++i)
    #pragma unroll
    for (int j = 0; j < 4; ++j) acc[i][j] = (f32x4){0.f,0.f,0.f,0.f};

  auto loop = [&](auto SW) {
    for (int kt = 0; kt < 16; ++kt) {
      #pragma unroll
      for (int u = 0; u < 4; ++u) {
        gl_lds16(aptr[u] + kt * 64, adst[u]);
        gl_lds16(bptr[u] + kt * 64, bdst[u]);
      }
      __syncthreads();
      #pragma unroll
      for (int ks = 0; ks < 2; ++ks) {
        short8 af[4], bf[4];
        #pragma unroll
        for (int q = 0; q < 4; ++q) {
          af[q] = *(const short8*)((const char*)As + aoff[ks][q]);
          bf[q] = *(const short8*)((const char*)Bs + boff[ks][q]);
        }
        #pragma unroll
        for (int mi = 0; mi < 4; ++mi)
          #pragma unroll
          for (int nj = 0; nj < 4; ++nj) {
            if constexpr (decltype(SW)::value)
              acc[mi][nj] = __builtin_amdgcn_mfma_f32_16x16x32_bf16(bf[nj], af[mi], acc[mi][nj], 0, 0, 0);
            else
              acc[mi][nj] = __builtin_amdgcn_mfma_f32_16x16x32_bf16(af[mi], bf[nj], acc[mi][nj], 0, 0, 0);
          }
      }
      __syncthreads();
    }
  };
  if (swp) loop(BC<true>{}); else loop(BC<false>{});

  if constexpr (KIND == 0) {
    #pragma unroll
    for (int mi = 0; mi < 4; ++mi) {
      const int m = row0 + wm + mi * 16 + lt;
      #pragma unroll
      for (int nj = 0; nj < 4; ++nj) {
        const int nb = col0 + wn + nj * 16 + (lg << 2);
        float4 bb = *(const float4*)(b0 + nb);
        float4 o = make_float4(acc[mi][nj][0] + bb.x, acc[mi][nj][1] + bb.y,
                               acc[mi][nj][2] + bb.z, acc[mi][nj][3] + bb.w);
        *(float4*)(Cout + (size_t)m * 1024 + nb) = o;
      }
    }
  } else if (proj < 2) {
    const float* bias = proj ? b1 : b0;
    u16* Ob = proj ? O1 : O0;
    const int col0p = (gy & 7) << 7;
    #pragma unroll
    for (int mi = 0; mi < 4; ++mi) {
      const int m = row0 + wm + mi * 16 + lt;
      const int bb_ = m >> 11, lpos = m & (L_ - 1);
      #pragma unroll
      for (int nj = 0; nj < 4; ++nj) {
        const int nb = col0p + wn + nj * 16 + (lg << 2);
        const int d0 = nb & 63, h = nb >> 6;
        float4 ba = *(const float4*)(bias + nb);
        const float o0 = acc[mi][nj][0] + ba.x, o1 = acc[mi][nj][1] + ba.y;
        const float o2 = acc[mi][nj][2] + ba.z, o3 = acc[mi][nj][3] + ba.w;
        const float* ct = costab + lpos * 32 + (d0 >> 1);
        const float* st = sintab + lpos * 32 + (d0 >> 1);
        const float c0 = ct[0], c1 = ct[1], s0 = st[0], s1 = st[1];
        const float r0 = o0 * c0 - o1 * s0, r1 = o0 * s0 + o1 * c0;
        const float r2 = o2 * c1 - o3 * s1, r3 = o2 * s1 + o3 * c1;
        *(u16x4*)(Ob + ((size_t)(bb_ * 16 + h) * L_ + lpos) * 64 + d0) = f2b4(r0, r1, r2, r3);
      }
    }
  } else {
    const int col0p = (gy & 7) << 7;
    #pragma unroll
    for (int mi = 0; mi < 4; ++mi) {
      const int lb = row0 + wm + mi * 16 + (lg << 2);
      const int bb_ = lb >> 11;
      #pragma unroll
      for (int nj = 0; nj < 4; ++nj) {
        const int n = col0p + wn + nj * 16 + lt;
        const int h = n >> 6, dh = n & 63;
        const float bv1 = b2[n];
        *(u16x4*)(O2 + ((size_t)(bb_ * 16 + h) * 64 + dh) * L_ + (lb & (L_ - 1))) =
            f2b4(acc[mi][nj][0] + bv1, acc[mi][nj][1] + bv1,
                 acc[mi][nj][2] + bv1, acc[mi][nj][3] + bv1);
      }
    }
  }
}

// ---------------------------------------------------------------- MFMA attention, single-pass, LDS-resident P
// Block pr: stripes {pr, 127-pr} (16 rows each), kvA+kvB == 33 tiles pooled
// round-robin over 8 waves. Compute: QK -> exp (unnorm) -> bf16 P in LDS -> PV regs.
// Epilogue: lsum/PV reduce, then streaming normalized fp32 P rows + zeros + AO.
__global__ __launch_bounds__(512, 4) void attn_mfma(
    const u16* __restrict__ Qb, const u16* __restrict__ Kb, const u16* __restrict__ Vt,
    const float* __restrict__ pbg, float* __restrict__ Pout, u16* __restrict__ AOb)
{
  __shared__ u16 PL[33 * 16 * 64];        // 67584 B: stripe A rows (stride kvA*128B) then stripe B
  __shared__ float PVacc[2][16][64];      // 8192 B
  __shared__ float lsbuf[8][2][16];       // 1024 B
  const int t = threadIdx.x, w = t >> 6, lane = t & 63;
  const int lt = lane & 15, lg = lane >> 4;
  const int bh = blockIdx.y, b = bh >> 4, h = bh & 15;
  const int pr = blockIdx.x;
  const int sA = pr, sB = 127 - pr;
  const int kvA = (sA >> 2) + 1, kvB = (sB >> 2) + 1;
  const int swz = (lt & 7) << 4;
  const float C1 = 0.18033688011112042f;  // 0.125 * log2(e)
  char* PLb = (char*)PL;

  // Q fragments for both stripes
  const u16* qpA = Qb + ((size_t)bh * L_ + sA * 16 + lt) * 64 + lg * 8;
  const u16* qpB = Qb + ((size_t)bh * L_ + sB * 16 + lt) * 64 + lg * 8;
  const short8 qA0 = *(const short8*)(qpA), qA1 = *(const short8*)(qpA + 32);
  const short8 qB0 = *(const short8*)(qpB), qB1 = *(const short8*)(qpB + 32);

  f32x4 oaccA[4], oaccB[4];
  #pragma unroll
  for (int dt = 0; dt < 4; ++dt) {
    oaccA[dt] = (f32x4){0.f,0.f,0.f,0.f};
    oaccB[dt] = (f32x4){0.f,0.f,0.f,0.f};
  }
  float lsumA = 0.f, lsumB = 0.f;

  auto tile = [&](int s, int kvt, const short8& q0, const short8& q1,
                  f32x4* oacc, float& lsum, int pb0, int rstride) {
    const int j0 = kvt << 6;
    const int i  = s * 16 + lt;
    const u16* kp = Kb + ((size_t)bh * L_ + j0 + lt) * 64 + lg * 8;
    #pragma unroll
    for (int jt = 0; jt < 4; ++jt) {
      short8 kf0 = *(const short8*)(kp + jt * 1024);
      short8 kf1 = *(const short8*)(kp + jt * 1024 + 32);
      f32x4 z = (f32x4){0.f,0.f,0.f,0.f};
      z = __builtin_amdgcn_mfma_f32_16x16x32_bf16(kf0, q0, z, 0, 0, 0);
      z = __builtin_amdgcn_mfma_f32_16x16x32_bf16(kf1, q1, z, 0, 0, 0);
      const int jb = j0 + jt * 16 + (lg << 2);
      const int dd = i - jb;
      float pr4[4];
      #pragma unroll
      for (int r = 0; r < 4; ++r) {
        const int d  = dd - r;
        const int dc = d < 0 ? 0 : d;
        const float pe = exp2f(fmaf(z[r], C1, pbg[dc]));
        pr4[r] = d < 0 ? 0.f : pe;
        lsum += pr4[r];
      }
      *(u16x4*)(PLb + pb0 + lt * rstride + ((kvt * 128 + jt * 32 + lg * 8) ^ swz)) =
          f2b4(pr4[0], pr4[1], pr4[2], pr4[3]);
    }
    short8 pa0 = *(const short8*)(PLb + pb0 + lt * rstride + ((kvt * 128 + lg * 16) ^ swz));
    short8 pa1 = *(const short8*)(PLb + pb0 + lt * rstride + ((kvt * 128 + 64 + lg * 16) ^ swz));
    const u16* vp = Vt + ((size_t)bh * 64 + lt) * L_ + j0 + lg * 8;
    #pragma unroll
    for (int dt = 0; dt < 4; ++dt) {
      short8 vf0 = *(const short8*)(vp + dt * 16 * L_);
      short8 vf1 = *(const short8*)(vp + dt * 16 * L_ + 32);
      oacc[dt] = __builtin_amdgcn_mfma_f32_16x16x32_bf16(pa0, vf0, oacc[dt], 0, 0, 0);
      oacc[dt] = __builtin_amdgcn_mfma_f32_16x16x32_bf16(pa1, vf1, oacc[dt], 0, 0, 0);
    }
  };

  // pooled tiles: stripe A indices w, w+8, ...; stripe B continues the global round-robin
  for (int kvt = w; kvt < kvA; kvt += 8)
    tile(sA, kvt, qA0, qA1, oaccA, lsumA, 0, kvA << 7);
  const int st0 = (8 + w - (kvA & 7)) & 7;
  for (int kvt = st0; kvt < kvB; kvt += 8)
    tile(sB, kvt, qB0, qB1, oaccB, lsumB, kvA << 11, kvB << 7);

  // per-wave lsum partials
  lsumA += __shfl_xor(lsumA, 16); lsumA += __shfl_xor(lsumA, 32);
  lsumB += __shfl_xor(lsumB, 16); lsumB += __shfl_xor(lsumB, 32);
  if (lane < 16) { lsbuf[w][0][lt] = lsumA; lsbuf[w][1][lt] = lsumB; }

  // deterministic PV reduce (8 rounds)
  for (int rr = 0; rr < 8; ++rr) {
    if (w == rr) {
      #pragma unroll
      for (int dt = 0; dt < 4; ++dt)
        #pragma unroll
        for (int r = 0; r < 4; ++r) {
          if (rr == 0) {
            PVacc[0][(lg << 2) + r][dt * 16 + lt] = oaccA[dt][r];
            PVacc[1][(lg << 2) + r][dt * 16 + lt] = oaccB[dt][r];
          } else {
            PVacc[0][(lg << 2) + r][dt * 16 + lt] += oaccA[dt][r];
            PVacc[1][(lg << 2) + r][dt * 16 + lt] += oaccB[dt][r];
          }
        }
    }
    __syncthreads();
  }

  // ---- AO write (normalized): 2048 bf16 outs, 4 per thread
  {
    const int st = t >> 8, rl = (t >> 4) & 15, c0 = (t & 15) << 2;
    float den = 0.f;
    #pragma unroll
    for (int ww = 0; ww < 8; ++ww) den += lsbuf[ww][st][rl];
    const float rv = 1.f / den;
    const int s_ = st ? sB : sA;
    const int i = s_ * 16 + rl;
    u16x4 o = f2b4(PVacc[st][rl][c0] * rv, PVacc[st][rl][c0 + 1] * rv,
                   PVacc[st][rl][c0 + 2] * rv, PVacc[st][rl][c0 + 3] * rv);
    *(u16x4*)(AOb + ((size_t)(b * L_ + i)) * 1024 + h * 64 + c0) = o;
  }

  // ---- streaming P rows: 32 rows x 8KB, 16 threads per row, fully coalesced
  {
    const int rowslot = t >> 4, ct = t & 15;
    const int st = rowslot >> 4, rl = rowslot & 15;
    const int s_ = st ? sB : sA;
    const int i  = s_ * 16 + rl;
    float den = 0.f;
    #pragma unroll
    for (int ww = 0; ww < 8; ++ww) den += lsbuf[ww][st][rl];
    const float rv = 1.f / den;
    const char* rb = PLb + (st ? (kvA << 11) : 0) + rl * ((st ? kvB : kvA) << 7);
    const int rsw = (rl & 7) << 4;
    float* prow = Pout + ((size_t)bh * L_ + i) * L_;
    const int lim4 = i >> 2;
    for (int c4 = ct; c4 < 512; c4 += 16) {
      float4 o = make_float4(0.f, 0.f, 0.f, 0.f);
      if (c4 <= lim4) {
        u16x4 dv = *(const u16x4*)(rb + ((c4 << 3) ^ rsw));
        o.x = bf2f(dv.x) * rv; o.y = bf2f(dv.y) * rv;
        o.z = bf2f(dv.z) * rv; o.w = bf2f(dv.w) * rv;
        if (c4 == lim4) {
          const int j0c = c4 << 2;
          if (j0c + 1 > i) o.y = 0.f;
          if (j0c + 2 > i) o.z = 0.f;
          if (j0c + 3 > i) o.w = 0.f;
        }
      }
      *(float4*)(prow + (c4 << 2)) = o;
    }
  }
}

// ---------------------------------------------------------------- launch
extern "C" void kernel_launch(void* const* d_in, const int* in_sizes, int n_in,
                              void* d_out, int out_size, void* d_ws, size_t ws_size,
                              hipStream_t stream) {
  const float* x  = (const float*)d_in[0];
  const float* Wq = (const float*)d_in[1];
  const float* bq = (const float*)d_in[2];
  const float* Wk = (const float*)d_in[3];
  const float* bk = (const float*)d_in[4];
  const float* Wv = (const float*)d_in[5];
  const float* bv = (const float*)d_in[6];
  const float* Wo = (const float*)d_in[7];
  const float* bo = (const float*)d_in[8];

  float* out  = (float*)d_out;
  float* Pout = out + (size_t)BL_ * D_;

  float* ws = (float*)d_ws;
  u16* XB  = (u16*)(ws + WS_XB);
  u16* WT4 = (u16*)(ws + WS_WT4);
  u16* QB  = (u16*)(ws + WS_QB);
  u16* KB  = (u16*)(ws + WS_KB);
  u16* VT  = (u16*)(ws + WS_VT);
  u16* AOB = (u16*)(ws + WS_AOB);
  float* cosT = ws + WS_COS;
  float* sinT = ws + WS_SIN;
  float* pblG = ws + WS_PBL;

  fill_tables<<<256, 256, 0, stream>>>(cosT, sinT, pblG);
  xcast<<<2048, 256, 0, stream>>>(x, XB);
  wtrans4<<<dim3(16,16,4), 256, 0, stream>>>(Wq, Wk, Wv, Wo, WT4);

  gemm_k<1><<<dim3(32,24), 256, 0, stream>>>(XB, WT4, bq, bk, bv, cosT, sinT,
                                             QB, KB, VT, nullptr);

  attn_mfma<<<dim3(64,32), 512, 0, stream>>>(QB, KB, VT, pblG, Pout, AOB);

  gemm_k<0><<<dim3(32,8), 256, 0, stream>>>(AOB, WT4 + (size_t)3*1024*1024, bo,
                                            nullptr, nullptr, nullptr, nullptr,
                                            nullptr, nullptr, nullptr, out);
}

// Round 9
// 300.758 us; speedup vs baseline: 22.3281x; 1.1197x over previous
//
#include <hip/hip_runtime.h>
#include <math.h>

#define B_  2
#define L_  2048
#define D_  1024
#define H_  16
#define DH_ 64
#define BL_ (B_*L_)   // 4096

typedef unsigned short u16;
typedef __attribute__((ext_vector_type(8))) short short8;
typedef __attribute__((ext_vector_type(4))) float f32x4;
typedef __attribute__((ext_vector_type(4))) unsigned short u16x4;

template<bool V> struct BC { static constexpr bool value = V; };

// ---- workspace offsets (floats)
#define WS_XB   0            // x bf16 [4096][1024]
#define WS_WT4  2097152      // Wt bf16 [4][1024][1024]
#define WS_QB   4194304      // [32][2048][64] bf16
#define WS_KB   6291456
#define WS_VT   8388608      // [32][64][2048] bf16
#define WS_AOB  10485760     // AO bf16 [4096][1024]
#define WS_COS  12582912     // [2048][32] f32
#define WS_SIN  12648448
#define WS_PBL  12713984     // [2048] f32 (pre-scaled by log2e)
// end ~12.72M floats ~ 50.9 MB

__device__ __forceinline__ u16 f2b(float f) {
  union { float f; unsigned u; } v; v.f = f;
  unsigned r = (v.u + 0x7fffu + ((v.u >> 16) & 1u)) >> 16;
  return (u16)r;
}
__device__ __forceinline__ u16x4 f2b4(float a, float b, float c, float d) {
  u16x4 u; u.x = f2b(a); u.y = f2b(b); u.z = f2b(c); u.w = f2b(d); return u;
}
__device__ __forceinline__ float bf2f(u16 u) {
  union { unsigned u; float f; } v; v.u = ((unsigned)u) << 16; return v.f;
}
__device__ __forceinline__ void gl_lds16(const void* g, void* l) {
  __builtin_amdgcn_global_load_lds(
      (const __attribute__((address_space(1))) unsigned int*)g,
      (__attribute__((address_space(3))) unsigned int*)l, 16, 0, 0);
}

// ---------------------------------------------------------------- tables
__global__ void fill_tables(float* __restrict__ costab, float* __restrict__ sintab,
                            float* __restrict__ pbl) {
  int idx = blockIdx.x * 256 + threadIdx.x;
  if (idx < L_ * 32) {
    int l = idx >> 5, tp = idx & 31;
    double inv = pow(10000.0, -2.0 * (double)tp / 64.0);
    double th  = (double)l * inv;
    costab[idx] = (float)cos(th);
    sintab[idx] = (float)sin(th);
  }
  if (idx < L_) {
    double d = (double)idx;
    double v = 0.5  * cos(6.283185307179586 * d / 24.0)
             + 0.25 * cos(6.283185307179586 * d / 168.0);
    pbl[idx] = (float)(v * 1.4426950408889634);
  }
}

// ---------------------------------------------------------------- x -> bf16
__global__ __launch_bounds__(256) void xcast(const float* __restrict__ x, u16* __restrict__ xb) {
  const size_t i = ((size_t)blockIdx.x * 256 + threadIdx.x) * 8;
  float4 a = *(const float4*)(x + i);
  float4 b = *(const float4*)(x + i + 4);
  u16 us[8] = { f2b(a.x),f2b(a.y),f2b(a.z),f2b(a.w), f2b(b.x),f2b(b.y),f2b(b.z),f2b(b.w) };
  *(short8*)(xb + i) = *(short8*)us;
}

// ---------------------------------------------------------------- W[k][n] f32 -> Wt[n][k] bf16 (4 weights, z-indexed)
__global__ __launch_bounds__(256) void wtrans4(const float* __restrict__ W0, const float* __restrict__ W1,
                                               const float* __restrict__ W2, const float* __restrict__ W3,
                                               u16* __restrict__ Wt) {
  __shared__ u16 tt[64][80];
  const int z = blockIdx.z;
  const float* W = (z == 0) ? W0 : (z == 1) ? W1 : (z == 2) ? W2 : W3;
  u16* Wtz = Wt + (size_t)z * 1024 * 1024;
  const int k0 = blockIdx.x << 6, n0 = blockIdx.y << 6;
  const int t = threadIdx.x;
  {
    const int r = t >> 4, c4 = (t & 15) << 2;
    for (int rr = r; rr < 64; rr += 16) {
      float4 v = *(const float4*)(W + (size_t)(k0 + rr) * D_ + n0 + c4);
      tt[c4+0][rr] = f2b(v.x); tt[c4+1][rr] = f2b(v.y);
      tt[c4+2][rr] = f2b(v.z); tt[c4+3][rr] = f2b(v.w);
    }
  }
  __syncthreads();
  const int n = t >> 2, kc = (t & 3) << 4;
  u16* dst = Wtz + (size_t)(n0 + n) * D_ + k0 + kc;
  #pragma unroll
  for (int u = 0; u < 16; ++u) dst[u] = tt[n][kc + u];
}

// ---------------------------------------------------------------- bf16 MFMA GEMM, 128x128 tile, BK=64
template<int KIND>
__global__ __launch_bounds__(256) void gemm_k(
    const u16* __restrict__ Ag, const u16* __restrict__ Bg,
    const float* __restrict__ b0, const float* __restrict__ b1, const float* __restrict__ b2,
    const float* __restrict__ costab, const float* __restrict__ sintab,
    u16* __restrict__ O0, u16* __restrict__ O1, u16* __restrict__ O2,
    float* __restrict__ Cout)
{
  __shared__ u16 As[8192];
  __shared__ u16 Bs[8192];
  const int t = threadIdx.x, w = t >> 6, lane = t & 63;
  const int lt = lane & 15, lg = lane >> 4;
  const int row0 = blockIdx.x << 7;
  const int gy   = blockIdx.y;
  const int col0 = gy << 7;
  const int wm = (w & 1) << 6, wn = (w >> 1) << 6;
  const int proj = (KIND == 1) ? (gy >> 3) : 0;
  const bool swp = (KIND == 0) || (proj < 2);

  const int srow = lane >> 3;
  const int gch  = (lane & 7) ^ (srow & 7);
  const u16* aptr[4]; const u16* bptr[4];
  char* adst[4]; char* bdst[4];
  #pragma unroll
  for (int u = 0; u < 4; ++u) {
    const int rl = w * 32 + u * 8 + srow;
    aptr[u] = Ag + (size_t)(row0 + rl) * 1024 + gch * 8;
    bptr[u] = Bg + (size_t)(col0 + rl) * 1024 + gch * 8;
    adst[u] = (char*)As + (w * 32 + u * 8) * 128;
    bdst[u] = (char*)Bs + (w * 32 + u * 8) * 128;
  }
  int aoff[2][4], boff[2][4];
  #pragma unroll
  for (int ks = 0; ks < 2; ++ks)
    #pragma unroll
    for (int q = 0; q < 4; ++q) {
      const int ra = wm + q * 16 + lt;
      aoff[ks][q] = ra * 128 + (((ks * 4 + lg) ^ (ra & 7)) << 4);
      const int rb = wn + q * 16 + lt;
      boff[ks][q] = rb * 128 + (((ks * 4 + lg) ^ (rb & 7)) << 4);
    }

  f32x4 acc[4][4];
  #pragma unroll
  for (int i = 0; i < 4; ++i)
    #pragma unroll
    for (int j = 0; j < 4; ++j) acc[i][j] = (f32x4){0.f,0.f,0.f,0.f};

  auto loop = [&](auto SW) {
    for (int kt = 0; kt < 16; ++kt) {
      #pragma unroll
      for (int u = 0; u < 4; ++u) {
        gl_lds16(aptr[u] + kt * 64, adst[u]);
        gl_lds16(bptr[u] + kt * 64, bdst[u]);
      }
      __syncthreads();
      #pragma unroll
      for (int ks = 0; ks < 2; ++ks) {
        short8 af[4], bf[4];
        #pragma unroll
        for (int q = 0; q < 4; ++q) {
          af[q] = *(const short8*)((const char*)As + aoff[ks][q]);
          bf[q] = *(const short8*)((const char*)Bs + boff[ks][q]);
        }
        #pragma unroll
        for (int mi = 0; mi < 4; ++mi)
          #pragma unroll
          for (int nj = 0; nj < 4; ++nj) {
            if constexpr (decltype(SW)::value)
              acc[mi][nj] = __builtin_amdgcn_mfma_f32_16x16x32_bf16(bf[nj], af[mi], acc[mi][nj], 0, 0, 0);
            else
              acc[mi][nj] = __builtin_amdgcn_mfma_f32_16x16x32_bf16(af[mi], bf[nj], acc[mi][nj], 0, 0, 0);
          }
      }
      __syncthreads();
    }
  };
  if (swp) loop(BC<true>{}); else loop(BC<false>{});

  if constexpr (KIND == 0) {
    #pragma unroll
    for (int mi = 0; mi < 4; ++mi) {
      const int m = row0 + wm + mi * 16 + lt;
      #pragma unroll
      for (int nj = 0; nj < 4; ++nj) {
        const int nb = col0 + wn + nj * 16 + (lg << 2);
        float4 bb = *(const float4*)(b0 + nb);
        float4 o = make_float4(acc[mi][nj][0] + bb.x, acc[mi][nj][1] + bb.y,
                               acc[mi][nj][2] + bb.z, acc[mi][nj][3] + bb.w);
        *(float4*)(Cout + (size_t)m * 1024 + nb) = o;
      }
    }
  } else if (proj < 2) {
    const float* bias = proj ? b1 : b0;
    u16* Ob = proj ? O1 : O0;
    const int col0p = (gy & 7) << 7;
    #pragma unroll
    for (int mi = 0; mi < 4; ++mi) {
      const int m = row0 + wm + mi * 16 + lt;
      const int bb_ = m >> 11, lpos = m & (L_ - 1);
      #pragma unroll
      for (int nj = 0; nj < 4; ++nj) {
        const int nb = col0p + wn + nj * 16 + (lg << 2);
        const int d0 = nb & 63, h = nb >> 6;
        float4 ba = *(const float4*)(bias + nb);
        const float o0 = acc[mi][nj][0] + ba.x, o1 = acc[mi][nj][1] + ba.y;
        const float o2 = acc[mi][nj][2] + ba.z, o3 = acc[mi][nj][3] + ba.w;
        const float* ct = costab + lpos * 32 + (d0 >> 1);
        const float* st = sintab + lpos * 32 + (d0 >> 1);
        const float c0 = ct[0], c1 = ct[1], s0 = st[0], s1 = st[1];
        const float r0 = o0 * c0 - o1 * s0, r1 = o0 * s0 + o1 * c0;
        const float r2 = o2 * c1 - o3 * s1, r3 = o2 * s1 + o3 * c1;
        *(u16x4*)(Ob + ((size_t)(bb_ * 16 + h) * L_ + lpos) * 64 + d0) = f2b4(r0, r1, r2, r3);
      }
    }
  } else {
    const int col0p = (gy & 7) << 7;
    #pragma unroll
    for (int mi = 0; mi < 4; ++mi) {
      const int lb = row0 + wm + mi * 16 + (lg << 2);
      const int bb_ = lb >> 11;
      #pragma unroll
      for (int nj = 0; nj < 4; ++nj) {
        const int n = col0p + wn + nj * 16 + lt;
        const int h = n >> 6, dh = n & 63;
        const float bv1 = b2[n];
        *(u16x4*)(O2 + ((size_t)(bb_ * 16 + h) * 64 + dh) * L_ + (lb & (L_ - 1))) =
            f2b4(acc[mi][nj][0] + bv1, acc[mi][nj][1] + bv1,
                 acc[mi][nj][2] + bv1, acc[mi][nj][3] + bv1);
      }
    }
  }
}

// ---------------------------------------------------------------- MFMA attention, single-pass, LDS-resident P
// XCD-swizzled block mapping: each XCD owns 4 consecutive bh (K/V/Q L2-local).
// Block: stripes {pr, 127-pr}, 33 kv tiles pooled over 8 waves.
// Epilogue: lsum barrier -> stream normalized P (stores drain early) -> PV reduce -> AO.
__global__ __launch_bounds__(512, 4) void attn_mfma(
    const u16* __restrict__ Qb, const u16* __restrict__ Kb, const u16* __restrict__ Vt,
    const float* __restrict__ pbg, float* __restrict__ Pout, u16* __restrict__ AOb)
{
  __shared__ u16 PL[33 * 16 * 64];        // 67584 B
  __shared__ float PVacc[2][16][64];      // 8192 B
  __shared__ float lsbuf[8][2][16];       // 1024 B
  const int t = threadIdx.x, w = t >> 6, lane = t & 63;
  const int lt = lane & 15, lg = lane >> 4;
  // XCD-bijective swizzle: 2048 blocks, 8 XCDs, 256 each
  const int wg = blockIdx.x + (blockIdx.y << 6);
  const int sid = (wg & 7) * 256 + (wg >> 3);
  const int bh = sid >> 6, pr = sid & 63;
  const int b = bh >> 4, h = bh & 15;
  const int sA = pr, sB = 127 - pr;
  const int kvA = (sA >> 2) + 1, kvB = (sB >> 2) + 1;
  const int swz = (lt & 7) << 4;
  const float C1 = 0.18033688011112042f;  // 0.125 * log2(e)
  char* PLb = (char*)PL;

  f32x4 oaccA[4], oaccB[4];
  #pragma unroll
  for (int dt = 0; dt < 4; ++dt) {
    oaccA[dt] = (f32x4){0.f,0.f,0.f,0.f};
    oaccB[dt] = (f32x4){0.f,0.f,0.f,0.f};
  }
  float lsumA = 0.f, lsumB = 0.f;

  auto tile = [&](int s, int kvt, const short8& q0, const short8& q1,
                  f32x4* oacc, float& lsum, int pb0, int rstride, bool masked) {
    const int j0 = kvt << 6;
    const int i  = s * 16 + lt;
    const u16* kp = Kb + ((size_t)bh * L_ + j0 + lt) * 64 + lg * 8;
    // K frags
    short8 kf[8];
    #pragma unroll
    for (int jt = 0; jt < 4; ++jt) {
      kf[2*jt]   = *(const short8*)(kp + jt * 1024);
      kf[2*jt+1] = *(const short8*)(kp + jt * 1024 + 32);
    }
    f32x4 z[4];
    #pragma unroll
    for (int jt = 0; jt < 4; ++jt) {
      f32x4 zz = (f32x4){0.f,0.f,0.f,0.f};
      zz = __builtin_amdgcn_mfma_f32_16x16x32_bf16(kf[2*jt],   q0, zz, 0, 0, 0);
      zz = __builtin_amdgcn_mfma_f32_16x16x32_bf16(kf[2*jt+1], q1, zz, 0, 0, 0);
      z[jt] = zz;
    }
    // V frags issued now; latency hides under exp block
    const u16* vp = Vt + ((size_t)bh * 64 + lt) * L_ + j0 + lg * 8;
    short8 vf[8];
    #pragma unroll
    for (int dt = 0; dt < 4; ++dt) {
      vf[2*dt]   = *(const short8*)(vp + dt * 16 * L_);
      vf[2*dt+1] = *(const short8*)(vp + dt * 16 * L_ + 32);
    }
    // exp + LDS staging
    #pragma unroll
    for (int jt = 0; jt < 4; ++jt) {
      const int jb = j0 + jt * 16 + (lg << 2);
      const int dd = i - jb;
      float pr4[4];
      if (masked) {
        #pragma unroll
        for (int r = 0; r < 4; ++r) {
          const int d  = dd - r;
          const int dc = d < 0 ? 0 : d;
          const float pe = exp2f(fmaf(z[jt][r], C1, pbg[dc]));
          pr4[r] = d < 0 ? 0.f : pe;
          lsum += pr4[r];
        }
      } else {
        #pragma unroll
        for (int r = 0; r < 4; ++r) {
          pr4[r] = exp2f(fmaf(z[jt][r], C1, pbg[dd - r]));
          lsum += pr4[r];
        }
      }
      *(u16x4*)(PLb + pb0 + lt * rstride + ((kvt * 128 + jt * 32 + lg * 8) ^ swz)) =
          f2b4(pr4[0], pr4[1], pr4[2], pr4[3]);
    }
    short8 pa0 = *(const short8*)(PLb + pb0 + lt * rstride + ((kvt * 128 + lg * 16) ^ swz));
    short8 pa1 = *(const short8*)(PLb + pb0 + lt * rstride + ((kvt * 128 + 64 + lg * 16) ^ swz));
    #pragma unroll
    for (int dt = 0; dt < 4; ++dt) {
      oacc[dt] = __builtin_amdgcn_mfma_f32_16x16x32_bf16(pa0, vf[2*dt],   oacc[dt], 0, 0, 0);
      oacc[dt] = __builtin_amdgcn_mfma_f32_16x16x32_bf16(pa1, vf[2*dt+1], oacc[dt], 0, 0, 0);
    }
  };

  // stripe A
  {
    const u16* qpA = Qb + ((size_t)bh * L_ + sA * 16 + lt) * 64 + lg * 8;
    const short8 qA0 = *(const short8*)(qpA), qA1 = *(const short8*)(qpA + 32);
    for (int kvt = w; kvt < kvA; kvt += 8)
      tile(sA, kvt, qA0, qA1, oaccA, lsumA, 0, kvA << 7, kvt == kvA - 1);
  }
  // stripe B (continue round-robin so every wave gets 4-5 total tiles)
  {
    const u16* qpB = Qb + ((size_t)bh * L_ + sB * 16 + lt) * 64 + lg * 8;
    const short8 qB0 = *(const short8*)(qpB), qB1 = *(const short8*)(qpB + 32);
    const int st0 = (8 + w - (kvA & 7)) & 7;
    for (int kvt = st0; kvt < kvB; kvt += 8)
      tile(sB, kvt, qB0, qB1, oaccB, lsumB, kvA << 11, kvB << 7, kvt == kvB - 1);
  }

  // per-wave lsum partials -> LDS
  lsumA += __shfl_xor(lsumA, 16); lsumA += __shfl_xor(lsumA, 32);
  lsumB += __shfl_xor(lsumB, 16); lsumB += __shfl_xor(lsumB, 32);
  if (lane < 16) { lsbuf[w][0][lt] = lsumA; lsbuf[w][1][lt] = lsumB; }
  __syncthreads();

  // ---- streaming P FIRST (stores drain under the PV reduce)
  {
    const int rowslot = t >> 4, ct = t & 15;
    const int st = rowslot >> 4, rl = rowslot & 15;
    const int s_ = st ? sB : sA;
    const int i  = s_ * 16 + rl;
    float den = 0.f;
    #pragma unroll
    for (int ww = 0; ww < 8; ++ww) den += lsbuf[ww][st][rl];
    const float rv = 1.f / den;
    const char* rb = PLb + (st ? (kvA << 11) : 0) + rl * ((st ? kvB : kvA) << 7);
    const int rsw = (rl & 7) << 4;
    float* prow = Pout + ((size_t)bh * L_ + i) * L_;
    const int lim4 = i >> 2;
    for (int cc = 0; cc < 8; ++cc) {
      const int c4b = ct + cc * 64;
      u16x4 dv[4];
      #pragma unroll
      for (int u = 0; u < 4; ++u) {
        const int c4 = c4b + u * 16;
        dv[u] = (c4 <= lim4) ? *(const u16x4*)(rb + ((c4 << 3) ^ rsw))
                             : (u16x4){0, 0, 0, 0};
      }
      #pragma unroll
      for (int u = 0; u < 4; ++u) {
        const int c4 = c4b + u * 16;
        float4 o = make_float4(0.f, 0.f, 0.f, 0.f);
        if (c4 <= lim4) {
          o.x = bf2f(dv[u].x) * rv; o.y = bf2f(dv[u].y) * rv;
          o.z = bf2f(dv[u].z) * rv; o.w = bf2f(dv[u].w) * rv;
          if (c4 == lim4) {
            const int j0c = c4 << 2;
            if (j0c + 1 > i) o.y = 0.f;
            if (j0c + 2 > i) o.z = 0.f;
            if (j0c + 3 > i) o.w = 0.f;
          }
        }
        *(float4*)(prow + (c4 << 2)) = o;
      }
    }
  }

  // ---- deterministic PV reduce (8 rounds), overlapped with store drain
  for (int rr = 0; rr < 8; ++rr) {
    if (w == rr) {
      #pragma unroll
      for (int dt = 0; dt < 4; ++dt)
        #pragma unroll
        for (int r = 0; r < 4; ++r) {
          if (rr == 0) {
            PVacc[0][(lg << 2) + r][dt * 16 + lt] = oaccA[dt][r];
            PVacc[1][(lg << 2) + r][dt * 16 + lt] = oaccB[dt][r];
          } else {
            PVacc[0][(lg << 2) + r][dt * 16 + lt] += oaccA[dt][r];
            PVacc[1][(lg << 2) + r][dt * 16 + lt] += oaccB[dt][r];
          }
        }
    }
    __syncthreads();
  }

  // ---- AO write (normalized)
  {
    const int st = t >> 8, rl = (t >> 4) & 15, c0 = (t & 15) << 2;
    float den = 0.f;
    #pragma unroll
    for (int ww = 0; ww < 8; ++ww) den += lsbuf[ww][st][rl];
    const float rv = 1.f / den;
    const int s_ = st ? sB : sA;
    const int i = s_ * 16 + rl;
    u16x4 o = f2b4(PVacc[st][rl][c0] * rv, PVacc[st][rl][c0 + 1] * rv,
                   PVacc[st][rl][c0 + 2] * rv, PVacc[st][rl][c0 + 3] * rv);
    *(u16x4*)(AOb + ((size_t)(b * L_ + i)) * 1024 + h * 64 + c0) = o;
  }
}

// ---------------------------------------------------------------- launch
extern "C" void kernel_launch(void* const* d_in, const int* in_sizes, int n_in,
                              void* d_out, int out_size, void* d_ws, size_t ws_size,
                              hipStream_t stream) {
  const float* x  = (const float*)d_in[0];
  const float* Wq = (const float*)d_in[1];
  const float* bq = (const float*)d_in[2];
  const float* Wk = (const float*)d_in[3];
  const float* bk = (const float*)d_in[4];
  const float* Wv = (const float*)d_in[5];
  const float* bv = (const float*)d_in[6];
  const float* Wo = (const float*)d_in[7];
  const float* bo = (const float*)d_in[8];

  float* out  = (float*)d_out;
  float* Pout = out + (size_t)BL_ * D_;

  float* ws = (float*)d_ws;
  u16* XB  = (u16*)(ws + WS_XB);
  u16* WT4 = (u16*)(ws + WS_WT4);
  u16* QB  = (u16*)(ws + WS_QB);
  u16* KB  = (u16*)(ws + WS_KB);
  u16* VT  = (u16*)(ws + WS_VT);
  u16* AOB = (u16*)(ws + WS_AOB);
  float* cosT = ws + WS_COS;
  float* sinT = ws + WS_SIN;
  float* pblG = ws + WS_PBL;

  fill_tables<<<256, 256, 0, stream>>>(cosT, sinT, pblG);
  xcast<<<2048, 256, 0, stream>>>(x, XB);
  wtrans4<<<dim3(16,16,4), 256, 0, stream>>>(Wq, Wk, Wv, Wo, WT4);

  gemm_k<1><<<dim3(32,24), 256, 0, stream>>>(XB, WT4, bq, bk, bv, cosT, sinT,
                                             QB, KB, VT, nullptr);

  attn_mfma<<<dim3(64,32), 512, 0, stream>>>(QB, KB, VT, pblG, Pout, AOB);

  gemm_k<0><<<dim3(32,8), 256, 0, stream>>>(AOB, WT4 + (size_t)3*1024*1024, bo,
                                            nullptr, nullptr, nullptr, nullptr,
                                            nullptr, nullptr, nullptr, out);
}

// Round 11
// 285.858 us; speedup vs baseline: 23.4918x; 1.0521x over previous
//
#include <hip/hip_runtime.h>
#include <math.h>

#define B_  2
#define L_  2048
#define D_  1024
#define H_  16
#define DH_ 64
#define BL_ (B_*L_)   // 4096

typedef unsigned short u16;
typedef __attribute__((ext_vector_type(8))) short short8;
typedef __attribute__((ext_vector_type(4))) float f32x4;
typedef __attribute__((ext_vector_type(4))) unsigned short u16x4;

template<bool V> struct BC { static constexpr bool value = V; };

// ---- workspace offsets (floats)
#define WS_XB   0            // x bf16 [4096][1024]
#define WS_WT4  2097152      // Wt bf16 [4][1024][1024]
#define WS_QB   4194304      // [32][2048][64] bf16
#define WS_KB   6291456
#define WS_VT   8388608      // [32][64][2048] bf16
#define WS_AOB  10485760     // AO bf16 [4096][1024]
#define WS_COS  12582912     // [2048][32] f32
#define WS_SIN  12648448
#define WS_PBL  12713984     // [2048] f32 (pre-scaled by log2e)
// end ~12.72M floats ~ 50.9 MB

__device__ __forceinline__ u16 f2b(float f) {
  union { float f; unsigned u; } v; v.f = f;
  unsigned r = (v.u + 0x7fffu + ((v.u >> 16) & 1u)) >> 16;
  return (u16)r;
}
__device__ __forceinline__ u16x4 f2b4(float a, float b, float c, float d) {
  u16x4 u; u.x = f2b(a); u.y = f2b(b); u.z = f2b(c); u.w = f2b(d); return u;
}
__device__ __forceinline__ float bf2f(u16 u) {
  union { unsigned u; float f; } v; v.u = ((unsigned)u) << 16; return v.f;
}
__device__ __forceinline__ void gl_lds16(const void* g, void* l) {
  __builtin_amdgcn_global_load_lds(
      (const __attribute__((address_space(1))) unsigned int*)g,
      (__attribute__((address_space(3))) unsigned int*)l, 16, 0, 0);
}
__device__ __forceinline__ void nt_store4(float x, float y, float z, float w, float* p) {
  f32x4 v = (f32x4){x, y, z, w};
  __builtin_nontemporal_store(v, (f32x4*)p);
}

// ---------------------------------------------------------------- tables
__global__ void fill_tables(float* __restrict__ costab, float* __restrict__ sintab,
                            float* __restrict__ pbl) {
  int idx = blockIdx.x * 256 + threadIdx.x;
  if (idx < L_ * 32) {
    int l = idx >> 5, tp = idx & 31;
    double inv = pow(10000.0, -2.0 * (double)tp / 64.0);
    double th  = (double)l * inv;
    costab[idx] = (float)cos(th);
    sintab[idx] = (float)sin(th);
  }
  if (idx < L_) {
    double d = (double)idx;
    double v = 0.5  * cos(6.283185307179586 * d / 24.0)
             + 0.25 * cos(6.283185307179586 * d / 168.0);
    pbl[idx] = (float)(v * 1.4426950408889634);
  }
}

// ---------------------------------------------------------------- x -> bf16
__global__ __launch_bounds__(256) void xcast(const float* __restrict__ x, u16* __restrict__ xb) {
  const size_t i = ((size_t)blockIdx.x * 256 + threadIdx.x) * 8;
  float4 a = *(const float4*)(x + i);
  float4 b = *(const float4*)(x + i + 4);
  u16 us[8] = { f2b(a.x),f2b(a.y),f2b(a.z),f2b(a.w), f2b(b.x),f2b(b.y),f2b(b.z),f2b(b.w) };
  *(short8*)(xb + i) = *(short8*)us;
}

// ---------------------------------------------------------------- W[k][n] f32 -> Wt[n][k] bf16 (4 weights, z-indexed)
__global__ __launch_bounds__(256) void wtrans4(const float* __restrict__ W0, const float* __restrict__ W1,
                                               const float* __restrict__ W2, const float* __restrict__ W3,
                                               u16* __restrict__ Wt) {
  __shared__ u16 tt[64][80];
  const int z = blockIdx.z;
  const float* W = (z == 0) ? W0 : (z == 1) ? W1 : (z == 2) ? W2 : W3;
  u16* Wtz = Wt + (size_t)z * 1024 * 1024;
  const int k0 = blockIdx.x << 6, n0 = blockIdx.y << 6;
  const int t = threadIdx.x;
  {
    const int r = t >> 4, c4 = (t & 15) << 2;
    for (int rr = r; rr < 64; rr += 16) {
      float4 v = *(const float4*)(W + (size_t)(k0 + rr) * D_ + n0 + c4);
      tt[c4+0][rr] = f2b(v.x); tt[c4+1][rr] = f2b(v.y);
      tt[c4+2][rr] = f2b(v.z); tt[c4+3][rr] = f2b(v.w);
    }
  }
  __syncthreads();
  const int n = t >> 2, kc = (t & 3) << 4;
  u16* dst = Wtz + (size_t)(n0 + n) * D_ + k0 + kc;
  #pragma unroll
  for (int u = 0; u < 16; ++u) dst[u] = tt[n][kc + u];
}

// ---------------------------------------------------------------- bf16 MFMA GEMM, 128x128 tile, BK=64
template<int KIND>
__global__ __launch_bounds__(256) void gemm_k(
    const u16* __restrict__ Ag, const u16* __restrict__ Bg,
    const float* __restrict__ b0, const float* __restrict__ b1, const float* __restrict__ b2,
    const float* __restrict__ costab, const float* __restrict__ sintab,
    u16* __restrict__ O0, u16* __restrict__ O1, u16* __restrict__ O2,
    float* __restrict__ Cout)
{
  __shared__ u16 As[8192];
  __shared__ u16 Bs[8192];
  const int t = threadIdx.x, w = t >> 6, lane = t & 63;
  const int lt = lane & 15, lg = lane >> 4;
  const int row0 = blockIdx.x << 7;
  const int gy   = blockIdx.y;
  const int col0 = gy << 7;
  const int wm = (w & 1) << 6, wn = (w >> 1) << 6;
  const int proj = (KIND == 1) ? (gy >> 3) : 0;
  const bool swp = (KIND == 0) || (proj < 2);

  const int srow = lane >> 3;
  const int gch  = (lane & 7) ^ (srow & 7);
  const u16* aptr[4]; const u16* bptr[4];
  char* adst[4]; char* bdst[4];
  #pragma unroll
  for (int u = 0; u < 4; ++u) {
    const int rl = w * 32 + u * 8 + srow;
    aptr[u] = Ag + (size_t)(row0 + rl) * 1024 + gch * 8;
    bptr[u] = Bg + (size_t)(col0 + rl) * 1024 + gch * 8;
    adst[u] = (char*)As + (w * 32 + u * 8) * 128;
    bdst[u] = (char*)Bs + (w * 32 + u * 8) * 128;
  }
  int aoff[2][4], boff[2][4];
  #pragma unroll
  for (int ks = 0; ks < 2; ++ks)
    #pragma unroll
    for (int q = 0; q < 4; ++q) {
      const int ra = wm + q * 16 + lt;
      aoff[ks][q] = ra * 128 + (((ks * 4 + lg) ^ (ra & 7)) << 4);
      const int rb = wn + q * 16 + lt;
      boff[ks][q] = rb * 128 + (((ks * 4 + lg) ^ (rb & 7)) << 4);
    }

  f32x4 acc[4][4];
  #pragma unroll
  for (int i = 0; i < 4; ++i)
    #pragma unroll
    for (int j = 0; j < 4; ++j) acc[i][j] = (f32x4){0.f,0.f,0.f,0.f};

  auto loop = [&](auto SW) {
    for (int kt = 0; kt < 16; ++kt) {
      #pragma unroll
      for (int u = 0; u < 4; ++u) {
        gl_lds16(aptr[u] + kt * 64, adst[u]);
        gl_lds16(bptr[u] + kt * 64, bdst[u]);
      }
      __syncthreads();
      #pragma unroll
      for (int ks = 0; ks < 2; ++ks) {
        short8 af[4], bf[4];
        #pragma unroll
        for (int q = 0; q < 4; ++q) {
          af[q] = *(const short8*)((const char*)As + aoff[ks][q]);
          bf[q] = *(const short8*)((const char*)Bs + boff[ks][q]);
        }
        #pragma unroll
        for (int mi = 0; mi < 4; ++mi)
          #pragma unroll
          for (int nj = 0; nj < 4; ++nj) {
            if constexpr (decltype(SW)::value)
              acc[mi][nj] = __builtin_amdgcn_mfma_f32_16x16x32_bf16(bf[nj], af[mi], acc[mi][nj], 0, 0, 0);
            else
              acc[mi][nj] = __builtin_amdgcn_mfma_f32_16x16x32_bf16(af[mi], bf[nj], acc[mi][nj], 0, 0, 0);
          }
      }
      __syncthreads();
    }
  };
  if (swp) loop(BC<true>{}); else loop(BC<false>{});

  if constexpr (KIND == 0) {
    #pragma unroll
    for (int mi = 0; mi < 4; ++mi) {
      const int m = row0 + wm + mi * 16 + lt;
      #pragma unroll
      for (int nj = 0; nj < 4; ++nj) {
        const int nb = col0 + wn + nj * 16 + (lg << 2);
        float4 bb = *(const float4*)(b0 + nb);
        nt_store4(acc[mi][nj][0] + bb.x, acc[mi][nj][1] + bb.y,
                  acc[mi][nj][2] + bb.z, acc[mi][nj][3] + bb.w,
                  Cout + (size_t)m * 1024 + nb);
      }
    }
  } else if (proj < 2) {
    const float* bias = proj ? b1 : b0;
    u16* Ob = proj ? O1 : O0;
    const int col0p = (gy & 7) << 7;
    #pragma unroll
    for (int mi = 0; mi < 4; ++mi) {
      const int m = row0 + wm + mi * 16 + lt;
      const int bb_ = m >> 11, lpos = m & (L_ - 1);
      #pragma unroll
      for (int nj = 0; nj < 4; ++nj) {
        const int nb = col0p + wn + nj * 16 + (lg << 2);
        const int d0 = nb & 63, h = nb >> 6;
        float4 ba = *(const float4*)(bias + nb);
        const float o0 = acc[mi][nj][0] + ba.x, o1 = acc[mi][nj][1] + ba.y;
        const float o2 = acc[mi][nj][2] + ba.z, o3 = acc[mi][nj][3] + ba.w;
        const float* ct = costab + lpos * 32 + (d0 >> 1);
        const float* st = sintab + lpos * 32 + (d0 >> 1);
        const float c0 = ct[0], c1 = ct[1], s0 = st[0], s1 = st[1];
        const float r0 = o0 * c0 - o1 * s0, r1 = o0 * s0 + o1 * c0;
        const float r2 = o2 * c1 - o3 * s1, r3 = o2 * s1 + o3 * c1;
        *(u16x4*)(Ob + ((size_t)(bb_ * 16 + h) * L_ + lpos) * 64 + d0) = f2b4(r0, r1, r2, r3);
      }
    }
  } else {
    const int col0p = (gy & 7) << 7;
    #pragma unroll
    for (int mi = 0; mi < 4; ++mi) {
      const int lb = row0 + wm + mi * 16 + (lg << 2);
      const int bb_ = lb >> 11;
      #pragma unroll
      for (int nj = 0; nj < 4; ++nj) {
        const int n = col0p + wn + nj * 16 + lt;
        const int h = n >> 6, dh = n & 63;
        const float bv1 = b2[n];
        *(u16x4*)(O2 + ((size_t)(bb_ * 16 + h) * 64 + dh) * L_ + (lb & (L_ - 1))) =
            f2b4(acc[mi][nj][0] + bv1, acc[mi][nj][1] + bv1,
                 acc[mi][nj][2] + bv1, acc[mi][nj][3] + bv1);
      }
    }
  }
}

// ---------------------------------------------------------------- MFMA attention, single-pass, LDS-resident P
// XCD-swizzled block mapping; 33 kv tiles pooled over 8 waves.
// P streamed with NON-TEMPORAL stores (P is write-once) so K/V stay L2-resident.
__global__ __launch_bounds__(512, 4) void attn_mfma(
    const u16* __restrict__ Qb, const u16* __restrict__ Kb, const u16* __restrict__ Vt,
    const float* __restrict__ pbg, float* __restrict__ Pout, u16* __restrict__ AOb)
{
  __shared__ u16 PL[33 * 16 * 64];        // 67584 B
  __shared__ float PVacc[2][16][64];      // 8192 B
  __shared__ float lsbuf[8][2][16];       // 1024 B
  const int t = threadIdx.x, w = t >> 6, lane = t & 63;
  const int lt = lane & 15, lg = lane >> 4;
  // XCD-bijective swizzle: 2048 blocks, 8 XCDs, 256 each
  const int wg = blockIdx.x + (blockIdx.y << 6);
  const int sid = (wg & 7) * 256 + (wg >> 3);
  const int bh = sid >> 6, pr = sid & 63;
  const int b = bh >> 4, h = bh & 15;
  const int sA = pr, sB = 127 - pr;
  const int kvA = (sA >> 2) + 1, kvB = (sB >> 2) + 1;
  const int swz = (lt & 7) << 4;
  const float C1 = 0.18033688011112042f;  // 0.125 * log2(e)
  char* PLb = (char*)PL;

  f32x4 oaccA[4], oaccB[4];
  #pragma unroll
  for (int dt = 0; dt < 4; ++dt) {
    oaccA[dt] = (f32x4){0.f,0.f,0.f,0.f};
    oaccB[dt] = (f32x4){0.f,0.f,0.f,0.f};
  }
  float lsumA = 0.f, lsumB = 0.f;

  auto tile = [&](int s, int kvt, const short8& q0, const short8& q1,
                  f32x4* oacc, float& lsum, int pb0, int rstride, bool masked) {
    const int j0 = kvt << 6;
    const int i  = s * 16 + lt;
    const u16* kp = Kb + ((size_t)bh * L_ + j0 + lt) * 64 + lg * 8;
    short8 kf[8];
    #pragma unroll
    for (int jt = 0; jt < 4; ++jt) {
      kf[2*jt]   = *(const short8*)(kp + jt * 1024);
      kf[2*jt+1] = *(const short8*)(kp + jt * 1024 + 32);
    }
    f32x4 z[4];
    #pragma unroll
    for (int jt = 0; jt < 4; ++jt) {
      f32x4 zz = (f32x4){0.f,0.f,0.f,0.f};
      zz = __builtin_amdgcn_mfma_f32_16x16x32_bf16(kf[2*jt],   q0, zz, 0, 0, 0);
      zz = __builtin_amdgcn_mfma_f32_16x16x32_bf16(kf[2*jt+1], q1, zz, 0, 0, 0);
      z[jt] = zz;
    }
    const u16* vp = Vt + ((size_t)bh * 64 + lt) * L_ + j0 + lg * 8;
    short8 vf[8];
    #pragma unroll
    for (int dt = 0; dt < 4; ++dt) {
      vf[2*dt]   = *(const short8*)(vp + dt * 16 * L_);
      vf[2*dt+1] = *(const short8*)(vp + dt * 16 * L_ + 32);
    }
    #pragma unroll
    for (int jt = 0; jt < 4; ++jt) {
      const int jb = j0 + jt * 16 + (lg << 2);
      const int dd = i - jb;
      float pr4[4];
      if (masked) {
        #pragma unroll
        for (int r = 0; r < 4; ++r) {
          const int d  = dd - r;
          const int dc = d < 0 ? 0 : d;
          const float pe = exp2f(fmaf(z[jt][r], C1, pbg[dc]));
          pr4[r] = d < 0 ? 0.f : pe;
          lsum += pr4[r];
        }
      } else {
        #pragma unroll
        for (int r = 0; r < 4; ++r) {
          pr4[r] = exp2f(fmaf(z[jt][r], C1, pbg[dd - r]));
          lsum += pr4[r];
        }
      }
      *(u16x4*)(PLb + pb0 + lt * rstride + ((kvt * 128 + jt * 32 + lg * 8) ^ swz)) =
          f2b4(pr4[0], pr4[1], pr4[2], pr4[3]);
    }
    short8 pa0 = *(const short8*)(PLb + pb0 + lt * rstride + ((kvt * 128 + lg * 16) ^ swz));
    short8 pa1 = *(const short8*)(PLb + pb0 + lt * rstride + ((kvt * 128 + 64 + lg * 16) ^ swz));
    #pragma unroll
    for (int dt = 0; dt < 4; ++dt) {
      oacc[dt] = __builtin_amdgcn_mfma_f32_16x16x32_bf16(pa0, vf[2*dt],   oacc[dt], 0, 0, 0);
      oacc[dt] = __builtin_amdgcn_mfma_f32_16x16x32_bf16(pa1, vf[2*dt+1], oacc[dt], 0, 0, 0);
    }
  };

  // stripe A
  {
    const u16* qpA = Qb + ((size_t)bh * L_ + sA * 16 + lt) * 64 + lg * 8;
    const short8 qA0 = *(const short8*)(qpA), qA1 = *(const short8*)(qpA + 32);
    for (int kvt = w; kvt < kvA; kvt += 8)
      tile(sA, kvt, qA0, qA1, oaccA, lsumA, 0, kvA << 7, kvt == kvA - 1);
  }
  // stripe B (continue round-robin so every wave gets 4-5 total tiles)
  {
    const u16* qpB = Qb + ((size_t)bh * L_ + sB * 16 + lt) * 64 + lg * 8;
    const short8 qB0 = *(const short8*)(qpB), qB1 = *(const short8*)(qpB + 32);
    const int st0 = (8 + w - (kvA & 7)) & 7;
    for (int kvt = st0; kvt < kvB; kvt += 8)
      tile(sB, kvt, qB0, qB1, oaccB, lsumB, kvA << 11, kvB << 7, kvt == kvB - 1);
  }

  // per-wave lsum partials -> LDS
  lsumA += __shfl_xor(lsumA, 16); lsumA += __shfl_xor(lsumA, 32);
  lsumB += __shfl_xor(lsumB, 16); lsumB += __shfl_xor(lsumB, 32);
  if (lane < 16) { lsbuf[w][0][lt] = lsumA; lsbuf[w][1][lt] = lsumB; }
  __syncthreads();

  // ---- streaming P FIRST (non-temporal: write-once, keep K/V in L2)
  {
    const int rowslot = t >> 4, ct = t & 15;
    const int st = rowslot >> 4, rl = rowslot & 15;
    const int s_ = st ? sB : sA;
    const int i  = s_ * 16 + rl;
    float den = 0.f;
    #pragma unroll
    for (int ww = 0; ww < 8; ++ww) den += lsbuf[ww][st][rl];
    const float rv = 1.f / den;
    const char* rb = PLb + (st ? (kvA << 11) : 0) + rl * ((st ? kvB : kvA) << 7);
    const int rsw = (rl & 7) << 4;
    float* prow = Pout + ((size_t)bh * L_ + i) * L_;
    const int lim4 = i >> 2;
    for (int cc = 0; cc < 8; ++cc) {
      const int c4b = ct + cc * 64;
      u16x4 dv[4];
      #pragma unroll
      for (int u = 0; u < 4; ++u) {
        const int c4 = c4b + u * 16;
        dv[u] = (c4 <= lim4) ? *(const u16x4*)(rb + ((c4 << 3) ^ rsw))
                             : (u16x4){0, 0, 0, 0};
      }
      #pragma unroll
      for (int u = 0; u < 4; ++u) {
        const int c4 = c4b + u * 16;
        float ox = 0.f, oy = 0.f, oz = 0.f, ow = 0.f;
        if (c4 <= lim4) {
          ox = bf2f(dv[u].x) * rv; oy = bf2f(dv[u].y) * rv;
          oz = bf2f(dv[u].z) * rv; ow = bf2f(dv[u].w) * rv;
          if (c4 == lim4) {
            const int j0c = c4 << 2;
            if (j0c + 1 > i) oy = 0.f;
            if (j0c + 2 > i) oz = 0.f;
            if (j0c + 3 > i) ow = 0.f;
          }
        }
        nt_store4(ox, oy, oz, ow, prow + (c4 << 2));
      }
    }
  }

  // ---- deterministic PV reduce (8 rounds), overlapped with store drain
  for (int rr = 0; rr < 8; ++rr) {
    if (w == rr) {
      #pragma unroll
      for (int dt = 0; dt < 4; ++dt)
        #pragma unroll
        for (int r = 0; r < 4; ++r) {
          if (rr == 0) {
            PVacc[0][(lg << 2) + r][dt * 16 + lt] = oaccA[dt][r];
            PVacc[1][(lg << 2) + r][dt * 16 + lt] = oaccB[dt][r];
          } else {
            PVacc[0][(lg << 2) + r][dt * 16 + lt] += oaccA[dt][r];
            PVacc[1][(lg << 2) + r][dt * 16 + lt] += oaccB[dt][r];
          }
        }
    }
    __syncthreads();
  }

  // ---- AO write (normalized; cached — re-read by out-projection GEMM)
  {
    const int st = t >> 8, rl = (t >> 4) & 15, c0 = (t & 15) << 2;
    float den = 0.f;
    #pragma unroll
    for (int ww = 0; ww < 8; ++ww) den += lsbuf[ww][st][rl];
    const float rv = 1.f / den;
    const int s_ = st ? sB : sA;
    const int i = s_ * 16 + rl;
    u16x4 o = f2b4(PVacc[st][rl][c0] * rv, PVacc[st][rl][c0 + 1] * rv,
                   PVacc[st][rl][c0 + 2] * rv, PVacc[st][rl][c0 + 3] * rv);
    *(u16x4*)(AOb + ((size_t)(b * L_ + i)) * 1024 + h * 64 + c0) = o;
  }
}

// ---------------------------------------------------------------- launch
extern "C" void kernel_launch(void* const* d_in, const int* in_sizes, int n_in,
                              void* d_out, int out_size, void* d_ws, size_t ws_size,
                              hipStream_t stream) {
  const float* x  = (const float*)d_in[0];
  const float* Wq = (const float*)d_in[1];
  const float* bq = (const float*)d_in[2];
  const float* Wk = (const float*)d_in[3];
  const float* bk = (const float*)d_in[4];
  const float* Wv = (const float*)d_in[5];
  const float* bv = (const float*)d_in[6];
  const float* Wo = (const float*)d_in[7];
  const float* bo = (const float*)d_in[8];

  float* out  = (float*)d_out;
  float* Pout = out + (size_t)BL_ * D_;

  float* ws = (float*)d_ws;
  u16* XB  = (u16*)(ws + WS_XB);
  u16* WT4 = (u16*)(ws + WS_WT4);
  u16* QB  = (u16*)(ws + WS_QB);
  u16* KB  = (u16*)(ws + WS_KB);
  u16* VT  = (u16*)(ws + WS_VT);
  u16* AOB = (u16*)(ws + WS_AOB);
  float* cosT = ws + WS_COS;
  float* sinT = ws + WS_SIN;
  float* pblG = ws + WS_PBL;

  fill_tables<<<256, 256, 0, stream>>>(cosT, sinT, pblG);
  xcast<<<2048, 256, 0, stream>>>(x, XB);
  wtrans4<<<dim3(16,16,4), 256, 0, stream>>>(Wq, Wk, Wv, Wo, WT4);

  gemm_k<1><<<dim3(32,24), 256, 0, stream>>>(XB, WT4, bq, bk, bv, cosT, sinT,
                                             QB, KB, VT, nullptr);

  attn_mfma<<<dim3(64,32), 512, 0, stream>>>(QB, KB, VT, pblG, Pout, AOB);

  gemm_k<0><<<dim3(32,8), 256, 0, stream>>>(AOB, WT4 + (size_t)3*1024*1024, bo,
                                            nullptr, nullptr, nullptr, nullptr,
                                            nullptr, nullptr, nullptr, out);
}

// Round 12
// 256.929 us; speedup vs baseline: 26.1370x; 1.1126x over previous
//
#include <hip/hip_runtime.h>
#include <math.h>

#define B_  2
#define L_  2048
#define D_  1024
#define H_  16
#define DH_ 64
#define BL_ (B_*L_)   // 4096

typedef unsigned short u16;
typedef __attribute__((ext_vector_type(8))) short short8;
typedef __attribute__((ext_vector_type(4))) float f32x4;
typedef __attribute__((ext_vector_type(4))) unsigned short u16x4;

template<bool V> struct BC { static constexpr bool value = V; };

// ---- workspace offsets (floats)
#define WS_XB   0            // x bf16 [4096][1024]
#define WS_WT4  2097152      // Wt bf16 [4][1024][1024]
#define WS_QB   4194304      // [32][2048][64] bf16
#define WS_KB   6291456
#define WS_VT   8388608      // [32][64][2048] bf16
#define WS_AOB  10485760     // AO bf16 [4096][1024]
#define WS_COS  12582912     // [2048][32] f32
#define WS_SIN  12648448
#define WS_PBL  12713984     // [2048] f32 (pre-scaled by log2e)
// end ~12.72M floats ~ 50.9 MB

__device__ __forceinline__ u16 f2b(float f) {
  union { float f; unsigned u; } v; v.f = f;
  unsigned r = (v.u + 0x7fffu + ((v.u >> 16) & 1u)) >> 16;
  return (u16)r;
}
__device__ __forceinline__ u16x4 f2b4(float a, float b, float c, float d) {
  u16x4 u; u.x = f2b(a); u.y = f2b(b); u.z = f2b(c); u.w = f2b(d); return u;
}
__device__ __forceinline__ float bf2f(u16 u) {
  union { unsigned u; float f; } v; v.u = ((unsigned)u) << 16; return v.f;
}
__device__ __forceinline__ void gl_lds16(const void* g, void* l) {
  __builtin_amdgcn_global_load_lds(
      (const __attribute__((address_space(1))) unsigned int*)g,
      (__attribute__((address_space(3))) unsigned int*)l, 16, 0, 0);
}
__device__ __forceinline__ void nt_store4(float x, float y, float z, float w, float* p) {
  f32x4 v = (f32x4){x, y, z, w};
  __builtin_nontemporal_store(v, (f32x4*)p);
}

// ---------------------------------------------------------------- tables
__global__ void fill_tables(float* __restrict__ costab, float* __restrict__ sintab,
                            float* __restrict__ pbl) {
  int idx = blockIdx.x * 256 + threadIdx.x;
  if (idx < L_ * 32) {
    int l = idx >> 5, tp = idx & 31;
    double inv = pow(10000.0, -2.0 * (double)tp / 64.0);
    double th  = (double)l * inv;
    costab[idx] = (float)cos(th);
    sintab[idx] = (float)sin(th);
  }
  if (idx < L_) {
    double d = (double)idx;
    double v = 0.5  * cos(6.283185307179586 * d / 24.0)
             + 0.25 * cos(6.283185307179586 * d / 168.0);
    pbl[idx] = (float)(v * 1.4426950408889634);
  }
}

// ---------------------------------------------------------------- x -> bf16
__global__ __launch_bounds__(256) void xcast(const float* __restrict__ x, u16* __restrict__ xb) {
  const size_t i = ((size_t)blockIdx.x * 256 + threadIdx.x) * 8;
  float4 a = *(const float4*)(x + i);
  float4 b = *(const float4*)(x + i + 4);
  u16 us[8] = { f2b(a.x),f2b(a.y),f2b(a.z),f2b(a.w), f2b(b.x),f2b(b.y),f2b(b.z),f2b(b.w) };
  *(short8*)(xb + i) = *(short8*)us;
}

// ---------------------------------------------------------------- W[k][n] f32 -> Wt[n][k] bf16 (4 weights, z-indexed)
__global__ __launch_bounds__(256) void wtrans4(const float* __restrict__ W0, const float* __restrict__ W1,
                                               const float* __restrict__ W2, const float* __restrict__ W3,
                                               u16* __restrict__ Wt) {
  __shared__ u16 tt[64][80];
  const int z = blockIdx.z;
  const float* W = (z == 0) ? W0 : (z == 1) ? W1 : (z == 2) ? W2 : W3;
  u16* Wtz = Wt + (size_t)z * 1024 * 1024;
  const int k0 = blockIdx.x << 6, n0 = blockIdx.y << 6;
  const int t = threadIdx.x;
  {
    const int r = t >> 4, c4 = (t & 15) << 2;
    for (int rr = r; rr < 64; rr += 16) {
      float4 v = *(const float4*)(W + (size_t)(k0 + rr) * D_ + n0 + c4);
      tt[c4+0][rr] = f2b(v.x); tt[c4+1][rr] = f2b(v.y);
      tt[c4+2][rr] = f2b(v.z); tt[c4+3][rr] = f2b(v.w);
    }
  }
  __syncthreads();
  const int n = t >> 2, kc = (t & 3) << 4;
  u16* dst = Wtz + (size_t)(n0 + n) * D_ + k0 + kc;
  #pragma unroll
  for (int u = 0; u < 16; ++u) dst[u] = tt[n][kc + u];
}

// ---------------------------------------------------------------- bf16 MFMA GEMM, 128x128 tile, BK=64
// XCD-bijective swizzle: each XCD owns a contiguous gy-range (W panels resident in its L2).
template<int KIND>
__global__ __launch_bounds__(256) void gemm_k(
    const u16* __restrict__ Ag, const u16* __restrict__ Bg,
    const float* __restrict__ b0, const float* __restrict__ b1, const float* __restrict__ b2,
    const float* __restrict__ costab, const float* __restrict__ sintab,
    u16* __restrict__ O0, u16* __restrict__ O1, u16* __restrict__ O2,
    float* __restrict__ Cout)
{
  __shared__ u16 As[8192];
  __shared__ u16 Bs[8192];
  const int t = threadIdx.x, w = t >> 6, lane = t & 63;
  const int lt = lane & 15, lg = lane >> 4;
  const int wg = blockIdx.x + (blockIdx.y << 5);
  int sid;
  if constexpr (KIND == 1) sid = (wg & 7) * 96 + (wg >> 3);   // 768 blocks, 3 gy per XCD
  else                     sid = (wg & 7) * 32 + (wg >> 3);   // 256 blocks, 1 gy per XCD
  const int row0 = (sid & 31) << 7;
  const int gy   = sid >> 5;
  const int col0 = gy << 7;
  const int wm = (w & 1) << 6, wn = (w >> 1) << 6;
  const int proj = (KIND == 1) ? (gy >> 3) : 0;
  const bool swp = (KIND == 0) || (proj < 2);

  const int srow = lane >> 3;
  const int gch  = (lane & 7) ^ (srow & 7);
  const u16* aptr[4]; const u16* bptr[4];
  char* adst[4]; char* bdst[4];
  #pragma unroll
  for (int u = 0; u < 4; ++u) {
    const int rl = w * 32 + u * 8 + srow;
    aptr[u] = Ag + (size_t)(row0 + rl) * 1024 + gch * 8;
    bptr[u] = Bg + (size_t)(col0 + rl) * 1024 + gch * 8;
    adst[u] = (char*)As + (w * 32 + u * 8) * 128;
    bdst[u] = (char*)Bs + (w * 32 + u * 8) * 128;
  }
  int aoff[2][4], boff[2][4];
  #pragma unroll
  for (int ks = 0; ks < 2; ++ks)
    #pragma unroll
    for (int q = 0; q < 4; ++q) {
      const int ra = wm + q * 16 + lt;
      aoff[ks][q] = ra * 128 + (((ks * 4 + lg) ^ (ra & 7)) << 4);
      const int rb = wn + q * 16 + lt;
      boff[ks][q] = rb * 128 + (((ks * 4 + lg) ^ (rb & 7)) << 4);
    }

  f32x4 acc[4][4];
  #pragma unroll
  for (int i = 0; i < 4; ++i)
    #pragma unroll
    for (int j = 0; j < 4; ++j) acc[i][j] = (f32x4){0.f,0.f,0.f,0.f};

  auto loop = [&](auto SW) {
    for (int kt = 0; kt < 16; ++kt) {
      #pragma unroll
      for (int u = 0; u < 4; ++u) {
        gl_lds16(aptr[u] + kt * 64, adst[u]);
        gl_lds16(bptr[u] + kt * 64, bdst[u]);
      }
      __syncthreads();
      #pragma unroll
      for (int ks = 0; ks < 2; ++ks) {
        short8 af[4], bf[4];
        #pragma unroll
        for (int q = 0; q < 4; ++q) {
          af[q] = *(const short8*)((const char*)As + aoff[ks][q]);
          bf[q] = *(const short8*)((const char*)Bs + boff[ks][q]);
        }
        #pragma unroll
        for (int mi = 0; mi < 4; ++mi)
          #pragma unroll
          for (int nj = 0; nj < 4; ++nj) {
            if constexpr (decltype(SW)::value)
              acc[mi][nj] = __builtin_amdgcn_mfma_f32_16x16x32_bf16(bf[nj], af[mi], acc[mi][nj], 0, 0, 0);
            else
              acc[mi][nj] = __builtin_amdgcn_mfma_f32_16x16x32_bf16(af[mi], bf[nj], acc[mi][nj], 0, 0, 0);
          }
      }
      __syncthreads();
    }
  };
  if (swp) loop(BC<true>{}); else loop(BC<false>{});

  if constexpr (KIND == 0) {
    #pragma unroll
    for (int mi = 0; mi < 4; ++mi) {
      const int m = row0 + wm + mi * 16 + lt;
      #pragma unroll
      for (int nj = 0; nj < 4; ++nj) {
        const int nb = col0 + wn + nj * 16 + (lg << 2);
        float4 bb = *(const float4*)(b0 + nb);
        nt_store4(acc[mi][nj][0] + bb.x, acc[mi][nj][1] + bb.y,
                  acc[mi][nj][2] + bb.z, acc[mi][nj][3] + bb.w,
                  Cout + (size_t)m * 1024 + nb);
      }
    }
  } else if (proj < 2) {
    const float* bias = proj ? b1 : b0;
    u16* Ob = proj ? O1 : O0;
    const int col0p = (gy & 7) << 7;
    #pragma unroll
    for (int mi = 0; mi < 4; ++mi) {
      const int m = row0 + wm + mi * 16 + lt;
      const int bb_ = m >> 11, lpos = m & (L_ - 1);
      #pragma unroll
      for (int nj = 0; nj < 4; ++nj) {
        const int nb = col0p + wn + nj * 16 + (lg << 2);
        const int d0 = nb & 63, h = nb >> 6;
        float4 ba = *(const float4*)(bias + nb);
        const float o0 = acc[mi][nj][0] + ba.x, o1 = acc[mi][nj][1] + ba.y;
        const float o2 = acc[mi][nj][2] + ba.z, o3 = acc[mi][nj][3] + ba.w;
        const float* ct = costab + lpos * 32 + (d0 >> 1);
        const float* st = sintab + lpos * 32 + (d0 >> 1);
        const float c0 = ct[0], c1 = ct[1], s0 = st[0], s1 = st[1];
        const float r0 = o0 * c0 - o1 * s0, r1 = o0 * s0 + o1 * c0;
        const float r2 = o2 * c1 - o3 * s1, r3 = o2 * s1 + o3 * c1;
        *(u16x4*)(Ob + ((size_t)(bb_ * 16 + h) * L_ + lpos) * 64 + d0) = f2b4(r0, r1, r2, r3);
      }
    }
  } else {
    const int col0p = (gy & 7) << 7;
    #pragma unroll
    for (int mi = 0; mi < 4; ++mi) {
      const int lb = row0 + wm + mi * 16 + (lg << 2);
      const int bb_ = lb >> 11;
      #pragma unroll
      for (int nj = 0; nj < 4; ++nj) {
        const int n = col0p + wn + nj * 16 + lt;
        const int h = n >> 6, dh = n & 63;
        const float bv1 = b2[n];
        *(u16x4*)(O2 + ((size_t)(bb_ * 16 + h) * 64 + dh) * L_ + (lb & (L_ - 1))) =
            f2b4(acc[mi][nj][0] + bv1, acc[mi][nj][1] + bv1,
                 acc[mi][nj][2] + bv1, acc[mi][nj][3] + bv1);
      }
    }
  }
}

// ---------------------------------------------------------------- MFMA attention, single-pass, LDS-resident P
// pb table in LDS (aliased onto PVacc: unused until the PV reduce, which
// round-0 overwrites with '='). Wave-per-row P streaming: 1KB contiguous
// non-temporal stores. XCD-swizzled block mapping.
__global__ __launch_bounds__(512, 4) void attn_mfma(
    const u16* __restrict__ Qb, const u16* __restrict__ Kb, const u16* __restrict__ Vt,
    const float* __restrict__ pbg, float* __restrict__ Pout, u16* __restrict__ AOb)
{
  __shared__ u16 PL[33 * 16 * 64];        // 67584 B
  __shared__ float PVacc[2][16][64];      // 8192 B = 2048 floats; doubles as pbl pre-reduce
  __shared__ float lsbuf[8][2][16];       // 1024 B
  float* pbl = &PVacc[0][0][0];
  const int t = threadIdx.x, w = t >> 6, lane = t & 63;
  const int lt = lane & 15, lg = lane >> 4;
  // stage pb table (pre-scaled by log2e) into LDS
  *(float4*)(pbl + t * 4) = *(const float4*)(pbg + t * 4);
  // XCD-bijective swizzle: 2048 blocks, 8 XCDs, 256 each
  const int wg = blockIdx.x + (blockIdx.y << 6);
  const int sid = (wg & 7) * 256 + (wg >> 3);
  const int bh = sid >> 6, pr = sid & 63;
  const int b = bh >> 4, h = bh & 15;
  const int sA = pr, sB = 127 - pr;
  const int kvA = (sA >> 2) + 1, kvB = (sB >> 2) + 1;
  const int swz = (lt & 7) << 4;
  const float C1 = 0.18033688011112042f;  // 0.125 * log2(e)
  char* PLb = (char*)PL;
  __syncthreads();                         // pbl visible to all waves

  f32x4 oaccA[4], oaccB[4];
  #pragma unroll
  for (int dt = 0; dt < 4; ++dt) {
    oaccA[dt] = (f32x4){0.f,0.f,0.f,0.f};
    oaccB[dt] = (f32x4){0.f,0.f,0.f,0.f};
  }
  float lsumA = 0.f, lsumB = 0.f;

  auto tile = [&](int s, int kvt, const short8& q0, const short8& q1,
                  f32x4* oacc, float& lsum, int pb0, int rstride, bool masked) {
    const int j0 = kvt << 6;
    const int i  = s * 16 + lt;
    const u16* kp = Kb + ((size_t)bh * L_ + j0 + lt) * 64 + lg * 8;
    short8 kf[8];
    #pragma unroll
    for (int jt = 0; jt < 4; ++jt) {
      kf[2*jt]   = *(const short8*)(kp + jt * 1024);
      kf[2*jt+1] = *(const short8*)(kp + jt * 1024 + 32);
    }
    f32x4 z[4];
    #pragma unroll
    for (int jt = 0; jt < 4; ++jt) {
      f32x4 zz = (f32x4){0.f,0.f,0.f,0.f};
      zz = __builtin_amdgcn_mfma_f32_16x16x32_bf16(kf[2*jt],   q0, zz, 0, 0, 0);
      zz = __builtin_amdgcn_mfma_f32_16x16x32_bf16(kf[2*jt+1], q1, zz, 0, 0, 0);
      z[jt] = zz;
    }
    const u16* vp = Vt + ((size_t)bh * 64 + lt) * L_ + j0 + lg * 8;
    short8 vf[8];
    #pragma unroll
    for (int dt = 0; dt < 4; ++dt) {
      vf[2*dt]   = *(const short8*)(vp + dt * 16 * L_);
      vf[2*dt+1] = *(const short8*)(vp + dt * 16 * L_ + 32);
    }
    #pragma unroll
    for (int jt = 0; jt < 4; ++jt) {
      const int jb = j0 + jt * 16 + (lg << 2);
      const int dd = i - jb;
      float pr4[4];
      if (masked) {
        #pragma unroll
        for (int r = 0; r < 4; ++r) {
          const int d  = dd - r;
          const int dc = d < 0 ? 0 : d;
          const float pe = exp2f(fmaf(z[jt][r], C1, pbl[dc]));
          pr4[r] = d < 0 ? 0.f : pe;
          lsum += pr4[r];
        }
      } else {
        #pragma unroll
        for (int r = 0; r < 4; ++r) {
          pr4[r] = exp2f(fmaf(z[jt][r], C1, pbl[dd - r]));
          lsum += pr4[r];
        }
      }
      *(u16x4*)(PLb + pb0 + lt * rstride + ((kvt * 128 + jt * 32 + lg * 8) ^ swz)) =
          f2b4(pr4[0], pr4[1], pr4[2], pr4[3]);
    }
    short8 pa0 = *(const short8*)(PLb + pb0 + lt * rstride + ((kvt * 128 + lg * 16) ^ swz));
    short8 pa1 = *(const short8*)(PLb + pb0 + lt * rstride + ((kvt * 128 + 64 + lg * 16) ^ swz));
    #pragma unroll
    for (int dt = 0; dt < 4; ++dt) {
      oacc[dt] = __builtin_amdgcn_mfma_f32_16x16x32_bf16(pa0, vf[2*dt],   oacc[dt], 0, 0, 0);
      oacc[dt] = __builtin_amdgcn_mfma_f32_16x16x32_bf16(pa1, vf[2*dt+1], oacc[dt], 0, 0, 0);
    }
  };

  // stripe A
  {
    const u16* qpA = Qb + ((size_t)bh * L_ + sA * 16 + lt) * 64 + lg * 8;
    const short8 qA0 = *(const short8*)(qpA), qA1 = *(const short8*)(qpA + 32);
    for (int kvt = w; kvt < kvA; kvt += 8)
      tile(sA, kvt, qA0, qA1, oaccA, lsumA, 0, kvA << 7, kvt == kvA - 1);
  }
  // stripe B (continue round-robin so every wave gets 4-5 total tiles)
  {
    const u16* qpB = Qb + ((size_t)bh * L_ + sB * 16 + lt) * 64 + lg * 8;
    const short8 qB0 = *(const short8*)(qpB), qB1 = *(const short8*)(qpB + 32);
    const int st0 = (8 + w - (kvA & 7)) & 7;
    for (int kvt = st0; kvt < kvB; kvt += 8)
      tile(sB, kvt, qB0, qB1, oaccB, lsumB, kvA << 11, kvB << 7, kvt == kvB - 1);
  }

  // per-wave lsum partials -> LDS
  lsumA += __shfl_xor(lsumA, 16); lsumA += __shfl_xor(lsumA, 32);
  lsumB += __shfl_xor(lsumB, 16); lsumB += __shfl_xor(lsumB, 32);
  if (lane < 16) { lsbuf[w][0][lt] = lsumA; lsbuf[w][1][lt] = lsumB; }
  __syncthreads();

  // ---- streaming P FIRST (non-temporal, wave-per-row: 1KB contiguous stores)
  #pragma unroll
  for (int rp = 0; rp < 4; ++rp) {
    const int rid = rp * 8 + w;             // 0..31
    const int st = rid >> 4, rl = rid & 15;
    const int s_ = st ? sB : sA;
    const int i  = s_ * 16 + rl;
    float den = 0.f;
    #pragma unroll
    for (int ww = 0; ww < 8; ++ww) den += lsbuf[ww][st][rl];
    const float rv = 1.f / den;
    const char* rb = PLb + (st ? (kvA << 11) : 0) + rl * ((st ? kvB : kvA) << 7);
    const int rsw = (rl & 7) << 4;
    float* prow = Pout + ((size_t)bh * L_ + i) * L_;
    const int lim4 = i >> 2;
    #pragma unroll
    for (int cc = 0; cc < 8; ++cc) {
      const int c4 = lane + cc * 64;
      float ox = 0.f, oy = 0.f, oz = 0.f, ow = 0.f;
      if (c4 <= lim4) {
        u16x4 dv = *(const u16x4*)(rb + ((c4 << 3) ^ rsw));
        ox = bf2f(dv.x) * rv; oy = bf2f(dv.y) * rv;
        oz = bf2f(dv.z) * rv; ow = bf2f(dv.w) * rv;
        if (c4 == lim4) {
          const int j0c = c4 << 2;
          if (j0c + 1 > i) oy = 0.f;
          if (j0c + 2 > i) oz = 0.f;
          if (j0c + 3 > i) ow = 0.f;
        }
      }
      nt_store4(ox, oy, oz, ow, prow + (c4 << 2));
    }
  }

  // ---- deterministic PV reduce (8 rounds), overlapped with store drain
  // (round 0 '=' overwrites the pbl alias — pbl no longer needed)
  for (int rr = 0; rr < 8; ++rr) {
    if (w == rr) {
      #pragma unroll
      for (int dt = 0; dt < 4; ++dt)
        #pragma unroll
        for (int r = 0; r < 4; ++r) {
          if (rr == 0) {
            PVacc[0][(lg << 2) + r][dt * 16 + lt] = oaccA[dt][r];
            PVacc[1][(lg << 2) + r][dt * 16 + lt] = oaccB[dt][r];
          } else {
            PVacc[0][(lg << 2) + r][dt * 16 + lt] += oaccA[dt][r];
            PVacc[1][(lg << 2) + r][dt * 16 + lt] += oaccB[dt][r];
          }
        }
    }
    __syncthreads();
  }

  // ---- AO write (normalized; cached — re-read by out-projection GEMM)
  {
    const int st = t >> 8, rl = (t >> 4) & 15, c0 = (t & 15) << 2;
    float den = 0.f;
    #pragma unroll
    for (int ww = 0; ww < 8; ++ww) den += lsbuf[ww][st][rl];
    const float rv = 1.f / den;
    const int s_ = st ? sB : sA;
    const int i = s_ * 16 + rl;
    u16x4 o = f2b4(PVacc[st][rl][c0] * rv, PVacc[st][rl][c0 + 1] * rv,
                   PVacc[st][rl][c0 + 2] * rv, PVacc[st][rl][c0 + 3] * rv);
    *(u16x4*)(AOb + ((size_t)(b * L_ + i)) * 1024 + h * 64 + c0) = o;
  }
}

// ---------------------------------------------------------------- launch
extern "C" void kernel_launch(void* const* d_in, const int* in_sizes, int n_in,
                              void* d_out, int out_size, void* d_ws, size_t ws_size,
                              hipStream_t stream) {
  const float* x  = (const float*)d_in[0];
  const float* Wq = (const float*)d_in[1];
  const float* bq = (const float*)d_in[2];
  const float* Wk = (const float*)d_in[3];
  const float* bk = (const float*)d_in[4];
  const float* Wv = (const float*)d_in[5];
  const float* bv = (const float*)d_in[6];
  const float* Wo = (const float*)d_in[7];
  const float* bo = (const float*)d_in[8];

  float* out  = (float*)d_out;
  float* Pout = out + (size_t)BL_ * D_;

  float* ws = (float*)d_ws;
  u16* XB  = (u16*)(ws + WS_XB);
  u16* WT4 = (u16*)(ws + WS_WT4);
  u16* QB  = (u16*)(ws + WS_QB);
  u16* KB  = (u16*)(ws + WS_KB);
  u16* VT  = (u16*)(ws + WS_VT);
  u16* AOB = (u16*)(ws + WS_AOB);
  float* cosT = ws + WS_COS;
  float* sinT = ws + WS_SIN;
  float* pblG = ws + WS_PBL;

  fill_tables<<<256, 256, 0, stream>>>(cosT, sinT, pblG);
  xcast<<<2048, 256, 0, stream>>>(x, XB);
  wtrans4<<<dim3(16,16,4), 256, 0, stream>>>(Wq, Wk, Wv, Wo, WT4);

  gemm_k<1><<<dim3(32,24), 256, 0, stream>>>(XB, WT4, bq, bk, bv, cosT, sinT,
                                             QB, KB, VT, nullptr);

  attn_mfma<<<dim3(64,32), 512, 0, stream>>>(QB, KB, VT, pblG, Pout, AOB);

  gemm_k<0><<<dim3(32,8), 256, 0, stream>>>(AOB, WT4 + (size_t)3*1024*1024, bo,
                                            nullptr, nullptr, nullptr, nullptr,
                                            nullptr, nullptr, nullptr, out);
}